// Round 1
// baseline (12008.618 us; speedup 1.0000x reference)
//
#include <hip/hip_runtime.h>
#include <math.h>

#define DEV __device__ __forceinline__

constexpr int NGAUSS = 50;
constexpr int LAY = 6;
constexpr float STEP = 6.0f / 49.0f;
constexpr float COEFF = -0.5f / (STEP * STEP);
constexpr float LN2F = 0.69314718055994531f;
constexpr float PI_OVER_CUT = 0.52359877559829887f;  // pi/6

DEV float sspf(float x) {
    // softplus(x) - ln2, numerically stable
    float ax = fabsf(x);
    return fmaxf(x, 0.f) + log1pf(__expf(-ax)) - LN2F;
}

// ---------------- geometry: dist + cosine cutoff ----------------
__global__ void k_geom(const int* __restrict__ ei, const float* __restrict__ pos,
                       float* __restrict__ dist, float* __restrict__ cosC, int E) {
    int e = blockIdx.x * 256 + threadIdx.x;
    if (e >= E) return;
    int r = ei[e], c = ei[E + e];
    float dx = pos[3 * r + 0] - pos[3 * c + 0];
    float dy = pos[3 * r + 1] - pos[3 * c + 1];
    float dz = pos[3 * r + 2] - pos[3 * c + 2];
    float d = sqrtf(dx * dx + dy * dy + dz * dz);
    dist[e] = d;
    cosC[e] = 0.5f * (__cosf(d * PI_OVER_CUT) + 1.0f);
}

// ---------------- feature embedding stage 1: h = x@fe_w1 + b ----------------
__global__ void k_fe1(const float* __restrict__ x, const float* __restrict__ w,
                      const float* __restrict__ b, float* __restrict__ h, int N) {
    int idx = blockIdx.x * 256 + threadIdx.x;
    if (idx >= N * 64) return;
    int n = idx >> 6, c = idx & 63;
    const float* xr = x + (size_t)n * 28;
    float acc = b[c];
    #pragma unroll
    for (int k = 0; k < 28; k++) acc = fmaf(xr[k], w[k * 64 + c], acc);
    h[idx] = acc;
}

// ---------------- BN stats: per-channel sum / sumsq ----------------
__global__ void k_bnstat(const float* __restrict__ h, float* __restrict__ stats, int N) {
    __shared__ float s_s[256], s_q[256];
    int tid = threadIdx.x;
    int c = tid & 63, g = tid >> 6;
    float s = 0.f, q = 0.f;
    for (int n = blockIdx.x * 4 + g; n < N; n += gridDim.x * 4) {
        float v = h[(size_t)n * 64 + c];
        s += v; q += v * v;
    }
    s_s[tid] = s; s_q[tid] = q;
    __syncthreads();
    if (tid < 64) {
        s = s_s[tid] + s_s[tid + 64] + s_s[tid + 128] + s_s[tid + 192];
        q = s_q[tid] + s_q[tid + 64] + s_q[tid + 128] + s_q[tid + 192];
        atomicAdd(&stats[tid], s);
        atomicAdd(&stats[64 + tid], q);
    }
}

__global__ void k_bnfin(const float* __restrict__ stats, float* __restrict__ prm,
                        const float* __restrict__ gamma, const float* __restrict__ beta,
                        float invN) {
    int c = threadIdx.x;  // 64 threads
    float mu = stats[c] * invN;
    float var = stats[64 + c] * invN - mu * mu;
    float sc = gamma[c] * rsqrtf(var + 1e-5f);
    prm[c] = sc;
    prm[64 + c] = beta[c] - mu * sc;
}

// ---------------- feature embedding stage 2: v = relu(relu(bn(h)) @ fe_w2 + b) ----------------
__global__ void k_fe2(const float* __restrict__ h, const float* __restrict__ prm,
                      const float* __restrict__ w, const float* __restrict__ b,
                      float* __restrict__ v, int N) {
    int idx = blockIdx.x * 256 + threadIdx.x;
    if (idx >= N * 128) return;
    int n = idx >> 7, c = idx & 127;
    const float* hr = h + ((size_t)n << 6);
    float acc = b[c];
    #pragma unroll 8
    for (int k = 0; k < 64; k++) {
        float hv = fmaxf(fmaf(hr[k], prm[k], prm[64 + k]), 0.f);
        acc = fmaf(hv, w[(k << 7) + c], acc);
    }
    v[idx] = fmaxf(acc, 0.f);
}

// ---------------- generic [N,128]x[128,128] GEMM, optional ssp / residual ----------------
__global__ void k_gemm128(const float* __restrict__ A, const float* __restrict__ W,
                          const float* __restrict__ b, const float* __restrict__ resid,
                          float* __restrict__ C, int N, int act) {
    int idx = blockIdx.x * 256 + threadIdx.x;
    if (idx >= N * 128) return;
    int n = idx >> 7, c = idx & 127;
    const float* ar = A + ((size_t)n << 7);
    float acc = b ? b[c] : 0.f;
    #pragma unroll 8
    for (int k = 0; k < 128; k++) acc = fmaf(ar[k], W[(k << 7) + c], acc);
    if (act) acc = sspf(acc);
    if (resid) acc += resid[idx];
    C[idx] = acc;
}

// ---------------- edge kernel: per-edge MLP gate + gather + scatter-add ----------------
__launch_bounds__(256, 2)
__global__ void k_edge(const int* __restrict__ ei, const float* __restrict__ dist,
                       const float* __restrict__ cosC, const float* __restrict__ vlin,
                       const float* __restrict__ w1, const float* __restrict__ b1,
                       const float* __restrict__ w2, const float* __restrict__ b2,
                       float* __restrict__ agg, int E) {
    __shared__ float s_w1[NGAUSS][128];   // 25.6 KB
    __shared__ float s_demb[64][NGAUSS];  // 12.8 KB
    __shared__ float s_t1[64][128];       // 32 KB
    const int tid = threadIdx.x;
    const int e0 = blockIdx.x * 64;

    for (int i = tid; i < NGAUSS * 128; i += 256) s_w1[0][i] = w1[i];
    for (int i = tid; i < 64 * NGAUSS; i += 256) {
        int r = i / NGAUSS, k = i - r * NGAUSS;
        int e = e0 + r;
        float d = (e < E) ? dist[e] : 1e9f;
        float t = d - k * STEP;
        s_demb[r][k] = __expf(COEFF * t * t);
    }
    __syncthreads();

    const int cg = tid & 31, rg = tid >> 5;
    const int r0 = rg << 3;
    const int c4 = cg << 2;

    // GEMM1: t1 = ssp(demb @ w1 + b1)   [64,50]x[50,128]
    float4 acc[8];
    #pragma unroll
    for (int i = 0; i < 8; i++) acc[i] = make_float4(0.f, 0.f, 0.f, 0.f);
    #pragma unroll 2
    for (int k = 0; k < NGAUSS; k++) {
        float4 wv = *(const float4*)&s_w1[k][c4];
        #pragma unroll
        for (int i = 0; i < 8; i++) {
            float dv = s_demb[r0 + i][k];
            acc[i].x = fmaf(dv, wv.x, acc[i].x);
            acc[i].y = fmaf(dv, wv.y, acc[i].y);
            acc[i].z = fmaf(dv, wv.z, acc[i].z);
            acc[i].w = fmaf(dv, wv.w, acc[i].w);
        }
    }
    float4 b1v = *(const float4*)&b1[c4];
    #pragma unroll
    for (int i = 0; i < 8; i++) {
        float4 t;
        t.x = sspf(acc[i].x + b1v.x);
        t.y = sspf(acc[i].y + b1v.y);
        t.z = sspf(acc[i].z + b1v.z);
        t.w = sspf(acc[i].w + b1v.w);
        *(float4*)&s_t1[r0 + i][c4] = t;
    }
    __syncthreads();

    // GEMM2: W = t1 @ w2 + b2   [64,128]x[128,128], w2 from L2
    float4 a2[8];
    #pragma unroll
    for (int i = 0; i < 8; i++) a2[i] = make_float4(0.f, 0.f, 0.f, 0.f);
    #pragma unroll 4
    for (int k = 0; k < 128; k++) {
        float4 wv = *(const float4*)&w2[(k << 7) + c4];
        #pragma unroll
        for (int i = 0; i < 8; i++) {
            float tv = s_t1[r0 + i][k];
            a2[i].x = fmaf(tv, wv.x, a2[i].x);
            a2[i].y = fmaf(tv, wv.y, a2[i].y);
            a2[i].z = fmaf(tv, wv.z, a2[i].z);
            a2[i].w = fmaf(tv, wv.w, a2[i].w);
        }
    }
    float4 b2v = *(const float4*)&b2[c4];
    #pragma unroll
    for (int i = 0; i < 8; i++) {
        int e = e0 + r0 + i;
        if (e >= E) continue;
        int src = ei[e], dst = ei[E + e];
        float cc = cosC[e];
        const float4 vl = *(const float4*)&vlin[((size_t)src << 7) + c4];
        float* ap = &agg[((size_t)dst << 7) + c4];
        atomicAdd(ap + 0, (a2[i].x + b2v.x) * cc * vl.x);
        atomicAdd(ap + 1, (a2[i].y + b2v.y) * cc * vl.y);
        atomicAdd(ap + 2, (a2[i].z + b2v.z) * cc * vl.z);
        atomicAdd(ap + 3, (a2[i].w + b2v.w) * cc * vl.w);
    }
}

// ---------------- readout ----------------
__global__ void k_u1(const float* __restrict__ v, const float* __restrict__ w,
                     const float* __restrict__ b, float* __restrict__ t, int N) {
    int idx = blockIdx.x * 256 + threadIdx.x;
    if (idx >= N * 64) return;
    int n = idx >> 6, c = idx & 63;
    const float* vr = v + ((size_t)n << 7);
    float acc = b[c];
    #pragma unroll 8
    for (int k = 0; k < 128; k++) acc = fmaf(vr[k], w[(k << 6) + c], acc);
    t[idx] = sspf(acc);
}

__global__ void k_u2(const float* __restrict__ t, const float* __restrict__ w,
                     const float* __restrict__ b, const int* __restrict__ batch,
                     float* __restrict__ out, int N) {
    int idx = blockIdx.x * 256 + threadIdx.x;
    if (idx >= N * 32) return;
    int n = idx >> 5, c = idx & 31;
    const float* tr = t + ((size_t)n << 6);
    float acc = b[c];
    #pragma unroll
    for (int k = 0; k < 64; k++) acc = fmaf(tr[k], w[(k << 5) + c], acc);
    atomicAdd(&out[(size_t)batch[n] * 32 + c], acc);
}

extern "C" void kernel_launch(void* const* d_in, const int* in_sizes, int n_in,
                              void* d_out, int out_size, void* d_ws, size_t ws_size,
                              hipStream_t stream) {
    const float* x      = (const float*)d_in[0];
    const float* pos    = (const float*)d_in[1];
    const int*   batch  = (const int*)d_in[2];
    const int*   ei     = (const int*)d_in[3];
    const float* fe_w1  = (const float*)d_in[4];
    const float* fe_b1  = (const float*)d_in[5];
    const float* bn_g   = (const float*)d_in[6];
    const float* bn_b   = (const float*)d_in[7];
    const float* fe_w2  = (const float*)d_in[8];
    const float* fe_b2  = (const float*)d_in[9];
    const float* lin_w  = (const float*)d_in[10];
    const float* mlp_w1 = (const float*)d_in[11];
    const float* mlp_b1 = (const float*)d_in[12];
    const float* mlp_w2 = (const float*)d_in[13];
    const float* mlp_b2 = (const float*)d_in[14];
    const float* v1_w   = (const float*)d_in[15];
    const float* v1_b   = (const float*)d_in[16];
    const float* v2_w   = (const float*)d_in[17];
    const float* v2_b   = (const float*)d_in[18];
    const float* u1_w   = (const float*)d_in[19];
    const float* u1_b   = (const float*)d_in[20];
    const float* u2_w   = (const float*)d_in[21];
    const float* u2_b   = (const float*)d_in[22];

    const int N = in_sizes[0] / 28;
    const int E = in_sizes[3] / 2;

    float* ws = (float*)d_ws;
    size_t o = 0;
    float* dist  = ws + o; o += (size_t)E;
    float* cosC  = ws + o; o += (size_t)E;
    float* h     = ws + o; o += (size_t)N * 64;
    float* stats = ws + o; o += 128;
    float* prm   = ws + o; o += 128;
    float* v     = ws + o; o += (size_t)N * 128;
    float* vlin  = ws + o; o += (size_t)N * 128;
    float* agg   = ws + o; o += (size_t)N * 128;
    float* tmp   = ws + o; o += (size_t)N * 128;

    hipMemsetAsync(stats, 0, 128 * sizeof(float), stream);
    k_geom<<<(E + 255) / 256, 256, 0, stream>>>(ei, pos, dist, cosC, E);
    k_fe1<<<(N * 64 + 255) / 256, 256, 0, stream>>>(x, fe_w1, fe_b1, h, N);
    k_bnstat<<<256, 256, 0, stream>>>(h, stats, N);
    k_bnfin<<<1, 64, 0, stream>>>(stats, prm, bn_g, bn_b, 1.0f / (float)N);
    k_fe2<<<(N * 128 + 255) / 256, 256, 0, stream>>>(h, prm, fe_w2, fe_b2, v, N);

    for (int l = 0; l < LAY; l++) {
        k_gemm128<<<(N * 128 + 255) / 256, 256, 0, stream>>>(
            v, lin_w + (size_t)l * 128 * 128, nullptr, nullptr, vlin, N, 0);
        hipMemsetAsync(agg, 0, (size_t)N * 128 * sizeof(float), stream);
        k_edge<<<(E + 63) / 64, 256, 0, stream>>>(
            ei, dist, cosC, vlin,
            mlp_w1 + (size_t)l * NGAUSS * 128, mlp_b1 + (size_t)l * 128,
            mlp_w2 + (size_t)l * 128 * 128, mlp_b2 + (size_t)l * 128, agg, E);
        k_gemm128<<<(N * 128 + 255) / 256, 256, 0, stream>>>(
            agg, v1_w + (size_t)l * 128 * 128, v1_b + (size_t)l * 128, nullptr, tmp, N, 1);
        k_gemm128<<<(N * 128 + 255) / 256, 256, 0, stream>>>(
            tmp, v2_w + (size_t)l * 128 * 128, v2_b + (size_t)l * 128, v, v, N, 0);
    }

    k_u1<<<(N * 64 + 255) / 256, 256, 0, stream>>>(v, u1_w, u1_b, tmp, N);
    hipMemsetAsync(d_out, 0, (size_t)out_size * sizeof(float), stream);
    k_u2<<<(N * 32 + 255) / 256, 256, 0, stream>>>(tmp, u2_w, u2_b, batch, (float*)d_out, N);
}

// Round 2
// 5999.190 us; speedup vs baseline: 2.0017x; 2.0017x over previous
//
#include <hip/hip_runtime.h>
#include <math.h>

#define DEV __device__ __forceinline__

constexpr int NGAUSS = 50;
constexpr int LAY = 6;
constexpr float STEP = 6.0f / 49.0f;
constexpr float COEFF = -0.5f / (STEP * STEP);
constexpr float LN2F = 0.69314718055994531f;
constexpr float PI_OVER_CUT = 0.52359877559829887f;  // pi/6

DEV float sspf(float x) {
    // softplus(x) - ln2, numerically stable, fast log/exp
    float ax = fabsf(x);
    float e = __expf(-ax);
    return fmaxf(x, 0.f) + __logf(1.f + e) - LN2F;
}

// ---------------- edge sort pre-pass (once per call) ----------------
__global__ void k_hist(const int* __restrict__ ei, int* __restrict__ counts, int E) {
    int e = blockIdx.x * 256 + threadIdx.x;
    if (e < E) atomicAdd(&counts[ei[E + e]], 1);
}

// exclusive scan of counts[n] -> cursor[n], single block of 1024
__global__ void k_scan(const int* __restrict__ counts, int* __restrict__ cursor, int n) {
    __shared__ int s[1024];
    __shared__ int carry;
    if (threadIdx.x == 0) carry = 0;
    __syncthreads();
    for (int base = 0; base < n; base += 1024) {
        int i = base + threadIdx.x;
        int v = (i < n) ? counts[i] : 0;
        s[threadIdx.x] = v;
        __syncthreads();
        for (int off = 1; off < 1024; off <<= 1) {
            int t = (threadIdx.x >= off) ? s[threadIdx.x - off] : 0;
            __syncthreads();
            s[threadIdx.x] += t;
            __syncthreads();
        }
        if (i < n) cursor[i] = carry + s[threadIdx.x] - v;
        __syncthreads();
        if (threadIdx.x == 1023) carry += s[1023];
        __syncthreads();
    }
}

// scatter edges into dst-sorted slots; fuse geometry (dist, cosine cutoff)
__global__ void k_scatter(const int* __restrict__ ei, const float* __restrict__ pos,
                          int* __restrict__ cursor, int* __restrict__ s_src,
                          int* __restrict__ s_dst, float* __restrict__ s_dist,
                          float* __restrict__ s_cos, int E) {
    int e = blockIdx.x * 256 + threadIdx.x;
    if (e >= E) return;
    int r = ei[e], c = ei[E + e];
    int p = atomicAdd(&cursor[c], 1);
    float dx = pos[3 * r + 0] - pos[3 * c + 0];
    float dy = pos[3 * r + 1] - pos[3 * c + 1];
    float dz = pos[3 * r + 2] - pos[3 * c + 2];
    float d = sqrtf(dx * dx + dy * dy + dz * dz);
    s_src[p] = r;
    s_dst[p] = c;
    s_dist[p] = d;
    s_cos[p] = 0.5f * (__cosf(d * PI_OVER_CUT) + 1.0f);
}

// ---------------- feature embedding stage 1: h = x@fe_w1 + b ----------------
__global__ void k_fe1(const float* __restrict__ x, const float* __restrict__ w,
                      const float* __restrict__ b, float* __restrict__ h, int N) {
    int idx = blockIdx.x * 256 + threadIdx.x;
    if (idx >= N * 64) return;
    int n = idx >> 6, c = idx & 63;
    const float* xr = x + (size_t)n * 28;
    float acc = b[c];
    #pragma unroll
    for (int k = 0; k < 28; k++) acc = fmaf(xr[k], w[k * 64 + c], acc);
    h[idx] = acc;
}

// ---------------- BN stats ----------------
__global__ void k_bnstat(const float* __restrict__ h, float* __restrict__ stats, int N) {
    __shared__ float s_s[256], s_q[256];
    int tid = threadIdx.x;
    int c = tid & 63, g = tid >> 6;
    float s = 0.f, q = 0.f;
    for (int n = blockIdx.x * 4 + g; n < N; n += gridDim.x * 4) {
        float v = h[(size_t)n * 64 + c];
        s += v; q += v * v;
    }
    s_s[tid] = s; s_q[tid] = q;
    __syncthreads();
    if (tid < 64) {
        s = s_s[tid] + s_s[tid + 64] + s_s[tid + 128] + s_s[tid + 192];
        q = s_q[tid] + s_q[tid + 64] + s_q[tid + 128] + s_q[tid + 192];
        atomicAdd(&stats[tid], s);
        atomicAdd(&stats[64 + tid], q);
    }
}

__global__ void k_bnfin(const float* __restrict__ stats, float* __restrict__ prm,
                        const float* __restrict__ gamma, const float* __restrict__ beta,
                        float invN) {
    int c = threadIdx.x;  // 64 threads
    float mu = stats[c] * invN;
    float var = stats[64 + c] * invN - mu * mu;
    float sc = gamma[c] * rsqrtf(var + 1e-5f);
    prm[c] = sc;
    prm[64 + c] = beta[c] - mu * sc;
}

// ---------------- feature embedding stage 2 ----------------
__global__ void k_fe2(const float* __restrict__ h, const float* __restrict__ prm,
                      const float* __restrict__ w, const float* __restrict__ b,
                      float* __restrict__ v, int N) {
    int idx = blockIdx.x * 256 + threadIdx.x;
    if (idx >= N * 128) return;
    int n = idx >> 7, c = idx & 127;
    const float* hr = h + ((size_t)n << 6);
    float acc = b[c];
    #pragma unroll 8
    for (int k = 0; k < 64; k++) {
        float hv = fmaxf(fmaf(hr[k], prm[k], prm[64 + k]), 0.f);
        acc = fmaf(hv, w[(k << 7) + c], acc);
    }
    v[idx] = fmaxf(acc, 0.f);
}

// ---------------- [N,128]x[128,128] GEMM, float4 per thread ----------------
__global__ void k_gemm128(const float* __restrict__ A, const float* __restrict__ W,
                          const float* __restrict__ b, const float* __restrict__ resid,
                          float* __restrict__ C, int N, int act) {
    int idx = blockIdx.x * 256 + threadIdx.x;
    if (idx >= N * 32) return;
    int n = idx >> 5, c4 = (idx & 31) << 2;
    const float* ar = A + ((size_t)n << 7);
    float4 acc = b ? *(const float4*)&b[c4] : make_float4(0.f, 0.f, 0.f, 0.f);
    #pragma unroll 4
    for (int k = 0; k < 128; k++) {
        float a = ar[k];
        float4 w4 = *(const float4*)&W[(k << 7) + c4];
        acc.x = fmaf(a, w4.x, acc.x);
        acc.y = fmaf(a, w4.y, acc.y);
        acc.z = fmaf(a, w4.z, acc.z);
        acc.w = fmaf(a, w4.w, acc.w);
    }
    if (act) { acc.x = sspf(acc.x); acc.y = sspf(acc.y); acc.z = sspf(acc.z); acc.w = sspf(acc.w); }
    if (resid) {
        float4 rv = *(const float4*)&resid[((size_t)n << 7) + c4];
        acc.x += rv.x; acc.y += rv.y; acc.z += rv.z; acc.w += rv.w;
    }
    *(float4*)&C[((size_t)n << 7) + c4] = acc;
}

// ---------------- edge kernel: sorted edges, segmented atomic flush ----------------
__launch_bounds__(256, 3)
__global__ void k_edge(const int* __restrict__ s_src, const int* __restrict__ s_dst,
                       const float* __restrict__ s_distA, const float* __restrict__ s_cosA,
                       const float* __restrict__ vlin,
                       const float* __restrict__ w1, const float* __restrict__ b1,
                       const float* __restrict__ w2, const float* __restrict__ b2,
                       float* __restrict__ agg, int E) {
    __shared__ float s_demb[64][NGAUSS];  // 12.8 KB
    __shared__ float s_t1[64][128];       // 32 KB
    const int tid = threadIdx.x;
    const int e0 = blockIdx.x * 64;

    for (int i = tid; i < 64 * NGAUSS; i += 256) {
        int r = i / NGAUSS, k = i - r * NGAUSS;
        int e = e0 + r;
        float d = (e < E) ? s_distA[e] : 1e9f;
        float t = d - k * STEP;
        s_demb[r][k] = __expf(COEFF * t * t);
    }
    __syncthreads();

    const int cg = tid & 31, rg = tid >> 5;
    const int r0 = rg << 3;
    const int c4 = cg << 2;

    // GEMM1: t1 = ssp(demb @ w1 + b1)   [64,50]x[50,128]; w1 via L1 (25.6KB)
    float4 b1v = *(const float4*)&b1[c4];
    float4 acc[8];
    #pragma unroll
    for (int i = 0; i < 8; i++) acc[i] = b1v;
    #pragma unroll 2
    for (int k = 0; k < NGAUSS; k++) {
        float4 wv = *(const float4*)&w1[(k << 7) + c4];
        #pragma unroll
        for (int i = 0; i < 8; i++) {
            float dv = s_demb[r0 + i][k];
            acc[i].x = fmaf(dv, wv.x, acc[i].x);
            acc[i].y = fmaf(dv, wv.y, acc[i].y);
            acc[i].z = fmaf(dv, wv.z, acc[i].z);
            acc[i].w = fmaf(dv, wv.w, acc[i].w);
        }
    }
    #pragma unroll
    for (int i = 0; i < 8; i++) {
        float4 t;
        t.x = sspf(acc[i].x);
        t.y = sspf(acc[i].y);
        t.z = sspf(acc[i].z);
        t.w = sspf(acc[i].w);
        *(float4*)&s_t1[r0 + i][c4] = t;
    }
    __syncthreads();

    // GEMM2: W = t1 @ w2 + b2   [64,128]x[128,128], w2 streamed from L2
    float4 b2v = *(const float4*)&b2[c4];
    float4 a2[8];
    #pragma unroll
    for (int i = 0; i < 8; i++) a2[i] = b2v;
    #pragma unroll 4
    for (int k = 0; k < 128; k++) {
        float4 wv = *(const float4*)&w2[(k << 7) + c4];
        #pragma unroll
        for (int i = 0; i < 8; i++) {
            float tv = s_t1[r0 + i][k];
            a2[i].x = fmaf(tv, wv.x, a2[i].x);
            a2[i].y = fmaf(tv, wv.y, a2[i].y);
            a2[i].z = fmaf(tv, wv.z, a2[i].z);
            a2[i].w = fmaf(tv, wv.w, a2[i].w);
        }
    }

    // epilogue: gather vlin[src], apply cosC, per-thread segmented atomic flush
    float4 run = make_float4(0.f, 0.f, 0.f, 0.f);
    int cur = -1;
    #pragma unroll
    for (int i = 0; i < 8; i++) {
        int e = e0 + r0 + i;
        int dst = (e < E) ? s_dst[e] : -1;
        float4 contrib = make_float4(0.f, 0.f, 0.f, 0.f);
        if (e < E) {
            float cc = s_cosA[e];
            int src = s_src[e];
            const float4 vl = *(const float4*)&vlin[((size_t)src << 7) + c4];
            contrib.x = a2[i].x * cc * vl.x;
            contrib.y = a2[i].y * cc * vl.y;
            contrib.z = a2[i].z * cc * vl.z;
            contrib.w = a2[i].w * cc * vl.w;
        }
        if (dst == cur) {
            run.x += contrib.x; run.y += contrib.y; run.z += contrib.z; run.w += contrib.w;
        } else {
            if (cur >= 0) {
                float* ap = &agg[((size_t)cur << 7) + c4];
                atomicAdd(ap + 0, run.x);
                atomicAdd(ap + 1, run.y);
                atomicAdd(ap + 2, run.z);
                atomicAdd(ap + 3, run.w);
            }
            cur = dst;
            run = contrib;
        }
    }
    if (cur >= 0) {
        float* ap = &agg[((size_t)cur << 7) + c4];
        atomicAdd(ap + 0, run.x);
        atomicAdd(ap + 1, run.y);
        atomicAdd(ap + 2, run.z);
        atomicAdd(ap + 3, run.w);
    }
}

// ---------------- readout ----------------
__global__ void k_u1(const float* __restrict__ v, const float* __restrict__ w,
                     const float* __restrict__ b, float* __restrict__ t, int N) {
    int idx = blockIdx.x * 256 + threadIdx.x;
    if (idx >= N * 16) return;
    int n = idx >> 4, c4 = (idx & 15) << 2;
    const float* vr = v + ((size_t)n << 7);
    float4 acc = *(const float4*)&b[c4];
    #pragma unroll 4
    for (int k = 0; k < 128; k++) {
        float a = vr[k];
        float4 w4 = *(const float4*)&w[(k << 6) + c4];
        acc.x = fmaf(a, w4.x, acc.x);
        acc.y = fmaf(a, w4.y, acc.y);
        acc.z = fmaf(a, w4.z, acc.z);
        acc.w = fmaf(a, w4.w, acc.w);
    }
    float4 t4;
    t4.x = sspf(acc.x); t4.y = sspf(acc.y); t4.z = sspf(acc.z); t4.w = sspf(acc.w);
    *(float4*)&t[((size_t)n << 6) + c4] = t4;
}

__global__ void k_u2(const float* __restrict__ t, const float* __restrict__ w,
                     const float* __restrict__ b, const int* __restrict__ batch,
                     float* __restrict__ out, int N) {
    int idx = blockIdx.x * 256 + threadIdx.x;
    if (idx >= N * 32) return;
    int n = idx >> 5, c = idx & 31;
    const float* tr = t + ((size_t)n << 6);
    float acc = b[c];
    #pragma unroll
    for (int k = 0; k < 64; k++) acc = fmaf(tr[k], w[(k << 5) + c], acc);
    atomicAdd(&out[(size_t)batch[n] * 32 + c], acc);
}

extern "C" void kernel_launch(void* const* d_in, const int* in_sizes, int n_in,
                              void* d_out, int out_size, void* d_ws, size_t ws_size,
                              hipStream_t stream) {
    const float* x      = (const float*)d_in[0];
    const float* pos    = (const float*)d_in[1];
    const int*   batch  = (const int*)d_in[2];
    const int*   ei     = (const int*)d_in[3];
    const float* fe_w1  = (const float*)d_in[4];
    const float* fe_b1  = (const float*)d_in[5];
    const float* bn_g   = (const float*)d_in[6];
    const float* bn_b   = (const float*)d_in[7];
    const float* fe_w2  = (const float*)d_in[8];
    const float* fe_b2  = (const float*)d_in[9];
    const float* lin_w  = (const float*)d_in[10];
    const float* mlp_w1 = (const float*)d_in[11];
    const float* mlp_b1 = (const float*)d_in[12];
    const float* mlp_w2 = (const float*)d_in[13];
    const float* mlp_b2 = (const float*)d_in[14];
    const float* v1_w   = (const float*)d_in[15];
    const float* v1_b   = (const float*)d_in[16];
    const float* v2_w   = (const float*)d_in[17];
    const float* v2_b   = (const float*)d_in[18];
    const float* u1_w   = (const float*)d_in[19];
    const float* u1_b   = (const float*)d_in[20];
    const float* u2_w   = (const float*)d_in[21];
    const float* u2_b   = (const float*)d_in[22];

    const int N = in_sizes[0] / 28;
    const int E = in_sizes[3] / 2;

    char* ws = (char*)d_ws;
    size_t o = 0;
    auto alloc = [&](size_t bytes) { void* p = ws + o; o += (bytes + 255) & ~(size_t)255; return p; };
    int*   counts = (int*)  alloc((size_t)N * 4);
    int*   cursor = (int*)  alloc((size_t)N * 4);
    int*   s_src  = (int*)  alloc((size_t)E * 4);
    int*   s_dst  = (int*)  alloc((size_t)E * 4);
    float* s_dist = (float*)alloc((size_t)E * 4);
    float* s_cos  = (float*)alloc((size_t)E * 4);
    float* stats  = (float*)alloc(128 * 4);
    float* prm    = (float*)alloc(128 * 4);
    float* v      = (float*)alloc((size_t)N * 128 * 4);
    float* vlin   = (float*)alloc((size_t)N * 128 * 4);
    float* agg    = (float*)alloc((size_t)N * 128 * 4);
    float* tmp    = (float*)alloc((size_t)N * 128 * 4);
    float* h      = tmp;  // alias: h only used before the layer loop

    // -------- one-time edge sort (dst-ordered) --------
    hipMemsetAsync(counts, 0, (size_t)N * 4, stream);
    k_hist<<<(E + 255) / 256, 256, 0, stream>>>(ei, counts, E);
    k_scan<<<1, 1024, 0, stream>>>(counts, cursor, N);
    k_scatter<<<(E + 255) / 256, 256, 0, stream>>>(ei, pos, cursor, s_src, s_dst, s_dist, s_cos, E);

    // -------- feature embedding --------
    hipMemsetAsync(stats, 0, 128 * 4, stream);
    k_fe1<<<(N * 64 + 255) / 256, 256, 0, stream>>>(x, fe_w1, fe_b1, h, N);
    k_bnstat<<<256, 256, 0, stream>>>(h, stats, N);
    k_bnfin<<<1, 64, 0, stream>>>(stats, prm, bn_g, bn_b, 1.0f / (float)N);
    k_fe2<<<(N * 128 + 255) / 256, 256, 0, stream>>>(h, prm, fe_w2, fe_b2, v, N);

    // -------- interaction layers --------
    for (int l = 0; l < LAY; l++) {
        k_gemm128<<<(N * 32 + 255) / 256, 256, 0, stream>>>(
            v, lin_w + (size_t)l * 128 * 128, nullptr, nullptr, vlin, N, 0);
        hipMemsetAsync(agg, 0, (size_t)N * 128 * 4, stream);
        k_edge<<<(E + 63) / 64, 256, 0, stream>>>(
            s_src, s_dst, s_dist, s_cos, vlin,
            mlp_w1 + (size_t)l * NGAUSS * 128, mlp_b1 + (size_t)l * 128,
            mlp_w2 + (size_t)l * 128 * 128, mlp_b2 + (size_t)l * 128, agg, E);
        k_gemm128<<<(N * 32 + 255) / 256, 256, 0, stream>>>(
            agg, v1_w + (size_t)l * 128 * 128, v1_b + (size_t)l * 128, nullptr, tmp, N, 1);
        k_gemm128<<<(N * 32 + 255) / 256, 256, 0, stream>>>(
            tmp, v2_w + (size_t)l * 128 * 128, v2_b + (size_t)l * 128, v, v, N, 0);
    }

    // -------- readout --------
    k_u1<<<(N * 16 + 255) / 256, 256, 0, stream>>>(v, u1_w, u1_b, tmp, N);
    hipMemsetAsync(d_out, 0, (size_t)out_size * 4, stream);
    k_u2<<<(N * 32 + 255) / 256, 256, 0, stream>>>(tmp, u2_w, u2_b, batch, (float*)d_out, N);
}

// Round 3
// 3445.732 us; speedup vs baseline: 3.4851x; 1.7410x over previous
//
#include <hip/hip_runtime.h>
#include <math.h>

#define DEV __device__ __forceinline__

constexpr int NGAUSS = 50;
constexpr int LAY = 6;
constexpr int K_TAB = 8192;
constexpr float DMAX = 40.0f;
constexpr float TSCALE = (float)(K_TAB - 1) / DMAX;   // fid = d * TSCALE
constexpr float STEP = 6.0f / 49.0f;
constexpr float COEFF = -0.5f / (STEP * STEP);
constexpr float LN2F = 0.69314718055994531f;
constexpr float PI_OVER_CUT = 0.52359877559829887f;  // pi/6

DEV float sspf(float x) {
    float ax = fabsf(x);
    float e = __expf(-ax);
    return fmaxf(x, 0.f) + __logf(1.f + e) - LN2F;
}

// ---------------- edge sort pre-pass (once per call) ----------------
__global__ void k_hist(const int* __restrict__ ei, int* __restrict__ counts, int E) {
    int e = blockIdx.x * 256 + threadIdx.x;
    if (e < E) atomicAdd(&counts[ei[E + e]], 1);
}

// exclusive scan, single block 1024 threads, shuffle-based
__global__ void k_scan(const int* __restrict__ counts, int* __restrict__ cursor, int n) {
    __shared__ int s_wsum[16];
    __shared__ int s_carry;
    if (threadIdx.x == 0) s_carry = 0;
    __syncthreads();
    const int lane = threadIdx.x & 63, wv = threadIdx.x >> 6;
    for (int base = 0; base < n; base += 1024) {
        int i = base + threadIdx.x;
        int v = (i < n) ? counts[i] : 0;
        int x = v;
        #pragma unroll
        for (int off = 1; off < 64; off <<= 1) {
            int y = __shfl_up(x, off, 64);
            if (lane >= off) x += y;
        }
        if (lane == 63) s_wsum[wv] = x;
        __syncthreads();
        if (wv == 0 && lane < 16) {
            int wval = s_wsum[lane];
            int wx = wval;
            #pragma unroll
            for (int off = 1; off < 16; off <<= 1) {
                int wy = __shfl_up(wx, off, 16);
                if (lane >= off) wx += wy;
            }
            s_wsum[lane] = wx - wval;  // exclusive wave prefix
        }
        __syncthreads();
        if (i < n) cursor[i] = s_carry + s_wsum[wv] + x - v;
        __syncthreads();
        if (threadIdx.x == 1023) s_carry += s_wsum[15] + x;
        __syncthreads();
    }
}

// scatter edges into dst-sorted slots; fuse geometry -> table coordinate fid
__global__ void k_scatter(const int* __restrict__ ei, const float* __restrict__ pos,
                          int* __restrict__ cursor, int* __restrict__ s_src,
                          int* __restrict__ s_dst, float* __restrict__ s_fid, int E) {
    int e = blockIdx.x * 256 + threadIdx.x;
    if (e >= E) return;
    int r = ei[e], c = ei[E + e];
    int p = atomicAdd(&cursor[c], 1);
    float dx = pos[3 * r + 0] - pos[3 * c + 0];
    float dy = pos[3 * r + 1] - pos[3 * c + 1];
    float dz = pos[3 * r + 2] - pos[3 * c + 2];
    float d = sqrtf(dx * dx + dy * dy + dz * dz);
    s_src[p] = r;
    s_dst[p] = c;
    s_fid[p] = fminf(d * TSCALE, (float)(K_TAB - 2) + 0.999f);
}

// ---------------- gate table build: T[k][c] = W_gate(d_k)  [one layer/launch] ----------------
// 32 knots per block, 256 threads: 8 row-groups x 32 channel-groups
__launch_bounds__(256)
__global__ void k_tab(const float* __restrict__ w1, const float* __restrict__ b1,
                      const float* __restrict__ w2, const float* __restrict__ b2,
                      float* __restrict__ tab) {
    __shared__ float s_demb[32][NGAUSS];  // 6.4 KB
    __shared__ float s_t1[32][128];       // 16 KB
    const int tid = threadIdx.x;
    const int k0 = blockIdx.x * 32;

    for (int i = tid; i < 32 * NGAUSS; i += 256) {
        int r = i / NGAUSS, g = i - r * NGAUSS;
        float d = (float)(k0 + r) * (1.0f / TSCALE);
        float t = d - g * STEP;
        s_demb[r][g] = __expf(COEFF * t * t);
    }
    __syncthreads();

    const int cg = tid & 31, rg = tid >> 5;
    const int r0 = rg << 2;        // 4 rows per thread
    const int c4 = cg << 2;

    // GEMM1: t1 = ssp(demb @ w1 + b1)
    float4 b1v = *(const float4*)&b1[c4];
    float4 acc[4];
    #pragma unroll
    for (int i = 0; i < 4; i++) acc[i] = b1v;
    #pragma unroll 2
    for (int k = 0; k < NGAUSS; k++) {
        float4 wv = *(const float4*)&w1[(k << 7) + c4];
        #pragma unroll
        for (int i = 0; i < 4; i++) {
            float dv = s_demb[r0 + i][k];
            acc[i].x = fmaf(dv, wv.x, acc[i].x);
            acc[i].y = fmaf(dv, wv.y, acc[i].y);
            acc[i].z = fmaf(dv, wv.z, acc[i].z);
            acc[i].w = fmaf(dv, wv.w, acc[i].w);
        }
    }
    #pragma unroll
    for (int i = 0; i < 4; i++) {
        float4 t;
        t.x = sspf(acc[i].x); t.y = sspf(acc[i].y);
        t.z = sspf(acc[i].z); t.w = sspf(acc[i].w);
        *(float4*)&s_t1[r0 + i][c4] = t;
    }
    __syncthreads();

    // GEMM2: W = t1 @ w2 + b2, then x cosC
    float4 b2v = *(const float4*)&b2[c4];
    float4 a2[4];
    #pragma unroll
    for (int i = 0; i < 4; i++) a2[i] = b2v;
    #pragma unroll 4
    for (int k = 0; k < 128; k++) {
        float4 wv = *(const float4*)&w2[(k << 7) + c4];
        #pragma unroll
        for (int i = 0; i < 4; i++) {
            float tv = s_t1[r0 + i][k];
            a2[i].x = fmaf(tv, wv.x, a2[i].x);
            a2[i].y = fmaf(tv, wv.y, a2[i].y);
            a2[i].z = fmaf(tv, wv.z, a2[i].z);
            a2[i].w = fmaf(tv, wv.w, a2[i].w);
        }
    }
    #pragma unroll
    for (int i = 0; i < 4; i++) {
        int knot = k0 + r0 + i;
        float d = (float)knot * (1.0f / TSCALE);
        float cc = 0.5f * (__cosf(d * PI_OVER_CUT) + 1.0f);
        float4 o;
        o.x = a2[i].x * cc; o.y = a2[i].y * cc;
        o.z = a2[i].z * cc; o.w = a2[i].w * cc;
        *(float4*)&tab[((size_t)knot << 7) + c4] = o;
    }
}

// ---------------- edge kernel: table lerp + gather + segmented scatter ----------------
__launch_bounds__(256)
__global__ void k_edge_tab(const int* __restrict__ s_src, const int* __restrict__ s_dst,
                           const float* __restrict__ s_fid, const float* __restrict__ vlin,
                           const float* __restrict__ tab, float* __restrict__ agg, int E) {
    __shared__ int sh_src[256];
    __shared__ int sh_dst[256];
    __shared__ float sh_fid[256];
    const int tid = threadIdx.x;
    const int e0 = blockIdx.x * 256;
    {
        int e = e0 + tid;
        bool ok = e < E;
        sh_src[tid] = ok ? s_src[e] : 0;
        sh_dst[tid] = ok ? s_dst[e] : -1;
        sh_fid[tid] = ok ? s_fid[e] : 0.f;
    }
    __syncthreads();

    const int c4 = (tid & 31) << 2;
    const int base = (tid >> 5) << 5;  // this thread's 32-edge span

    float4 run = make_float4(0.f, 0.f, 0.f, 0.f);
    int cur = -1;
    for (int i = 0; i < 32; i++) {
        int idx = base + i;
        int dst = sh_dst[idx];
        if (dst != cur) {
            if (cur >= 0) {
                float* ap = &agg[((size_t)cur << 7) + c4];
                atomicAdd(ap + 0, run.x);
                atomicAdd(ap + 1, run.y);
                atomicAdd(ap + 2, run.z);
                atomicAdd(ap + 3, run.w);
            }
            cur = dst;
            run = make_float4(0.f, 0.f, 0.f, 0.f);
        }
        if (dst >= 0) {
            float fid = sh_fid[idx];
            int i0 = (int)fid;
            float fr = fid - (float)i0;
            const float* tp = &tab[((size_t)i0 << 7) + c4];
            float4 t0 = *(const float4*)tp;
            float4 t1 = *(const float4*)(tp + 128);
            float4 vl = *(const float4*)&vlin[((size_t)sh_src[idx] << 7) + c4];
            float4 w;
            w.x = fmaf(fr, t1.x - t0.x, t0.x);
            w.y = fmaf(fr, t1.y - t0.y, t0.y);
            w.z = fmaf(fr, t1.z - t0.z, t0.z);
            w.w = fmaf(fr, t1.w - t0.w, t0.w);
            run.x = fmaf(w.x, vl.x, run.x);
            run.y = fmaf(w.y, vl.y, run.y);
            run.z = fmaf(w.z, vl.z, run.z);
            run.w = fmaf(w.w, vl.w, run.w);
        }
    }
    if (cur >= 0) {
        float* ap = &agg[((size_t)cur << 7) + c4];
        atomicAdd(ap + 0, run.x);
        atomicAdd(ap + 1, run.y);
        atomicAdd(ap + 2, run.z);
        atomicAdd(ap + 3, run.w);
    }
}

// ---------------- feature embedding ----------------
__global__ void k_fe1(const float* __restrict__ x, const float* __restrict__ w,
                      const float* __restrict__ b, float* __restrict__ h, int N) {
    int idx = blockIdx.x * 256 + threadIdx.x;
    if (idx >= N * 64) return;
    int n = idx >> 6, c = idx & 63;
    const float* xr = x + (size_t)n * 28;
    float acc = b[c];
    #pragma unroll
    for (int k = 0; k < 28; k++) acc = fmaf(xr[k], w[k * 64 + c], acc);
    h[idx] = acc;
}

__global__ void k_bnstat(const float* __restrict__ h, float* __restrict__ stats, int N) {
    __shared__ float s_s[256], s_q[256];
    int tid = threadIdx.x;
    int c = tid & 63, g = tid >> 6;
    float s = 0.f, q = 0.f;
    for (int n = blockIdx.x * 4 + g; n < N; n += gridDim.x * 4) {
        float v = h[(size_t)n * 64 + c];
        s += v; q += v * v;
    }
    s_s[tid] = s; s_q[tid] = q;
    __syncthreads();
    if (tid < 64) {
        s = s_s[tid] + s_s[tid + 64] + s_s[tid + 128] + s_s[tid + 192];
        q = s_q[tid] + s_q[tid + 64] + s_q[tid + 128] + s_q[tid + 192];
        atomicAdd(&stats[tid], s);
        atomicAdd(&stats[64 + tid], q);
    }
}

__global__ void k_bnfin(const float* __restrict__ stats, float* __restrict__ prm,
                        const float* __restrict__ gamma, const float* __restrict__ beta,
                        float invN) {
    int c = threadIdx.x;  // 64 threads
    float mu = stats[c] * invN;
    float var = stats[64 + c] * invN - mu * mu;
    float sc = gamma[c] * rsqrtf(var + 1e-5f);
    prm[c] = sc;
    prm[64 + c] = beta[c] - mu * sc;
}

__global__ void k_fe2(const float* __restrict__ h, const float* __restrict__ prm,
                      const float* __restrict__ w, const float* __restrict__ b,
                      float* __restrict__ v, int N) {
    int idx = blockIdx.x * 256 + threadIdx.x;
    if (idx >= N * 128) return;
    int n = idx >> 7, c = idx & 127;
    const float* hr = h + ((size_t)n << 6);
    float acc = b[c];
    #pragma unroll 8
    for (int k = 0; k < 64; k++) {
        float hv = fmaxf(fmaf(hr[k], prm[k], prm[64 + k]), 0.f);
        acc = fmaf(hv, w[(k << 7) + c], acc);
    }
    v[idx] = fmaxf(acc, 0.f);
}

// ---------------- [N,128]x[128,128] GEMM, float4 per thread ----------------
__global__ void k_gemm128(const float* __restrict__ A, const float* __restrict__ W,
                          const float* __restrict__ b, const float* __restrict__ resid,
                          float* __restrict__ C, int N, int act) {
    int idx = blockIdx.x * 256 + threadIdx.x;
    if (idx >= N * 32) return;
    int n = idx >> 5, c4 = (idx & 31) << 2;
    const float* ar = A + ((size_t)n << 7);
    float4 acc = b ? *(const float4*)&b[c4] : make_float4(0.f, 0.f, 0.f, 0.f);
    #pragma unroll 4
    for (int k = 0; k < 128; k++) {
        float a = ar[k];
        float4 w4 = *(const float4*)&W[(k << 7) + c4];
        acc.x = fmaf(a, w4.x, acc.x);
        acc.y = fmaf(a, w4.y, acc.y);
        acc.z = fmaf(a, w4.z, acc.z);
        acc.w = fmaf(a, w4.w, acc.w);
    }
    if (act) { acc.x = sspf(acc.x); acc.y = sspf(acc.y); acc.z = sspf(acc.z); acc.w = sspf(acc.w); }
    if (resid) {
        float4 rv = *(const float4*)&resid[((size_t)n << 7) + c4];
        acc.x += rv.x; acc.y += rv.y; acc.z += rv.z; acc.w += rv.w;
    }
    *(float4*)&C[((size_t)n << 7) + c4] = acc;
}

// ---------------- readout ----------------
__global__ void k_u1(const float* __restrict__ v, const float* __restrict__ w,
                     const float* __restrict__ b, float* __restrict__ t, int N) {
    int idx = blockIdx.x * 256 + threadIdx.x;
    if (idx >= N * 16) return;
    int n = idx >> 4, c4 = (idx & 15) << 2;
    const float* vr = v + ((size_t)n << 7);
    float4 acc = *(const float4*)&b[c4];
    #pragma unroll 4
    for (int k = 0; k < 128; k++) {
        float a = vr[k];
        float4 w4 = *(const float4*)&w[(k << 6) + c4];
        acc.x = fmaf(a, w4.x, acc.x);
        acc.y = fmaf(a, w4.y, acc.y);
        acc.z = fmaf(a, w4.z, acc.z);
        acc.w = fmaf(a, w4.w, acc.w);
    }
    float4 t4;
    t4.x = sspf(acc.x); t4.y = sspf(acc.y); t4.z = sspf(acc.z); t4.w = sspf(acc.w);
    *(float4*)&t[((size_t)n << 6) + c4] = t4;
}

__global__ void k_u2(const float* __restrict__ t, const float* __restrict__ w,
                     const float* __restrict__ b, const int* __restrict__ batch,
                     float* __restrict__ out, int N) {
    int idx = blockIdx.x * 256 + threadIdx.x;
    if (idx >= N * 32) return;
    int n = idx >> 5, c = idx & 31;
    const float* tr = t + ((size_t)n << 6);
    float acc = b[c];
    #pragma unroll
    for (int k = 0; k < 64; k++) acc = fmaf(tr[k], w[(k << 5) + c], acc);
    atomicAdd(&out[(size_t)batch[n] * 32 + c], acc);
}

extern "C" void kernel_launch(void* const* d_in, const int* in_sizes, int n_in,
                              void* d_out, int out_size, void* d_ws, size_t ws_size,
                              hipStream_t stream) {
    const float* x      = (const float*)d_in[0];
    const float* pos    = (const float*)d_in[1];
    const int*   batch  = (const int*)d_in[2];
    const int*   ei     = (const int*)d_in[3];
    const float* fe_w1  = (const float*)d_in[4];
    const float* fe_b1  = (const float*)d_in[5];
    const float* bn_g   = (const float*)d_in[6];
    const float* bn_b   = (const float*)d_in[7];
    const float* fe_w2  = (const float*)d_in[8];
    const float* fe_b2  = (const float*)d_in[9];
    const float* lin_w  = (const float*)d_in[10];
    const float* mlp_w1 = (const float*)d_in[11];
    const float* mlp_b1 = (const float*)d_in[12];
    const float* mlp_w2 = (const float*)d_in[13];
    const float* mlp_b2 = (const float*)d_in[14];
    const float* v1_w   = (const float*)d_in[15];
    const float* v1_b   = (const float*)d_in[16];
    const float* v2_w   = (const float*)d_in[17];
    const float* v2_b   = (const float*)d_in[18];
    const float* u1_w   = (const float*)d_in[19];
    const float* u1_b   = (const float*)d_in[20];
    const float* u2_w   = (const float*)d_in[21];
    const float* u2_b   = (const float*)d_in[22];

    const int N = in_sizes[0] / 28;
    const int E = in_sizes[3] / 2;

    char* ws = (char*)d_ws;
    size_t o = 0;
    auto alloc = [&](size_t bytes) { void* p = ws + o; o += (bytes + 255) & ~(size_t)255; return p; };
    int*   counts = (int*)  alloc((size_t)N * 4);
    int*   cursor = (int*)  alloc((size_t)N * 4);
    int*   s_src  = (int*)  alloc((size_t)E * 4);
    int*   s_dst  = (int*)  alloc((size_t)E * 4);
    float* s_fid  = (float*)alloc((size_t)E * 4);
    float* stats  = (float*)alloc(128 * 4);
    float* prm    = (float*)alloc(128 * 4);
    float* tab    = (float*)alloc((size_t)K_TAB * 128 * 4);
    float* v      = (float*)alloc((size_t)N * 128 * 4);
    float* vlin   = (float*)alloc((size_t)N * 128 * 4);
    float* agg    = (float*)alloc((size_t)N * 128 * 4);
    float* tmp    = (float*)alloc((size_t)N * 128 * 4);
    float* h      = tmp;  // alias: h only used before the layer loop

    // -------- one-time edge sort (dst-ordered) --------
    hipMemsetAsync(counts, 0, (size_t)N * 4, stream);
    k_hist<<<(E + 255) / 256, 256, 0, stream>>>(ei, counts, E);
    k_scan<<<1, 1024, 0, stream>>>(counts, cursor, N);
    k_scatter<<<(E + 255) / 256, 256, 0, stream>>>(ei, pos, cursor, s_src, s_dst, s_fid, E);

    // -------- feature embedding --------
    hipMemsetAsync(stats, 0, 128 * 4, stream);
    k_fe1<<<(N * 64 + 255) / 256, 256, 0, stream>>>(x, fe_w1, fe_b1, h, N);
    k_bnstat<<<256, 256, 0, stream>>>(h, stats, N);
    k_bnfin<<<1, 64, 0, stream>>>(stats, prm, bn_g, bn_b, 1.0f / (float)N);
    k_fe2<<<(N * 128 + 255) / 256, 256, 0, stream>>>(h, prm, fe_w2, fe_b2, v, N);

    // -------- interaction layers --------
    for (int l = 0; l < LAY; l++) {
        k_gemm128<<<(N * 32 + 255) / 256, 256, 0, stream>>>(
            v, lin_w + (size_t)l * 128 * 128, nullptr, nullptr, vlin, N, 0);
        k_tab<<<K_TAB / 32, 256, 0, stream>>>(
            mlp_w1 + (size_t)l * NGAUSS * 128, mlp_b1 + (size_t)l * 128,
            mlp_w2 + (size_t)l * 128 * 128, mlp_b2 + (size_t)l * 128, tab);
        hipMemsetAsync(agg, 0, (size_t)N * 128 * 4, stream);
        k_edge_tab<<<(E + 255) / 256, 256, 0, stream>>>(
            s_src, s_dst, s_fid, vlin, tab, agg, E);
        k_gemm128<<<(N * 32 + 255) / 256, 256, 0, stream>>>(
            agg, v1_w + (size_t)l * 128 * 128, v1_b + (size_t)l * 128, nullptr, tmp, N, 1);
        k_gemm128<<<(N * 32 + 255) / 256, 256, 0, stream>>>(
            tmp, v2_w + (size_t)l * 128 * 128, v2_b + (size_t)l * 128, v, v, N, 0);
    }

    // -------- readout --------
    k_u1<<<(N * 16 + 255) / 256, 256, 0, stream>>>(v, u1_w, u1_b, tmp, N);
    hipMemsetAsync(d_out, 0, (size_t)out_size * 4, stream);
    k_u2<<<(N * 32 + 255) / 256, 256, 0, stream>>>(tmp, u2_w, u2_b, batch, (float*)d_out, N);
}

// Round 4
// 1694.670 us; speedup vs baseline: 7.0861x; 2.0333x over previous
//
#include <hip/hip_runtime.h>
#include <math.h>

#define DEV __device__ __forceinline__

constexpr int NGAUSS = 50;
constexpr int LAY = 6;
constexpr int K_TAB = 8192;
constexpr float DMAX = 40.0f;
constexpr float TSCALE = (float)(K_TAB - 1) / DMAX;   // fid = d * TSCALE
constexpr float STEP = 6.0f / 49.0f;
constexpr float COEFF = -0.5f / (STEP * STEP);
constexpr float LN2F = 0.69314718055994531f;
constexpr float PI_OVER_CUT = 0.52359877559829887f;  // pi/6

DEV float sspf(float x) {
    float ax = fabsf(x);
    float e = __expf(-ax);
    return fmaxf(x, 0.f) + __logf(1.f + e) - LN2F;
}

// ---------------- edge sort pre-pass (once per call) ----------------
__global__ void k_hist(const int* __restrict__ ei, int* __restrict__ counts, int E) {
    int e = blockIdx.x * 256 + threadIdx.x;
    if (e < E) atomicAdd(&counts[ei[E + e]], 1);
}

// exclusive scan, single block 1024 threads, shuffle-based; writes cursor + pristine rowptr
__global__ void k_scan(const int* __restrict__ counts, int* __restrict__ cursor,
                       int* __restrict__ rowptr, int n) {
    __shared__ int s_wsum[16];
    __shared__ int s_carry;
    if (threadIdx.x == 0) s_carry = 0;
    __syncthreads();
    const int lane = threadIdx.x & 63, wv = threadIdx.x >> 6;
    for (int base = 0; base < n; base += 1024) {
        int i = base + threadIdx.x;
        int v = (i < n) ? counts[i] : 0;
        int x = v;
        #pragma unroll
        for (int off = 1; off < 64; off <<= 1) {
            int y = __shfl_up(x, off, 64);
            if (lane >= off) x += y;
        }
        if (lane == 63) s_wsum[wv] = x;
        __syncthreads();
        if (wv == 0 && lane < 16) {
            int wval = s_wsum[lane];
            int wx = wval;
            #pragma unroll
            for (int off = 1; off < 16; off <<= 1) {
                int wy = __shfl_up(wx, off, 16);
                if (lane >= off) wx += wy;
            }
            s_wsum[lane] = wx - wval;  // exclusive wave prefix
        }
        __syncthreads();
        if (i < n) {
            int excl = s_carry + s_wsum[wv] + x - v;
            cursor[i] = excl;
            rowptr[i] = excl;
        }
        __syncthreads();
        if (threadIdx.x == 1023) s_carry += s_wsum[15] + x;
        __syncthreads();
    }
}

// scatter edges into dst-sorted slots; fuse geometry -> table coordinate fid
__global__ void k_scatter(const int* __restrict__ ei, const float* __restrict__ pos,
                          int* __restrict__ cursor, int* __restrict__ s_src,
                          int* __restrict__ s_dst, float* __restrict__ s_fid, int E) {
    int e = blockIdx.x * 256 + threadIdx.x;
    if (e >= E) return;
    int r = ei[e], c = ei[E + e];
    int p = atomicAdd(&cursor[c], 1);
    float dx = pos[3 * r + 0] - pos[3 * c + 0];
    float dy = pos[3 * r + 1] - pos[3 * c + 1];
    float dz = pos[3 * r + 2] - pos[3 * c + 2];
    float d = sqrtf(dx * dx + dy * dy + dz * dz);
    s_src[p] = r;
    s_dst[p] = c;
    s_fid[p] = fminf(d * TSCALE, (float)(K_TAB - 2) + 0.999f);
}

// ---------------- gate table build, ALL layers in one launch ----------------
// grid = LAY*256 blocks; 32 knots per block; 256 threads: 8 row-groups x 32 col-groups
__launch_bounds__(256)
__global__ void k_tab_all(const float* __restrict__ w1A, const float* __restrict__ b1A,
                          const float* __restrict__ w2A, const float* __restrict__ b2A,
                          float* __restrict__ tabA) {
    const int layer = blockIdx.x >> 8;
    const int k0 = (blockIdx.x & 255) * 32;
    const float* w1 = w1A + (size_t)layer * NGAUSS * 128;
    const float* b1 = b1A + (size_t)layer * 128;
    const float* w2 = w2A + (size_t)layer * 128 * 128;
    const float* b2 = b2A + (size_t)layer * 128;
    float* tab = tabA + (size_t)layer * K_TAB * 128;

    __shared__ float s_demb[32][NGAUSS];  // 6.4 KB
    __shared__ float s_t1[32][128];       // 16 KB
    const int tid = threadIdx.x;

    for (int i = tid; i < 32 * NGAUSS; i += 256) {
        int r = i / NGAUSS, g = i - r * NGAUSS;
        float d = (float)(k0 + r) * (1.0f / TSCALE);
        float t = d - g * STEP;
        s_demb[r][g] = __expf(COEFF * t * t);
    }
    __syncthreads();

    const int cg = tid & 31, rg = tid >> 5;
    const int r0 = rg << 2;        // 4 rows per thread
    const int c4 = cg << 2;

    float4 b1v = *(const float4*)&b1[c4];
    float4 acc[4];
    #pragma unroll
    for (int i = 0; i < 4; i++) acc[i] = b1v;
    #pragma unroll 2
    for (int k = 0; k < NGAUSS; k++) {
        float4 wv = *(const float4*)&w1[(k << 7) + c4];
        #pragma unroll
        for (int i = 0; i < 4; i++) {
            float dv = s_demb[r0 + i][k];
            acc[i].x = fmaf(dv, wv.x, acc[i].x);
            acc[i].y = fmaf(dv, wv.y, acc[i].y);
            acc[i].z = fmaf(dv, wv.z, acc[i].z);
            acc[i].w = fmaf(dv, wv.w, acc[i].w);
        }
    }
    #pragma unroll
    for (int i = 0; i < 4; i++) {
        float4 t;
        t.x = sspf(acc[i].x); t.y = sspf(acc[i].y);
        t.z = sspf(acc[i].z); t.w = sspf(acc[i].w);
        *(float4*)&s_t1[r0 + i][c4] = t;
    }
    __syncthreads();

    float4 b2v = *(const float4*)&b2[c4];
    float4 a2[4];
    #pragma unroll
    for (int i = 0; i < 4; i++) a2[i] = b2v;
    #pragma unroll 4
    for (int k = 0; k < 128; k++) {
        float4 wv = *(const float4*)&w2[(k << 7) + c4];
        #pragma unroll
        for (int i = 0; i < 4; i++) {
            float tv = s_t1[r0 + i][k];
            a2[i].x = fmaf(tv, wv.x, a2[i].x);
            a2[i].y = fmaf(tv, wv.y, a2[i].y);
            a2[i].z = fmaf(tv, wv.z, a2[i].z);
            a2[i].w = fmaf(tv, wv.w, a2[i].w);
        }
    }
    #pragma unroll
    for (int i = 0; i < 4; i++) {
        int knot = k0 + r0 + i;
        float d = (float)knot * (1.0f / TSCALE);
        float cc = 0.5f * (__cosf(d * PI_OVER_CUT) + 1.0f);
        float4 o;
        o.x = a2[i].x * cc; o.y = a2[i].y * cc;
        o.z = a2[i].z * cc; o.w = a2[i].w * cc;
        *(float4*)&tab[((size_t)knot << 7) + c4] = o;
    }
}

// ---------------- edge kernel: table lerp + gather + segmented scatter ----------------
__launch_bounds__(256)
__global__ void k_edge_tab(const int* __restrict__ s_src, const int* __restrict__ s_dst,
                           const float* __restrict__ s_fid,
                           const int* __restrict__ rowptr, const int* __restrict__ counts,
                           const float* __restrict__ vlin,
                           const float* __restrict__ tab, float* __restrict__ agg, int E) {
    __shared__ int sh_src[256];
    __shared__ int sh_dst[256];
    __shared__ float sh_fid[256];
    const int tid = threadIdx.x;
    const int e0 = blockIdx.x * 256;
    {
        int e = e0 + tid;
        bool ok = e < E;
        sh_src[tid] = ok ? s_src[e] : 0;
        sh_dst[tid] = ok ? s_dst[e] : -1;
        sh_fid[tid] = ok ? s_fid[e] : 0.f;
    }
    __syncthreads();

    const int c4 = (tid & 31) << 2;
    const int lbase = (tid >> 5) << 5;     // local 32-edge span
    const int gbase = e0 + lbase;          // global span start

    float4 run = make_float4(0.f, 0.f, 0.f, 0.f);
    int cur = -1;
    for (int i = 0; i < 32; i++) {
        int idx = lbase + i;
        int dst = sh_dst[idx];
        if (dst != cur) {
            if (cur >= 0) {
                float* ap = &agg[((size_t)cur << 7) + c4];
                // if this node's whole edge list fits in my span, nobody else touches it
                int rs = rowptr[cur];
                if (rs >= gbase && rs + counts[cur] <= gbase + 32) {
                    *(float4*)ap = run;
                } else {
                    atomicAdd(ap + 0, run.x);
                    atomicAdd(ap + 1, run.y);
                    atomicAdd(ap + 2, run.z);
                    atomicAdd(ap + 3, run.w);
                }
            }
            cur = dst;
            run = make_float4(0.f, 0.f, 0.f, 0.f);
        }
        if (dst >= 0) {
            float fid = sh_fid[idx];
            int i0 = (int)fid;
            float fr = fid - (float)i0;
            const float* tp = &tab[((size_t)i0 << 7) + c4];
            float4 t0 = *(const float4*)tp;
            float4 t1 = *(const float4*)(tp + 128);
            float4 vl = *(const float4*)&vlin[((size_t)sh_src[idx] << 7) + c4];
            float4 w;
            w.x = fmaf(fr, t1.x - t0.x, t0.x);
            w.y = fmaf(fr, t1.y - t0.y, t0.y);
            w.z = fmaf(fr, t1.z - t0.z, t0.z);
            w.w = fmaf(fr, t1.w - t0.w, t0.w);
            run.x = fmaf(w.x, vl.x, run.x);
            run.y = fmaf(w.y, vl.y, run.y);
            run.z = fmaf(w.z, vl.z, run.z);
            run.w = fmaf(w.w, vl.w, run.w);
        }
    }
    if (cur >= 0) {
        float* ap = &agg[((size_t)cur << 7) + c4];
        int rs = rowptr[cur];
        if (rs >= gbase && rs + counts[cur] <= gbase + 32) {
            *(float4*)ap = run;
        } else {
            atomicAdd(ap + 0, run.x);
            atomicAdd(ap + 1, run.y);
            atomicAdd(ap + 2, run.z);
            atomicAdd(ap + 3, run.w);
        }
    }
}

// ---------------- feature embedding ----------------
__global__ void k_fe1(const float* __restrict__ x, const float* __restrict__ w,
                      const float* __restrict__ b, float* __restrict__ h, int N) {
    int idx = blockIdx.x * 256 + threadIdx.x;
    if (idx >= N * 64) return;
    int n = idx >> 6, c = idx & 63;
    const float* xr = x + (size_t)n * 28;
    float acc = b[c];
    #pragma unroll
    for (int k = 0; k < 28; k++) acc = fmaf(xr[k], w[k * 64 + c], acc);
    h[idx] = acc;
}

__global__ void k_bnstat(const float* __restrict__ h, float* __restrict__ stats, int N) {
    __shared__ float s_s[256], s_q[256];
    int tid = threadIdx.x;
    int c = tid & 63, g = tid >> 6;
    float s = 0.f, q = 0.f;
    for (int n = blockIdx.x * 4 + g; n < N; n += gridDim.x * 4) {
        float v = h[(size_t)n * 64 + c];
        s += v; q += v * v;
    }
    s_s[tid] = s; s_q[tid] = q;
    __syncthreads();
    if (tid < 64) {
        s = s_s[tid] + s_s[tid + 64] + s_s[tid + 128] + s_s[tid + 192];
        q = s_q[tid] + s_q[tid + 64] + s_q[tid + 128] + s_q[tid + 192];
        atomicAdd(&stats[tid], s);
        atomicAdd(&stats[64 + tid], q);
    }
}

__global__ void k_bnfin(const float* __restrict__ stats, float* __restrict__ prm,
                        const float* __restrict__ gamma, const float* __restrict__ beta,
                        float invN) {
    int c = threadIdx.x;  // 64 threads
    float mu = stats[c] * invN;
    float var = stats[64 + c] * invN - mu * mu;
    float sc = gamma[c] * rsqrtf(var + 1e-5f);
    prm[c] = sc;
    prm[64 + c] = beta[c] - mu * sc;
}

__global__ void k_fe2(const float* __restrict__ h, const float* __restrict__ prm,
                      const float* __restrict__ w, const float* __restrict__ b,
                      float* __restrict__ v, int N) {
    int idx = blockIdx.x * 256 + threadIdx.x;
    if (idx >= N * 128) return;
    int n = idx >> 7, c = idx & 127;
    const float* hr = h + ((size_t)n << 6);
    float acc = b[c];
    #pragma unroll 8
    for (int k = 0; k < 64; k++) {
        float hv = fmaxf(fmaf(hr[k], prm[k], prm[64 + k]), 0.f);
        acc = fmaf(hv, w[(k << 7) + c], acc);
    }
    v[idx] = fmaxf(acc, 0.f);
}

// ---------------- register-blocked [N,128]x[128,128] GEMM: C = A@W (no bias) ----------------
// 64 rows/block, 256 threads = 32 colgroups x 8 rowgroups, 8 rows x 4 cols per thread
__launch_bounds__(256, 2)
__global__ void k_gemm_rb(const float* __restrict__ A, const float* __restrict__ W,
                          float* __restrict__ C, int N) {
    __shared__ float sA[64 * 128];  // 32 KB
    const int tid = threadIdx.x;
    const int n0 = blockIdx.x * 64;

    for (int i = tid; i < 64 * 32; i += 256) {
        int row = i >> 5, cq = (i & 31) << 2;
        int gr = n0 + row;
        float4 val = (gr < N) ? *(const float4*)&A[((size_t)gr << 7) + cq]
                              : make_float4(0.f, 0.f, 0.f, 0.f);
        *(float4*)&sA[row * 128 + cq] = val;
    }
    __syncthreads();

    const int cg = tid & 31, rg = tid >> 5;
    const int r0 = rg << 3;
    const int c4 = cg << 2;

    float4 acc[8];
    #pragma unroll
    for (int i = 0; i < 8; i++) acc[i] = make_float4(0.f, 0.f, 0.f, 0.f);
    #pragma unroll 4
    for (int k = 0; k < 128; k++) {
        float4 wv = *(const float4*)&W[(k << 7) + c4];
        #pragma unroll
        for (int i = 0; i < 8; i++) {
            float a = sA[(r0 + i) * 128 + k];
            acc[i].x = fmaf(a, wv.x, acc[i].x);
            acc[i].y = fmaf(a, wv.y, acc[i].y);
            acc[i].z = fmaf(a, wv.z, acc[i].z);
            acc[i].w = fmaf(a, wv.w, acc[i].w);
        }
    }
    #pragma unroll
    for (int i = 0; i < 8; i++) {
        int gr = n0 + r0 + i;
        if (gr < N) *(float4*)&C[((size_t)gr << 7) + c4] = acc[i];
    }
}

// ---------------- fused layer update: 3 GEMMs ----------------
// t = ssp(agg@W1+b1); v_new = t@W2+b2 + v_old; vlin = v_new@lin (if lin != null)
__launch_bounds__(256, 2)
__global__ void k_update(const float* __restrict__ agg,
                         const float* __restrict__ w1, const float* __restrict__ b1,
                         const float* __restrict__ w2, const float* __restrict__ b2,
                         float* __restrict__ v,
                         const float* __restrict__ lin, float* __restrict__ vlin, int N) {
    __shared__ float sA[64 * 128];  // agg tile, later reused as v_new tile (32 KB)
    __shared__ float sT[64 * 128];  // t tile (32 KB)
    const int tid = threadIdx.x;
    const int n0 = blockIdx.x * 64;

    for (int i = tid; i < 64 * 32; i += 256) {
        int row = i >> 5, cq = (i & 31) << 2;
        int gr = n0 + row;
        float4 val = (gr < N) ? *(const float4*)&agg[((size_t)gr << 7) + cq]
                              : make_float4(0.f, 0.f, 0.f, 0.f);
        *(float4*)&sA[row * 128 + cq] = val;
    }
    __syncthreads();

    const int cg = tid & 31, rg = tid >> 5;
    const int r0 = rg << 3;
    const int c4 = cg << 2;

    // GEMM 1: t = ssp(agg@W1 + b1)
    {
        float4 b1v = *(const float4*)&b1[c4];
        float4 acc[8];
        #pragma unroll
        for (int i = 0; i < 8; i++) acc[i] = b1v;
        #pragma unroll 4
        for (int k = 0; k < 128; k++) {
            float4 wv = *(const float4*)&w1[(k << 7) + c4];
            #pragma unroll
            for (int i = 0; i < 8; i++) {
                float a = sA[(r0 + i) * 128 + k];
                acc[i].x = fmaf(a, wv.x, acc[i].x);
                acc[i].y = fmaf(a, wv.y, acc[i].y);
                acc[i].z = fmaf(a, wv.z, acc[i].z);
                acc[i].w = fmaf(a, wv.w, acc[i].w);
            }
        }
        #pragma unroll
        for (int i = 0; i < 8; i++) {
            float4 t;
            t.x = sspf(acc[i].x); t.y = sspf(acc[i].y);
            t.z = sspf(acc[i].z); t.w = sspf(acc[i].w);
            *(float4*)&sT[(r0 + i) * 128 + c4] = t;
        }
    }
    __syncthreads();

    // GEMM 2: v_new = t@W2 + b2 + v_old; store to global v and LDS (sA reuse)
    {
        float4 b2v = *(const float4*)&b2[c4];
        float4 acc[8];
        #pragma unroll
        for (int i = 0; i < 8; i++) acc[i] = b2v;
        #pragma unroll 4
        for (int k = 0; k < 128; k++) {
            float4 wv = *(const float4*)&w2[(k << 7) + c4];
            #pragma unroll
            for (int i = 0; i < 8; i++) {
                float a = sT[(r0 + i) * 128 + k];
                acc[i].x = fmaf(a, wv.x, acc[i].x);
                acc[i].y = fmaf(a, wv.y, acc[i].y);
                acc[i].z = fmaf(a, wv.z, acc[i].z);
                acc[i].w = fmaf(a, wv.w, acc[i].w);
            }
        }
        #pragma unroll
        for (int i = 0; i < 8; i++) {
            int gr = n0 + r0 + i;
            float4 vn = make_float4(0.f, 0.f, 0.f, 0.f);
            if (gr < N) {
                float4 vo = *(const float4*)&v[((size_t)gr << 7) + c4];
                vn.x = acc[i].x + vo.x; vn.y = acc[i].y + vo.y;
                vn.z = acc[i].z + vo.z; vn.w = acc[i].w + vo.w;
                *(float4*)&v[((size_t)gr << 7) + c4] = vn;
            }
            *(float4*)&sA[(r0 + i) * 128 + c4] = vn;
        }
    }
    if (!lin) return;
    __syncthreads();

    // GEMM 3: vlin = v_new @ lin
    {
        float4 acc[8];
        #pragma unroll
        for (int i = 0; i < 8; i++) acc[i] = make_float4(0.f, 0.f, 0.f, 0.f);
        #pragma unroll 4
        for (int k = 0; k < 128; k++) {
            float4 wv = *(const float4*)&lin[(k << 7) + c4];
            #pragma unroll
            for (int i = 0; i < 8; i++) {
                float a = sA[(r0 + i) * 128 + k];
                acc[i].x = fmaf(a, wv.x, acc[i].x);
                acc[i].y = fmaf(a, wv.y, acc[i].y);
                acc[i].z = fmaf(a, wv.z, acc[i].z);
                acc[i].w = fmaf(a, wv.w, acc[i].w);
            }
        }
        #pragma unroll
        for (int i = 0; i < 8; i++) {
            int gr = n0 + r0 + i;
            if (gr < N) *(float4*)&vlin[((size_t)gr << 7) + c4] = acc[i];
        }
    }
}

// ---------------- readout ----------------
__global__ void k_u1(const float* __restrict__ v, const float* __restrict__ w,
                     const float* __restrict__ b, float* __restrict__ t, int N) {
    int idx = blockIdx.x * 256 + threadIdx.x;
    if (idx >= N * 16) return;
    int n = idx >> 4, c4 = (idx & 15) << 2;
    const float* vr = v + ((size_t)n << 7);
    float4 acc = *(const float4*)&b[c4];
    #pragma unroll 4
    for (int k = 0; k < 128; k++) {
        float a = vr[k];
        float4 w4 = *(const float4*)&w[(k << 6) + c4];
        acc.x = fmaf(a, w4.x, acc.x);
        acc.y = fmaf(a, w4.y, acc.y);
        acc.z = fmaf(a, w4.z, acc.z);
        acc.w = fmaf(a, w4.w, acc.w);
    }
    float4 t4;
    t4.x = sspf(acc.x); t4.y = sspf(acc.y); t4.z = sspf(acc.z); t4.w = sspf(acc.w);
    *(float4*)&t[((size_t)n << 6) + c4] = t4;
}

__global__ void k_u2(const float* __restrict__ t, const float* __restrict__ w,
                     const float* __restrict__ b, const int* __restrict__ batch,
                     float* __restrict__ out, int N) {
    int idx = blockIdx.x * 256 + threadIdx.x;
    if (idx >= N * 32) return;
    int n = idx >> 5, c = idx & 31;
    const float* tr = t + ((size_t)n << 6);
    float acc = b[c];
    #pragma unroll
    for (int k = 0; k < 64; k++) acc = fmaf(tr[k], w[(k << 5) + c], acc);
    atomicAdd(&out[(size_t)batch[n] * 32 + c], acc);
}

extern "C" void kernel_launch(void* const* d_in, const int* in_sizes, int n_in,
                              void* d_out, int out_size, void* d_ws, size_t ws_size,
                              hipStream_t stream) {
    const float* x      = (const float*)d_in[0];
    const float* pos    = (const float*)d_in[1];
    const int*   batch  = (const int*)d_in[2];
    const int*   ei     = (const int*)d_in[3];
    const float* fe_w1  = (const float*)d_in[4];
    const float* fe_b1  = (const float*)d_in[5];
    const float* bn_g   = (const float*)d_in[6];
    const float* bn_b   = (const float*)d_in[7];
    const float* fe_w2  = (const float*)d_in[8];
    const float* fe_b2  = (const float*)d_in[9];
    const float* lin_w  = (const float*)d_in[10];
    const float* mlp_w1 = (const float*)d_in[11];
    const float* mlp_b1 = (const float*)d_in[12];
    const float* mlp_w2 = (const float*)d_in[13];
    const float* mlp_b2 = (const float*)d_in[14];
    const float* v1_w   = (const float*)d_in[15];
    const float* v1_b   = (const float*)d_in[16];
    const float* v2_w   = (const float*)d_in[17];
    const float* v2_b   = (const float*)d_in[18];
    const float* u1_w   = (const float*)d_in[19];
    const float* u1_b   = (const float*)d_in[20];
    const float* u2_w   = (const float*)d_in[21];
    const float* u2_b   = (const float*)d_in[22];

    const int N = in_sizes[0] / 28;
    const int E = in_sizes[3] / 2;

    char* ws = (char*)d_ws;
    size_t o = 0;
    auto alloc = [&](size_t bytes) { void* p = ws + o; o += (bytes + 255) & ~(size_t)255; return p; };
    int*   counts = (int*)  alloc((size_t)N * 4);
    int*   cursor = (int*)  alloc((size_t)N * 4);
    int*   rowptr = (int*)  alloc((size_t)N * 4);
    int*   s_src  = (int*)  alloc((size_t)E * 4);
    int*   s_dst  = (int*)  alloc((size_t)E * 4);
    float* s_fid  = (float*)alloc((size_t)E * 4);
    float* stats  = (float*)alloc(128 * 4);
    float* prm    = (float*)alloc(128 * 4);
    float* tab    = (float*)alloc((size_t)LAY * K_TAB * 128 * 4);  // 24 MB
    float* v      = (float*)alloc((size_t)N * 128 * 4);
    float* vlin   = (float*)alloc((size_t)N * 128 * 4);
    float* agg    = (float*)alloc((size_t)N * 128 * 4);
    float* h      = vlin;  // alias: h (N x 64) only used before vlin is first written
    float* ut     = agg;   // alias: readout temp (N x 64) after agg's last use

    // -------- one-time edge sort (dst-ordered CSR) --------
    hipMemsetAsync(counts, 0, (size_t)N * 4, stream);
    k_hist<<<(E + 255) / 256, 256, 0, stream>>>(ei, counts, E);
    k_scan<<<1, 1024, 0, stream>>>(counts, cursor, rowptr, N);
    k_scatter<<<(E + 255) / 256, 256, 0, stream>>>(ei, pos, cursor, s_src, s_dst, s_fid, E);

    // -------- gate tables for all layers --------
    k_tab_all<<<LAY * 256, 256, 0, stream>>>(mlp_w1, mlp_b1, mlp_w2, mlp_b2, tab);

    // -------- feature embedding --------
    hipMemsetAsync(stats, 0, 128 * 4, stream);
    k_fe1<<<(N * 64 + 255) / 256, 256, 0, stream>>>(x, fe_w1, fe_b1, h, N);
    k_bnstat<<<256, 256, 0, stream>>>(h, stats, N);
    k_bnfin<<<1, 64, 0, stream>>>(stats, prm, bn_g, bn_b, 1.0f / (float)N);
    k_fe2<<<(N * 128 + 255) / 256, 256, 0, stream>>>(h, prm, fe_w2, fe_b2, v, N);

    // vlin for layer 0
    const int gblk = (N + 63) / 64;
    k_gemm_rb<<<gblk, 256, 0, stream>>>(v, lin_w, vlin, N);

    // -------- interaction layers --------
    for (int l = 0; l < LAY; l++) {
        hipMemsetAsync(agg, 0, (size_t)N * 128 * 4, stream);
        k_edge_tab<<<(E + 255) / 256, 256, 0, stream>>>(
            s_src, s_dst, s_fid, rowptr, counts, vlin,
            tab + (size_t)l * K_TAB * 128, agg, E);
        const float* lin_next = (l + 1 < LAY) ? lin_w + (size_t)(l + 1) * 128 * 128 : nullptr;
        k_update<<<gblk, 256, 0, stream>>>(
            agg, v1_w + (size_t)l * 128 * 128, v1_b + (size_t)l * 128,
            v2_w + (size_t)l * 128 * 128, v2_b + (size_t)l * 128,
            v, lin_next, vlin, N);
    }

    // -------- readout --------
    k_u1<<<(N * 16 + 255) / 256, 256, 0, stream>>>(v, u1_w, u1_b, ut, N);
    hipMemsetAsync(d_out, 0, (size_t)out_size * 4, stream);
    k_u2<<<(N * 32 + 255) / 256, 256, 0, stream>>>(ut, u2_w, u2_b, batch, (float*)d_out, N);
}

// Round 5
// 1561.520 us; speedup vs baseline: 7.6903x; 1.0853x over previous
//
#include <hip/hip_runtime.h>
#include <math.h>

#define DEV __device__ __forceinline__

constexpr int NGAUSS = 50;
constexpr int LAY = 6;
constexpr int K_TAB = 8192;
constexpr float DMAX = 40.0f;
constexpr float TSCALE = (float)(K_TAB - 1) / DMAX;   // fid = d * TSCALE
constexpr float STEP = 6.0f / 49.0f;
constexpr float COEFF = -0.5f / (STEP * STEP);
constexpr float LN2F = 0.69314718055994531f;
constexpr float PI_OVER_CUT = 0.52359877559829887f;  // pi/6

DEV float sspf(float x) {
    float ax = fabsf(x);
    float e = __expf(-ax);
    return fmaxf(x, 0.f) + __logf(1.f + e) - LN2F;
}

// ---------------- edge sort pre-pass (once per call) ----------------
__global__ void k_hist(const int* __restrict__ ei, int* __restrict__ counts, int E) {
    int e = blockIdx.x * 256 + threadIdx.x;
    if (e < E) atomicAdd(&counts[ei[E + e]], 1);
}

// exclusive scan, single block 1024 threads, shuffle-based; writes cursor + pristine rowptr
__global__ void k_scan(const int* __restrict__ counts, int* __restrict__ cursor,
                       int* __restrict__ rowptr, int n) {
    __shared__ int s_wsum[16];
    __shared__ int s_carry;
    if (threadIdx.x == 0) s_carry = 0;
    __syncthreads();
    const int lane = threadIdx.x & 63, wv = threadIdx.x >> 6;
    for (int base = 0; base < n; base += 1024) {
        int i = base + threadIdx.x;
        int v = (i < n) ? counts[i] : 0;
        int x = v;
        #pragma unroll
        for (int off = 1; off < 64; off <<= 1) {
            int y = __shfl_up(x, off, 64);
            if (lane >= off) x += y;
        }
        if (lane == 63) s_wsum[wv] = x;
        __syncthreads();
        if (wv == 0 && lane < 16) {
            int wval = s_wsum[lane];
            int wx = wval;
            #pragma unroll
            for (int off = 1; off < 16; off <<= 1) {
                int wy = __shfl_up(wx, off, 16);
                if (lane >= off) wx += wy;
            }
            s_wsum[lane] = wx - wval;  // exclusive wave prefix
        }
        __syncthreads();
        if (i < n) {
            int excl = s_carry + s_wsum[wv] + x - v;
            cursor[i] = excl;
            rowptr[i] = excl;
        }
        __syncthreads();
        if (threadIdx.x == 1023) s_carry += s_wsum[15] + x;
        __syncthreads();
    }
}

// scatter edges into dst-sorted slots; fuse geometry -> table coordinate fid
__global__ void k_scatter(const int* __restrict__ ei, const float* __restrict__ pos,
                          int* __restrict__ cursor, int* __restrict__ s_src,
                          int* __restrict__ s_dst, float* __restrict__ s_fid, int E) {
    int e = blockIdx.x * 256 + threadIdx.x;
    if (e >= E) return;
    int r = ei[e], c = ei[E + e];
    int p = atomicAdd(&cursor[c], 1);
    float dx = pos[3 * r + 0] - pos[3 * c + 0];
    float dy = pos[3 * r + 1] - pos[3 * c + 1];
    float dz = pos[3 * r + 2] - pos[3 * c + 2];
    float d = sqrtf(dx * dx + dy * dy + dz * dz);
    s_src[p] = r;
    s_dst[p] = c;
    s_fid[p] = fminf(d * TSCALE, (float)(K_TAB - 2) + 0.999f);
}

// ---------------- gate table build, ALL layers in one launch ----------------
__launch_bounds__(256)
__global__ void k_tab_all(const float* __restrict__ w1A, const float* __restrict__ b1A,
                          const float* __restrict__ w2A, const float* __restrict__ b2A,
                          float* __restrict__ tabA) {
    const int layer = blockIdx.x >> 8;
    const int k0 = (blockIdx.x & 255) * 32;
    const float* w1 = w1A + (size_t)layer * NGAUSS * 128;
    const float* b1 = b1A + (size_t)layer * 128;
    const float* w2 = w2A + (size_t)layer * 128 * 128;
    const float* b2 = b2A + (size_t)layer * 128;
    float* tab = tabA + (size_t)layer * K_TAB * 128;

    __shared__ float s_demb[32][NGAUSS];  // 6.4 KB
    __shared__ float s_t1[32][128];       // 16 KB
    const int tid = threadIdx.x;

    for (int i = tid; i < 32 * NGAUSS; i += 256) {
        int r = i / NGAUSS, g = i - r * NGAUSS;
        float d = (float)(k0 + r) * (1.0f / TSCALE);
        float t = d - g * STEP;
        s_demb[r][g] = __expf(COEFF * t * t);
    }
    __syncthreads();

    const int cg = tid & 31, rg = tid >> 5;
    const int r0 = rg << 2;        // 4 rows per thread
    const int c4 = cg << 2;

    float4 b1v = *(const float4*)&b1[c4];
    float4 acc[4];
    #pragma unroll
    for (int i = 0; i < 4; i++) acc[i] = b1v;
    #pragma unroll 2
    for (int k = 0; k < NGAUSS; k++) {
        float4 wv = *(const float4*)&w1[(k << 7) + c4];
        #pragma unroll
        for (int i = 0; i < 4; i++) {
            float dv = s_demb[r0 + i][k];
            acc[i].x = fmaf(dv, wv.x, acc[i].x);
            acc[i].y = fmaf(dv, wv.y, acc[i].y);
            acc[i].z = fmaf(dv, wv.z, acc[i].z);
            acc[i].w = fmaf(dv, wv.w, acc[i].w);
        }
    }
    #pragma unroll
    for (int i = 0; i < 4; i++) {
        float4 t;
        t.x = sspf(acc[i].x); t.y = sspf(acc[i].y);
        t.z = sspf(acc[i].z); t.w = sspf(acc[i].w);
        *(float4*)&s_t1[r0 + i][c4] = t;
    }
    __syncthreads();

    float4 b2v = *(const float4*)&b2[c4];
    float4 a2[4];
    #pragma unroll
    for (int i = 0; i < 4; i++) a2[i] = b2v;
    #pragma unroll 4
    for (int k = 0; k < 128; k++) {
        float4 wv = *(const float4*)&w2[(k << 7) + c4];
        #pragma unroll
        for (int i = 0; i < 4; i++) {
            float tv = s_t1[r0 + i][k];
            a2[i].x = fmaf(tv, wv.x, a2[i].x);
            a2[i].y = fmaf(tv, wv.y, a2[i].y);
            a2[i].z = fmaf(tv, wv.z, a2[i].z);
            a2[i].w = fmaf(tv, wv.w, a2[i].w);
        }
    }
    #pragma unroll
    for (int i = 0; i < 4; i++) {
        int knot = k0 + r0 + i;
        float d = (float)knot * (1.0f / TSCALE);
        float cc = 0.5f * (__cosf(d * PI_OVER_CUT) + 1.0f);
        float4 o;
        o.x = a2[i].x * cc; o.y = a2[i].y * cc;
        o.z = a2[i].z * cc; o.w = a2[i].w * cc;
        *(float4*)&tab[((size_t)knot << 7) + c4] = o;
    }
}

// ---------------- edge kernel: table lerp + gather + segmented scatter ----------------
// batched loads (4 edges = 12 float4 gathers in flight) + segment-entry rowptr prefetch
__launch_bounds__(256)
__global__ void k_edge_tab(const int* __restrict__ s_src, const int* __restrict__ s_dst,
                           const float* __restrict__ s_fid,
                           const int* __restrict__ rowptr, const int* __restrict__ counts,
                           const float* __restrict__ vlin,
                           const float* __restrict__ tab, float* __restrict__ agg, int E) {
    __shared__ int sh_src[256];
    __shared__ int sh_dst[256];
    __shared__ float sh_fid[256];
    const int tid = threadIdx.x;
    const int e0 = blockIdx.x * 256;
    {
        int e = e0 + tid;
        bool ok = e < E;
        sh_src[tid] = ok ? s_src[e] : 0;
        sh_dst[tid] = ok ? s_dst[e] : -1;
        sh_fid[tid] = ok ? s_fid[e] : 0.f;
    }
    __syncthreads();

    const int c4 = (tid & 31) << 2;
    const int lbase = (tid >> 5) << 5;     // local 32-edge span
    const int gbase = e0 + lbase;          // global span start

    float4 run = make_float4(0.f, 0.f, 0.f, 0.f);
    int cur = -1, curRS = 0, curCNT = 0;

    for (int ii = 0; ii < 32; ii += 4) {
        float4 T0[4], T1[4], VL[4];
        float FR[4];
        int DST[4];
        #pragma unroll
        for (int j = 0; j < 4; j++) {
            int idx = lbase + ii + j;
            DST[j] = sh_dst[idx];
            float fid = sh_fid[idx];
            int i0 = (int)fid;
            FR[j] = fid - (float)i0;
            const float* tp = &tab[((size_t)i0 << 7) + c4];
            T0[j] = *(const float4*)tp;
            T1[j] = *(const float4*)(tp + 128);
            VL[j] = *(const float4*)&vlin[((size_t)sh_src[idx] << 7) + c4];
        }
        #pragma unroll
        for (int j = 0; j < 4; j++) {
            int dst = DST[j];
            if (dst != cur) {
                if (cur >= 0) {
                    float* ap = &agg[((size_t)cur << 7) + c4];
                    if (curRS >= gbase && curRS + curCNT <= gbase + 32) {
                        *(float4*)ap = run;   // whole segment owned by this thread
                    } else {
                        atomicAdd(ap + 0, run.x);
                        atomicAdd(ap + 1, run.y);
                        atomicAdd(ap + 2, run.z);
                        atomicAdd(ap + 3, run.w);
                    }
                }
                cur = dst;
                curRS  = (dst >= 0) ? rowptr[dst] : 0;   // prefetched for later flush
                curCNT = (dst >= 0) ? counts[dst] : 0;
                run = make_float4(0.f, 0.f, 0.f, 0.f);
            }
            if (dst >= 0) {
                float4 w;
                w.x = fmaf(FR[j], T1[j].x - T0[j].x, T0[j].x);
                w.y = fmaf(FR[j], T1[j].y - T0[j].y, T0[j].y);
                w.z = fmaf(FR[j], T1[j].z - T0[j].z, T0[j].z);
                w.w = fmaf(FR[j], T1[j].w - T0[j].w, T0[j].w);
                run.x = fmaf(w.x, VL[j].x, run.x);
                run.y = fmaf(w.y, VL[j].y, run.y);
                run.z = fmaf(w.z, VL[j].z, run.z);
                run.w = fmaf(w.w, VL[j].w, run.w);
            }
        }
    }
    if (cur >= 0) {
        float* ap = &agg[((size_t)cur << 7) + c4];
        if (curRS >= gbase && curRS + curCNT <= gbase + 32) {
            *(float4*)ap = run;
        } else {
            atomicAdd(ap + 0, run.x);
            atomicAdd(ap + 1, run.y);
            atomicAdd(ap + 2, run.z);
            atomicAdd(ap + 3, run.w);
        }
    }
}

// ---------------- feature embedding ----------------
__global__ void k_fe1(const float* __restrict__ x, const float* __restrict__ w,
                      const float* __restrict__ b, float* __restrict__ h, int N) {
    int idx = blockIdx.x * 256 + threadIdx.x;
    if (idx >= N * 64) return;
    int n = idx >> 6, c = idx & 63;
    const float* xr = x + (size_t)n * 28;
    float acc = b[c];
    #pragma unroll
    for (int k = 0; k < 28; k++) acc = fmaf(xr[k], w[k * 64 + c], acc);
    h[idx] = acc;
}

__global__ void k_bnstat(const float* __restrict__ h, float* __restrict__ stats, int N) {
    __shared__ float s_s[256], s_q[256];
    int tid = threadIdx.x;
    int c = tid & 63, g = tid >> 6;
    float s = 0.f, q = 0.f;
    for (int n = blockIdx.x * 4 + g; n < N; n += gridDim.x * 4) {
        float v = h[(size_t)n * 64 + c];
        s += v; q += v * v;
    }
    s_s[tid] = s; s_q[tid] = q;
    __syncthreads();
    if (tid < 64) {
        s = s_s[tid] + s_s[tid + 64] + s_s[tid + 128] + s_s[tid + 192];
        q = s_q[tid] + s_q[tid + 64] + s_q[tid + 128] + s_q[tid + 192];
        atomicAdd(&stats[tid], s);
        atomicAdd(&stats[64 + tid], q);
    }
}

__global__ void k_bnfin(const float* __restrict__ stats, float* __restrict__ prm,
                        const float* __restrict__ gamma, const float* __restrict__ beta,
                        float invN) {
    int c = threadIdx.x;  // 64 threads
    float mu = stats[c] * invN;
    float var = stats[64 + c] * invN - mu * mu;
    float sc = gamma[c] * rsqrtf(var + 1e-5f);
    prm[c] = sc;
    prm[64 + c] = beta[c] - mu * sc;
}

__global__ void k_fe2(const float* __restrict__ h, const float* __restrict__ prm,
                      const float* __restrict__ w, const float* __restrict__ b,
                      float* __restrict__ v, int N) {
    int idx = blockIdx.x * 256 + threadIdx.x;
    if (idx >= N * 128) return;
    int n = idx >> 7, c = idx & 127;
    const float* hr = h + ((size_t)n << 6);
    float acc = b[c];
    #pragma unroll 8
    for (int k = 0; k < 64; k++) {
        float hv = fmaxf(fmaf(hr[k], prm[k], prm[64 + k]), 0.f);
        acc = fmaf(hv, w[(k << 7) + c], acc);
    }
    v[idx] = fmaxf(acc, 0.f);
}

// ---------------- register-blocked [N,128]x[128,128] GEMM: C = A@W (no bias) ----------------
__launch_bounds__(256, 4)
__global__ void k_gemm_rb(const float* __restrict__ A, const float* __restrict__ W,
                          float* __restrict__ C, int N) {
    __shared__ float sA[64 * 128];  // 32 KB
    const int tid = threadIdx.x;
    const int n0 = blockIdx.x * 64;

    for (int i = tid; i < 64 * 32; i += 256) {
        int row = i >> 5, cq = (i & 31) << 2;
        int gr = n0 + row;
        float4 val = (gr < N) ? *(const float4*)&A[((size_t)gr << 7) + cq]
                              : make_float4(0.f, 0.f, 0.f, 0.f);
        *(float4*)&sA[row * 128 + cq] = val;
    }
    __syncthreads();

    const int cg = tid & 31, rg = tid >> 5;
    const int r0 = rg << 3;
    const int c4 = cg << 2;

    float4 acc[8];
    #pragma unroll
    for (int i = 0; i < 8; i++) acc[i] = make_float4(0.f, 0.f, 0.f, 0.f);
    #pragma unroll 4
    for (int k = 0; k < 128; k++) {
        float4 wv = *(const float4*)&W[(k << 7) + c4];
        #pragma unroll
        for (int i = 0; i < 8; i++) {
            float a = sA[(r0 + i) * 128 + k];
            acc[i].x = fmaf(a, wv.x, acc[i].x);
            acc[i].y = fmaf(a, wv.y, acc[i].y);
            acc[i].z = fmaf(a, wv.z, acc[i].z);
            acc[i].w = fmaf(a, wv.w, acc[i].w);
        }
    }
    #pragma unroll
    for (int i = 0; i < 8; i++) {
        int gr = n0 + r0 + i;
        if (gr < N) *(float4*)&C[((size_t)gr << 7) + c4] = acc[i];
    }
}

// ---------------- fused layer update: 3 GEMMs, single 32KB LDS buffer ----------------
// t = ssp(agg@W1+b1); v_new = t@W2+b2 + v_old; vlin = v_new@lin (if lin != null)
__launch_bounds__(256, 4)
__global__ void k_update(const float* __restrict__ agg,
                         const float* __restrict__ w1, const float* __restrict__ b1,
                         const float* __restrict__ w2, const float* __restrict__ b2,
                         float* __restrict__ v,
                         const float* __restrict__ lin, float* __restrict__ vlin, int N) {
    __shared__ float sA[64 * 128];  // 32 KB, serially holds agg -> t -> v_new
    const int tid = threadIdx.x;
    const int n0 = blockIdx.x * 64;

    for (int i = tid; i < 64 * 32; i += 256) {
        int row = i >> 5, cq = (i & 31) << 2;
        int gr = n0 + row;
        float4 val = (gr < N) ? *(const float4*)&agg[((size_t)gr << 7) + cq]
                              : make_float4(0.f, 0.f, 0.f, 0.f);
        *(float4*)&sA[row * 128 + cq] = val;
    }
    __syncthreads();

    const int cg = tid & 31, rg = tid >> 5;
    const int r0 = rg << 3;
    const int c4 = cg << 2;

    // GEMM 1: t = ssp(agg@W1 + b1) -> regs
    float4 acc[8];
    {
        float4 b1v = *(const float4*)&b1[c4];
        #pragma unroll
        for (int i = 0; i < 8; i++) acc[i] = b1v;
        #pragma unroll 4
        for (int k = 0; k < 128; k++) {
            float4 wv = *(const float4*)&w1[(k << 7) + c4];
            #pragma unroll
            for (int i = 0; i < 8; i++) {
                float a = sA[(r0 + i) * 128 + k];
                acc[i].x = fmaf(a, wv.x, acc[i].x);
                acc[i].y = fmaf(a, wv.y, acc[i].y);
                acc[i].z = fmaf(a, wv.z, acc[i].z);
                acc[i].w = fmaf(a, wv.w, acc[i].w);
            }
        }
    }
    __syncthreads();   // all reads of agg tile done
    #pragma unroll
    for (int i = 0; i < 8; i++) {
        float4 t;
        t.x = sspf(acc[i].x); t.y = sspf(acc[i].y);
        t.z = sspf(acc[i].z); t.w = sspf(acc[i].w);
        *(float4*)&sA[(r0 + i) * 128 + c4] = t;
    }
    __syncthreads();

    // GEMM 2: v_new = t@W2 + b2 + v_old -> regs
    {
        float4 b2v = *(const float4*)&b2[c4];
        #pragma unroll
        for (int i = 0; i < 8; i++) acc[i] = b2v;
        #pragma unroll 4
        for (int k = 0; k < 128; k++) {
            float4 wv = *(const float4*)&w2[(k << 7) + c4];
            #pragma unroll
            for (int i = 0; i < 8; i++) {
                float a = sA[(r0 + i) * 128 + k];
                acc[i].x = fmaf(a, wv.x, acc[i].x);
                acc[i].y = fmaf(a, wv.y, acc[i].y);
                acc[i].z = fmaf(a, wv.z, acc[i].z);
                acc[i].w = fmaf(a, wv.w, acc[i].w);
            }
        }
    }
    __syncthreads();   // all reads of t tile done
    #pragma unroll
    for (int i = 0; i < 8; i++) {
        int gr = n0 + r0 + i;
        float4 vn = make_float4(0.f, 0.f, 0.f, 0.f);
        if (gr < N) {
            float4 vo = *(const float4*)&v[((size_t)gr << 7) + c4];
            vn.x = acc[i].x + vo.x; vn.y = acc[i].y + vo.y;
            vn.z = acc[i].z + vo.z; vn.w = acc[i].w + vo.w;
            *(float4*)&v[((size_t)gr << 7) + c4] = vn;
        }
        *(float4*)&sA[(r0 + i) * 128 + c4] = vn;
    }
    if (!lin) return;
    __syncthreads();

    // GEMM 3: vlin = v_new @ lin
    {
        #pragma unroll
        for (int i = 0; i < 8; i++) acc[i] = make_float4(0.f, 0.f, 0.f, 0.f);
        #pragma unroll 4
        for (int k = 0; k < 128; k++) {
            float4 wv = *(const float4*)&lin[(k << 7) + c4];
            #pragma unroll
            for (int i = 0; i < 8; i++) {
                float a = sA[(r0 + i) * 128 + k];
                acc[i].x = fmaf(a, wv.x, acc[i].x);
                acc[i].y = fmaf(a, wv.y, acc[i].y);
                acc[i].z = fmaf(a, wv.z, acc[i].z);
                acc[i].w = fmaf(a, wv.w, acc[i].w);
            }
        }
        #pragma unroll
        for (int i = 0; i < 8; i++) {
            int gr = n0 + r0 + i;
            if (gr < N) *(float4*)&vlin[((size_t)gr << 7) + c4] = acc[i];
        }
    }
}

// ---------------- readout ----------------
__global__ void k_u1(const float* __restrict__ v, const float* __restrict__ w,
                     const float* __restrict__ b, float* __restrict__ t, int N) {
    int idx = blockIdx.x * 256 + threadIdx.x;
    if (idx >= N * 16) return;
    int n = idx >> 4, c4 = (idx & 15) << 2;
    const float* vr = v + ((size_t)n << 7);
    float4 acc = *(const float4*)&b[c4];
    #pragma unroll 4
    for (int k = 0; k < 128; k++) {
        float a = vr[k];
        float4 w4 = *(const float4*)&w[(k << 6) + c4];
        acc.x = fmaf(a, w4.x, acc.x);
        acc.y = fmaf(a, w4.y, acc.y);
        acc.z = fmaf(a, w4.z, acc.z);
        acc.w = fmaf(a, w4.w, acc.w);
    }
    float4 t4;
    t4.x = sspf(acc.x); t4.y = sspf(acc.y); t4.z = sspf(acc.z); t4.w = sspf(acc.w);
    *(float4*)&t[((size_t)n << 6) + c4] = t4;
}

__global__ void k_u2(const float* __restrict__ t, const float* __restrict__ w,
                     const float* __restrict__ b, const int* __restrict__ batch,
                     float* __restrict__ out, int N) {
    int idx = blockIdx.x * 256 + threadIdx.x;
    if (idx >= N * 32) return;
    int n = idx >> 5, c = idx & 31;
    const float* tr = t + ((size_t)n << 6);
    float acc = b[c];
    #pragma unroll
    for (int k = 0; k < 64; k++) acc = fmaf(tr[k], w[(k << 5) + c], acc);
    atomicAdd(&out[(size_t)batch[n] * 32 + c], acc);
}

extern "C" void kernel_launch(void* const* d_in, const int* in_sizes, int n_in,
                              void* d_out, int out_size, void* d_ws, size_t ws_size,
                              hipStream_t stream) {
    const float* x      = (const float*)d_in[0];
    const float* pos    = (const float*)d_in[1];
    const int*   batch  = (const int*)d_in[2];
    const int*   ei     = (const int*)d_in[3];
    const float* fe_w1  = (const float*)d_in[4];
    const float* fe_b1  = (const float*)d_in[5];
    const float* bn_g   = (const float*)d_in[6];
    const float* bn_b   = (const float*)d_in[7];
    const float* fe_w2  = (const float*)d_in[8];
    const float* fe_b2  = (const float*)d_in[9];
    const float* lin_w  = (const float*)d_in[10];
    const float* mlp_w1 = (const float*)d_in[11];
    const float* mlp_b1 = (const float*)d_in[12];
    const float* mlp_w2 = (const float*)d_in[13];
    const float* mlp_b2 = (const float*)d_in[14];
    const float* v1_w   = (const float*)d_in[15];
    const float* v1_b   = (const float*)d_in[16];
    const float* v2_w   = (const float*)d_in[17];
    const float* v2_b   = (const float*)d_in[18];
    const float* u1_w   = (const float*)d_in[19];
    const float* u1_b   = (const float*)d_in[20];
    const float* u2_w   = (const float*)d_in[21];
    const float* u2_b   = (const float*)d_in[22];

    const int N = in_sizes[0] / 28;
    const int E = in_sizes[3] / 2;

    char* ws = (char*)d_ws;
    size_t o = 0;
    auto alloc = [&](size_t bytes) { void* p = ws + o; o += (bytes + 255) & ~(size_t)255; return p; };
    int*   counts = (int*)  alloc((size_t)N * 4);
    int*   cursor = (int*)  alloc((size_t)N * 4);
    int*   rowptr = (int*)  alloc((size_t)N * 4);
    int*   s_src  = (int*)  alloc((size_t)E * 4);
    int*   s_dst  = (int*)  alloc((size_t)E * 4);
    float* s_fid  = (float*)alloc((size_t)E * 4);
    float* stats  = (float*)alloc(128 * 4);
    float* prm    = (float*)alloc(128 * 4);
    float* tab    = (float*)alloc((size_t)LAY * K_TAB * 128 * 4);  // 24 MB
    float* v      = (float*)alloc((size_t)N * 128 * 4);
    float* vlin   = (float*)alloc((size_t)N * 128 * 4);
    float* agg    = (float*)alloc((size_t)N * 128 * 4);
    float* h      = vlin;  // alias: h (N x 64) only used before vlin is first written
    float* ut     = agg;   // alias: readout temp (N x 64) after agg's last use

    // -------- one-time edge sort (dst-ordered CSR) --------
    hipMemsetAsync(counts, 0, (size_t)N * 4, stream);
    k_hist<<<(E + 255) / 256, 256, 0, stream>>>(ei, counts, E);
    k_scan<<<1, 1024, 0, stream>>>(counts, cursor, rowptr, N);
    k_scatter<<<(E + 255) / 256, 256, 0, stream>>>(ei, pos, cursor, s_src, s_dst, s_fid, E);

    // -------- gate tables for all layers --------
    k_tab_all<<<LAY * 256, 256, 0, stream>>>(mlp_w1, mlp_b1, mlp_w2, mlp_b2, tab);

    // -------- feature embedding --------
    hipMemsetAsync(stats, 0, 128 * 4, stream);
    k_fe1<<<(N * 64 + 255) / 256, 256, 0, stream>>>(x, fe_w1, fe_b1, h, N);
    k_bnstat<<<256, 256, 0, stream>>>(h, stats, N);
    k_bnfin<<<1, 64, 0, stream>>>(stats, prm, bn_g, bn_b, 1.0f / (float)N);
    k_fe2<<<(N * 128 + 255) / 256, 256, 0, stream>>>(h, prm, fe_w2, fe_b2, v, N);

    // vlin for layer 0
    const int gblk = (N + 63) / 64;
    k_gemm_rb<<<gblk, 256, 0, stream>>>(v, lin_w, vlin, N);

    // -------- interaction layers --------
    for (int l = 0; l < LAY; l++) {
        hipMemsetAsync(agg, 0, (size_t)N * 128 * 4, stream);
        k_edge_tab<<<(E + 255) / 256, 256, 0, stream>>>(
            s_src, s_dst, s_fid, rowptr, counts, vlin,
            tab + (size_t)l * K_TAB * 128, agg, E);
        const float* lin_next = (l + 1 < LAY) ? lin_w + (size_t)(l + 1) * 128 * 128 : nullptr;
        k_update<<<gblk, 256, 0, stream>>>(
            agg, v1_w + (size_t)l * 128 * 128, v1_b + (size_t)l * 128,
            v2_w + (size_t)l * 128 * 128, v2_b + (size_t)l * 128,
            v, lin_next, vlin, N);
    }

    // -------- readout --------
    k_u1<<<(N * 16 + 255) / 256, 256, 0, stream>>>(v, u1_w, u1_b, ut, N);
    hipMemsetAsync(d_out, 0, (size_t)out_size * 4, stream);
    k_u2<<<(N * 32 + 255) / 256, 256, 0, stream>>>(ut, u2_w, u2_b, batch, (float*)d_out, N);
}

// Round 6
// 1491.128 us; speedup vs baseline: 8.0534x; 1.0472x over previous
//
#include <hip/hip_runtime.h>
#include <hip/hip_fp16.h>
#include <math.h>

#define DEV __device__ __forceinline__

constexpr int NGAUSS = 50;
constexpr int LAY = 6;
constexpr int K_TAB = 8192;
constexpr float DMAX = 40.0f;
constexpr float TSCALE = (float)(K_TAB - 1) / DMAX;   // fid = d * TSCALE
constexpr float STEP = 6.0f / 49.0f;
constexpr float COEFF = -0.5f / (STEP * STEP);
constexpr float LN2F = 0.69314718055994531f;
constexpr float PI_OVER_CUT = 0.52359877559829887f;  // pi/6

DEV float sspf(float x) {
    float ax = fabsf(x);
    float e = __expf(-ax);
    return fmaxf(x, 0.f) + __logf(1.f + e) - LN2F;
}

// ---- fp16 pack/unpack helpers (storage fp16, math f32) ----
DEV float4 ld_h4(const ushort* p) {          // 8B load -> 4 floats
    uint2 r = *(const uint2*)p;
    __half2 a = __builtin_bit_cast(__half2, r.x);
    __half2 b = __builtin_bit_cast(__half2, r.y);
    float2 fa = __half22float2(a), fb = __half22float2(b);
    return make_float4(fa.x, fa.y, fb.x, fb.y);
}
DEV void st_h4(ushort* p, float4 v) {        // 4 floats -> 8B store
    uint2 r;
    r.x = __builtin_bit_cast(uint, __float22half2_rn(make_float2(v.x, v.y)));
    r.y = __builtin_bit_cast(uint, __float22half2_rn(make_float2(v.z, v.w)));
    *(uint2*)p = r;
}

// ---------------- edge sort pre-pass (once per call) ----------------
__global__ void k_hist(const int* __restrict__ ei, int* __restrict__ counts, int E) {
    int e = blockIdx.x * 256 + threadIdx.x;
    if (e < E) atomicAdd(&counts[ei[E + e]], 1);
}

// hierarchical scan: stage 1 — per-block (1024 elems) local exclusive scan + block sums
__global__ void k_scan1(const int* __restrict__ counts, int* __restrict__ locex,
                        int* __restrict__ bsum, int n) {
    __shared__ int s_wsum[16];
    const int tid = threadIdx.x;
    const int i = blockIdx.x * 1024 + tid;
    const int lane = tid & 63, wv = tid >> 6;
    int v = (i < n) ? counts[i] : 0;
    int x = v;
    #pragma unroll
    for (int off = 1; off < 64; off <<= 1) {
        int y = __shfl_up(x, off, 64);
        if (lane >= off) x += y;
    }
    if (lane == 63) s_wsum[wv] = x;
    __syncthreads();
    if (wv == 0 && lane < 16) {
        int wval = s_wsum[lane];
        int wx = wval;
        #pragma unroll
        for (int off = 1; off < 16; off <<= 1) {
            int wy = __shfl_up(wx, off, 16);
            if (lane >= off) wx += wy;
        }
        s_wsum[lane] = wx - wval;  // exclusive wave prefix
    }
    __syncthreads();
    if (i < n) locex[i] = s_wsum[wv] + x - v;
    if (tid == 1023) bsum[blockIdx.x] = s_wsum[15] + x;
}

// stage 2 — exclusive scan of block sums (nb <= 1024), one block
__global__ void k_scan2(int* __restrict__ bsum, int nb) {
    __shared__ int s_wsum[16];
    const int tid = threadIdx.x;
    const int lane = tid & 63, wv = tid >> 6;
    int v = (tid < nb) ? bsum[tid] : 0;
    int x = v;
    #pragma unroll
    for (int off = 1; off < 64; off <<= 1) {
        int y = __shfl_up(x, off, 64);
        if (lane >= off) x += y;
    }
    if (lane == 63) s_wsum[wv] = x;
    __syncthreads();
    if (wv == 0 && lane < 16) {
        int wval = s_wsum[lane];
        int wx = wval;
        #pragma unroll
        for (int off = 1; off < 16; off <<= 1) {
            int wy = __shfl_up(wx, off, 16);
            if (lane >= off) wx += wy;
        }
        s_wsum[lane] = wx - wval;
    }
    __syncthreads();
    if (tid < nb) bsum[tid] = s_wsum[wv] + x - v;  // exclusive
}

// stage 3 — add block offsets, emit cursor + pristine rowptr
__global__ void k_scan3(const int* __restrict__ locex, const int* __restrict__ bsumex,
                        int* __restrict__ cursor, int* __restrict__ rowptr, int n) {
    int i = blockIdx.x * 256 + threadIdx.x;
    if (i >= n) return;
    int e = locex[i] + bsumex[i >> 10];
    cursor[i] = e;
    rowptr[i] = e;
}

// scatter edges into dst-sorted slots; fuse geometry -> table coordinate fid
__global__ void k_scatter(const int* __restrict__ ei, const float* __restrict__ pos,
                          int* __restrict__ cursor, int* __restrict__ s_src,
                          int* __restrict__ s_dst, float* __restrict__ s_fid, int E) {
    int e = blockIdx.x * 256 + threadIdx.x;
    if (e >= E) return;
    int r = ei[e], c = ei[E + e];
    int p = atomicAdd(&cursor[c], 1);
    float dx = pos[3 * r + 0] - pos[3 * c + 0];
    float dy = pos[3 * r + 1] - pos[3 * c + 1];
    float dz = pos[3 * r + 2] - pos[3 * c + 2];
    float d = sqrtf(dx * dx + dy * dy + dz * dz);
    s_src[p] = r;
    s_dst[p] = c;
    s_fid[p] = fminf(d * TSCALE, (float)(K_TAB - 2) + 0.999f);
}

// ---------------- gate table build (fp16 output), ALL layers in one launch ----------------
__launch_bounds__(256)
__global__ void k_tab_all(const float* __restrict__ w1A, const float* __restrict__ b1A,
                          const float* __restrict__ w2A, const float* __restrict__ b2A,
                          ushort* __restrict__ tabA) {
    const int layer = blockIdx.x >> 8;
    const int k0 = (blockIdx.x & 255) * 32;
    const float* w1 = w1A + (size_t)layer * NGAUSS * 128;
    const float* b1 = b1A + (size_t)layer * 128;
    const float* w2 = w2A + (size_t)layer * 128 * 128;
    const float* b2 = b2A + (size_t)layer * 128;
    ushort* tab = tabA + (size_t)layer * K_TAB * 128;

    __shared__ float s_demb[32][NGAUSS];  // 6.4 KB
    __shared__ float s_t1[32][128];       // 16 KB
    const int tid = threadIdx.x;

    for (int i = tid; i < 32 * NGAUSS; i += 256) {
        int r = i / NGAUSS, g = i - r * NGAUSS;
        float d = (float)(k0 + r) * (1.0f / TSCALE);
        float t = d - g * STEP;
        s_demb[r][g] = __expf(COEFF * t * t);
    }
    __syncthreads();

    const int cg = tid & 31, rg = tid >> 5;
    const int r0 = rg << 2;        // 4 rows per thread
    const int c4 = cg << 2;

    float4 b1v = *(const float4*)&b1[c4];
    float4 acc[4];
    #pragma unroll
    for (int i = 0; i < 4; i++) acc[i] = b1v;
    #pragma unroll 2
    for (int k = 0; k < NGAUSS; k++) {
        float4 wv = *(const float4*)&w1[(k << 7) + c4];
        #pragma unroll
        for (int i = 0; i < 4; i++) {
            float dv = s_demb[r0 + i][k];
            acc[i].x = fmaf(dv, wv.x, acc[i].x);
            acc[i].y = fmaf(dv, wv.y, acc[i].y);
            acc[i].z = fmaf(dv, wv.z, acc[i].z);
            acc[i].w = fmaf(dv, wv.w, acc[i].w);
        }
    }
    #pragma unroll
    for (int i = 0; i < 4; i++) {
        float4 t;
        t.x = sspf(acc[i].x); t.y = sspf(acc[i].y);
        t.z = sspf(acc[i].z); t.w = sspf(acc[i].w);
        *(float4*)&s_t1[r0 + i][c4] = t;
    }
    __syncthreads();

    float4 b2v = *(const float4*)&b2[c4];
    float4 a2[4];
    #pragma unroll
    for (int i = 0; i < 4; i++) a2[i] = b2v;
    #pragma unroll 4
    for (int k = 0; k < 128; k++) {
        float4 wv = *(const float4*)&w2[(k << 7) + c4];
        #pragma unroll
        for (int i = 0; i < 4; i++) {
            float tv = s_t1[r0 + i][k];
            a2[i].x = fmaf(tv, wv.x, a2[i].x);
            a2[i].y = fmaf(tv, wv.y, a2[i].y);
            a2[i].z = fmaf(tv, wv.z, a2[i].z);
            a2[i].w = fmaf(tv, wv.w, a2[i].w);
        }
    }
    #pragma unroll
    for (int i = 0; i < 4; i++) {
        int knot = k0 + r0 + i;
        float d = (float)knot * (1.0f / TSCALE);
        float cc = 0.5f * (__cosf(d * PI_OVER_CUT) + 1.0f);
        float4 o;
        o.x = a2[i].x * cc; o.y = a2[i].y * cc;
        o.z = a2[i].z * cc; o.w = a2[i].w * cc;
        st_h4(&tab[((size_t)knot << 7) + c4], o);
    }
}

// ---------------- edge kernel: fp16 table lerp + fp16 gather + segmented scatter ----------------
__launch_bounds__(256)
__global__ void k_edge_tab(const int* __restrict__ s_src, const int* __restrict__ s_dst,
                           const float* __restrict__ s_fid,
                           const int* __restrict__ rowptr, const int* __restrict__ counts,
                           const ushort* __restrict__ vlin,
                           const ushort* __restrict__ tab, float* __restrict__ agg, int E) {
    __shared__ int sh_src[256];
    __shared__ int sh_dst[256];
    __shared__ float sh_fid[256];
    const int tid = threadIdx.x;
    const int e0 = blockIdx.x * 256;
    {
        int e = e0 + tid;
        bool ok = e < E;
        sh_src[tid] = ok ? s_src[e] : 0;
        sh_dst[tid] = ok ? s_dst[e] : -1;
        sh_fid[tid] = ok ? s_fid[e] : 0.f;
    }
    __syncthreads();

    const int c4 = (tid & 31) << 2;
    const int lbase = (tid >> 5) << 5;     // local 32-edge span
    const int gbase = e0 + lbase;          // global span start

    float4 run = make_float4(0.f, 0.f, 0.f, 0.f);
    int cur = -1, curRS = 0, curCNT = 0;

    for (int ii = 0; ii < 32; ii += 4) {
        float4 T0[4], T1[4], VL[4];
        float FR[4];
        int DST[4];
        #pragma unroll
        for (int j = 0; j < 4; j++) {
            int idx = lbase + ii + j;
            DST[j] = sh_dst[idx];
            float fid = sh_fid[idx];
            int i0 = (int)fid;
            FR[j] = fid - (float)i0;
            const ushort* tp = &tab[((size_t)i0 << 7) + c4];
            T0[j] = ld_h4(tp);
            T1[j] = ld_h4(tp + 128);
            VL[j] = ld_h4(&vlin[((size_t)sh_src[idx] << 7) + c4]);
        }
        #pragma unroll
        for (int j = 0; j < 4; j++) {
            int dst = DST[j];
            if (dst != cur) {
                if (cur >= 0) {
                    float* ap = &agg[((size_t)cur << 7) + c4];
                    if (curRS >= gbase && curRS + curCNT <= gbase + 32) {
                        *(float4*)ap = run;   // whole segment owned by this thread
                    } else {
                        atomicAdd(ap + 0, run.x);
                        atomicAdd(ap + 1, run.y);
                        atomicAdd(ap + 2, run.z);
                        atomicAdd(ap + 3, run.w);
                    }
                }
                cur = dst;
                curRS  = (dst >= 0) ? rowptr[dst] : 0;
                curCNT = (dst >= 0) ? counts[dst] : 0;
                run = make_float4(0.f, 0.f, 0.f, 0.f);
            }
            if (dst >= 0) {
                float4 w;
                w.x = fmaf(FR[j], T1[j].x - T0[j].x, T0[j].x);
                w.y = fmaf(FR[j], T1[j].y - T0[j].y, T0[j].y);
                w.z = fmaf(FR[j], T1[j].z - T0[j].z, T0[j].z);
                w.w = fmaf(FR[j], T1[j].w - T0[j].w, T0[j].w);
                run.x = fmaf(w.x, VL[j].x, run.x);
                run.y = fmaf(w.y, VL[j].y, run.y);
                run.z = fmaf(w.z, VL[j].z, run.z);
                run.w = fmaf(w.w, VL[j].w, run.w);
            }
        }
    }
    if (cur >= 0) {
        float* ap = &agg[((size_t)cur << 7) + c4];
        if (curRS >= gbase && curRS + curCNT <= gbase + 32) {
            *(float4*)ap = run;
        } else {
            atomicAdd(ap + 0, run.x);
            atomicAdd(ap + 1, run.y);
            atomicAdd(ap + 2, run.z);
            atomicAdd(ap + 3, run.w);
        }
    }
}

// ---------------- feature embedding ----------------
__global__ void k_fe1(const float* __restrict__ x, const float* __restrict__ w,
                      const float* __restrict__ b, float* __restrict__ h, int N) {
    int idx = blockIdx.x * 256 + threadIdx.x;
    if (idx >= N * 64) return;
    int n = idx >> 6, c = idx & 63;
    const float* xr = x + (size_t)n * 28;
    float acc = b[c];
    #pragma unroll
    for (int k = 0; k < 28; k++) acc = fmaf(xr[k], w[k * 64 + c], acc);
    h[idx] = acc;
}

__global__ void k_bnstat(const float* __restrict__ h, float* __restrict__ stats, int N) {
    __shared__ float s_s[256], s_q[256];
    int tid = threadIdx.x;
    int c = tid & 63, g = tid >> 6;
    float s = 0.f, q = 0.f;
    for (int n = blockIdx.x * 4 + g; n < N; n += gridDim.x * 4) {
        float v = h[(size_t)n * 64 + c];
        s += v; q += v * v;
    }
    s_s[tid] = s; s_q[tid] = q;
    __syncthreads();
    if (tid < 64) {
        s = s_s[tid] + s_s[tid + 64] + s_s[tid + 128] + s_s[tid + 192];
        q = s_q[tid] + s_q[tid + 64] + s_q[tid + 128] + s_q[tid + 192];
        atomicAdd(&stats[tid], s);
        atomicAdd(&stats[64 + tid], q);
    }
}

__global__ void k_bnfin(const float* __restrict__ stats, float* __restrict__ prm,
                        const float* __restrict__ gamma, const float* __restrict__ beta,
                        float invN) {
    int c = threadIdx.x;  // 64 threads
    float mu = stats[c] * invN;
    float var = stats[64 + c] * invN - mu * mu;
    float sc = gamma[c] * rsqrtf(var + 1e-5f);
    prm[c] = sc;
    prm[64 + c] = beta[c] - mu * sc;
}

__global__ void k_fe2(const float* __restrict__ h, const float* __restrict__ prm,
                      const float* __restrict__ w, const float* __restrict__ b,
                      float* __restrict__ v, int N) {
    int idx = blockIdx.x * 256 + threadIdx.x;
    if (idx >= N * 128) return;
    int n = idx >> 7, c = idx & 127;
    const float* hr = h + ((size_t)n << 6);
    float acc = b[c];
    #pragma unroll 8
    for (int k = 0; k < 64; k++) {
        float hv = fmaxf(fmaf(hr[k], prm[k], prm[64 + k]), 0.f);
        acc = fmaf(hv, w[(k << 7) + c], acc);
    }
    v[idx] = fmaxf(acc, 0.f);
}

// ---------------- register-blocked [N,128]x[128,128] GEMM, fp16 output (vlin) ----------------
__launch_bounds__(256, 4)
__global__ void k_gemm_rb(const float* __restrict__ A, const float* __restrict__ W,
                          ushort* __restrict__ C, int N) {
    __shared__ float sA[64 * 128];  // 32 KB
    const int tid = threadIdx.x;
    const int n0 = blockIdx.x * 64;

    for (int i = tid; i < 64 * 32; i += 256) {
        int row = i >> 5, cq = (i & 31) << 2;
        int gr = n0 + row;
        float4 val = (gr < N) ? *(const float4*)&A[((size_t)gr << 7) + cq]
                              : make_float4(0.f, 0.f, 0.f, 0.f);
        *(float4*)&sA[row * 128 + cq] = val;
    }
    __syncthreads();

    const int cg = tid & 31, rg = tid >> 5;
    const int r0 = rg << 3;
    const int c4 = cg << 2;

    float4 acc[8];
    #pragma unroll
    for (int i = 0; i < 8; i++) acc[i] = make_float4(0.f, 0.f, 0.f, 0.f);
    #pragma unroll 4
    for (int k = 0; k < 128; k++) {
        float4 wv = *(const float4*)&W[(k << 7) + c4];
        #pragma unroll
        for (int i = 0; i < 8; i++) {
            float a = sA[(r0 + i) * 128 + k];
            acc[i].x = fmaf(a, wv.x, acc[i].x);
            acc[i].y = fmaf(a, wv.y, acc[i].y);
            acc[i].z = fmaf(a, wv.z, acc[i].z);
            acc[i].w = fmaf(a, wv.w, acc[i].w);
        }
    }
    #pragma unroll
    for (int i = 0; i < 8; i++) {
        int gr = n0 + r0 + i;
        if (gr < N) st_h4(&C[((size_t)gr << 7) + c4], acc[i]);
    }
}

// ---------------- fused layer update: 3 GEMMs, single 32KB LDS buffer ----------------
// t = ssp(agg@W1+b1); v_new = t@W2+b2 + v_old; vlin(fp16) = v_new@lin (if lin != null)
__launch_bounds__(256, 4)
__global__ void k_update(const float* __restrict__ agg,
                         const float* __restrict__ w1, const float* __restrict__ b1,
                         const float* __restrict__ w2, const float* __restrict__ b2,
                         float* __restrict__ v,
                         const float* __restrict__ lin, ushort* __restrict__ vlin, int N) {
    __shared__ float sA[64 * 128];  // 32 KB, serially holds agg -> t -> v_new
    const int tid = threadIdx.x;
    const int n0 = blockIdx.x * 64;

    for (int i = tid; i < 64 * 32; i += 256) {
        int row = i >> 5, cq = (i & 31) << 2;
        int gr = n0 + row;
        float4 val = (gr < N) ? *(const float4*)&agg[((size_t)gr << 7) + cq]
                              : make_float4(0.f, 0.f, 0.f, 0.f);
        *(float4*)&sA[row * 128 + cq] = val;
    }
    __syncthreads();

    const int cg = tid & 31, rg = tid >> 5;
    const int r0 = rg << 3;
    const int c4 = cg << 2;

    // GEMM 1: t = ssp(agg@W1 + b1) -> regs
    float4 acc[8];
    {
        float4 b1v = *(const float4*)&b1[c4];
        #pragma unroll
        for (int i = 0; i < 8; i++) acc[i] = b1v;
        #pragma unroll 4
        for (int k = 0; k < 128; k++) {
            float4 wv = *(const float4*)&w1[(k << 7) + c4];
            #pragma unroll
            for (int i = 0; i < 8; i++) {
                float a = sA[(r0 + i) * 128 + k];
                acc[i].x = fmaf(a, wv.x, acc[i].x);
                acc[i].y = fmaf(a, wv.y, acc[i].y);
                acc[i].z = fmaf(a, wv.z, acc[i].z);
                acc[i].w = fmaf(a, wv.w, acc[i].w);
            }
        }
    }
    __syncthreads();
    #pragma unroll
    for (int i = 0; i < 8; i++) {
        float4 t;
        t.x = sspf(acc[i].x); t.y = sspf(acc[i].y);
        t.z = sspf(acc[i].z); t.w = sspf(acc[i].w);
        *(float4*)&sA[(r0 + i) * 128 + c4] = t;
    }
    __syncthreads();

    // GEMM 2: v_new = t@W2 + b2 + v_old -> regs
    {
        float4 b2v = *(const float4*)&b2[c4];
        #pragma unroll
        for (int i = 0; i < 8; i++) acc[i] = b2v;
        #pragma unroll 4
        for (int k = 0; k < 128; k++) {
            float4 wv = *(const float4*)&w2[(k << 7) + c4];
            #pragma unroll
            for (int i = 0; i < 8; i++) {
                float a = sA[(r0 + i) * 128 + k];
                acc[i].x = fmaf(a, wv.x, acc[i].x);
                acc[i].y = fmaf(a, wv.y, acc[i].y);
                acc[i].z = fmaf(a, wv.z, acc[i].z);
                acc[i].w = fmaf(a, wv.w, acc[i].w);
            }
        }
    }
    __syncthreads();
    #pragma unroll
    for (int i = 0; i < 8; i++) {
        int gr = n0 + r0 + i;
        float4 vn = make_float4(0.f, 0.f, 0.f, 0.f);
        if (gr < N) {
            float4 vo = *(const float4*)&v[((size_t)gr << 7) + c4];
            vn.x = acc[i].x + vo.x; vn.y = acc[i].y + vo.y;
            vn.z = acc[i].z + vo.z; vn.w = acc[i].w + vo.w;
            *(float4*)&v[((size_t)gr << 7) + c4] = vn;
        }
        *(float4*)&sA[(r0 + i) * 128 + c4] = vn;
    }
    if (!lin) return;
    __syncthreads();

    // GEMM 3: vlin(fp16) = v_new @ lin
    {
        #pragma unroll
        for (int i = 0; i < 8; i++) acc[i] = make_float4(0.f, 0.f, 0.f, 0.f);
        #pragma unroll 4
        for (int k = 0; k < 128; k++) {
            float4 wv = *(const float4*)&lin[(k << 7) + c4];
            #pragma unroll
            for (int i = 0; i < 8; i++) {
                float a = sA[(r0 + i) * 128 + k];
                acc[i].x = fmaf(a, wv.x, acc[i].x);
                acc[i].y = fmaf(a, wv.y, acc[i].y);
                acc[i].z = fmaf(a, wv.z, acc[i].z);
                acc[i].w = fmaf(a, wv.w, acc[i].w);
            }
        }
        #pragma unroll
        for (int i = 0; i < 8; i++) {
            int gr = n0 + r0 + i;
            if (gr < N) st_h4(&vlin[((size_t)gr << 7) + c4], acc[i]);
        }
    }
}

// ---------------- fused readout: one wave per node ----------------
// t = ssp(v@u1_w + u1_b) (64); s = t@u2_w + u2_b (32); atomicAdd per graph
__global__ void k_uout(const float* __restrict__ v, const float* __restrict__ u1w,
                       const float* __restrict__ u1b, const float* __restrict__ u2w,
                       const float* __restrict__ u2b, const int* __restrict__ batch,
                       float* __restrict__ out, int N) {
    __shared__ float sT[4][64];
    const int wv = threadIdx.x >> 6, lane = threadIdx.x & 63;
    const int n = blockIdx.x * 4 + wv;
    const bool ok = n < N;

    float t = 0.f;
    if (ok) {
        const float* vr = v + ((size_t)n << 7);
        float acc = u1b[lane];
        #pragma unroll 4
        for (int k = 0; k < 128; k++) acc = fmaf(vr[k], u1w[(k << 6) + lane], acc);
        t = sspf(acc);
    }
    sT[wv][lane] = t;
    __syncthreads();
    if (ok && lane < 32) {
        float acc = u2b[lane];
        #pragma unroll
        for (int k = 0; k < 64; k++) acc = fmaf(sT[wv][k], u2w[(k << 5) + lane], acc);
        atomicAdd(&out[(size_t)batch[n] * 32 + lane], acc);
    }
}

extern "C" void kernel_launch(void* const* d_in, const int* in_sizes, int n_in,
                              void* d_out, int out_size, void* d_ws, size_t ws_size,
                              hipStream_t stream) {
    const float* x      = (const float*)d_in[0];
    const float* pos    = (const float*)d_in[1];
    const int*   batch  = (const int*)d_in[2];
    const int*   ei     = (const int*)d_in[3];
    const float* fe_w1  = (const float*)d_in[4];
    const float* fe_b1  = (const float*)d_in[5];
    const float* bn_g   = (const float*)d_in[6];
    const float* bn_b   = (const float*)d_in[7];
    const float* fe_w2  = (const float*)d_in[8];
    const float* fe_b2  = (const float*)d_in[9];
    const float* lin_w  = (const float*)d_in[10];
    const float* mlp_w1 = (const float*)d_in[11];
    const float* mlp_b1 = (const float*)d_in[12];
    const float* mlp_w2 = (const float*)d_in[13];
    const float* mlp_b2 = (const float*)d_in[14];
    const float* v1_w   = (const float*)d_in[15];
    const float* v1_b   = (const float*)d_in[16];
    const float* v2_w   = (const float*)d_in[17];
    const float* v2_b   = (const float*)d_in[18];
    const float* u1_w   = (const float*)d_in[19];
    const float* u1_b   = (const float*)d_in[20];
    const float* u2_w   = (const float*)d_in[21];
    const float* u2_b   = (const float*)d_in[22];

    const int N = in_sizes[0] / 28;
    const int E = in_sizes[3] / 2;
    const int NB1 = (N + 1023) / 1024;

    char* ws = (char*)d_ws;
    size_t o = 0;
    auto alloc = [&](size_t bytes) { void* p = ws + o; o += (bytes + 255) & ~(size_t)255; return p; };
    int*    counts = (int*)   alloc((size_t)N * 4);
    int*    cursor = (int*)   alloc((size_t)N * 4);
    int*    rowptr = (int*)   alloc((size_t)N * 4);
    int*    bsum   = (int*)   alloc((size_t)NB1 * 4);
    int*    s_src  = (int*)   alloc((size_t)E * 4);
    int*    s_dst  = (int*)   alloc((size_t)E * 4);
    float*  s_fid  = (float*) alloc((size_t)E * 4);
    float*  stats  = (float*) alloc(128 * 4);
    float*  prm    = (float*) alloc(128 * 4);
    ushort* tab    = (ushort*)alloc((size_t)LAY * K_TAB * 128 * 2);  // 12 MB fp16
    float*  v      = (float*) alloc((size_t)N * 128 * 4);
    ushort* vlin   = (ushort*)alloc((size_t)N * 128 * 2);            // fp16
    float*  agg    = (float*) alloc((size_t)N * 128 * 4);
    float*  h      = agg;     // alias: h (N x 64 f32) used only before agg's first use
    int*    locex  = s_src;   // alias: scan scratch consumed before scatter writes s_src

    // -------- one-time edge sort (dst-ordered CSR) --------
    hipMemsetAsync(counts, 0, (size_t)N * 4, stream);
    k_hist<<<(E + 255) / 256, 256, 0, stream>>>(ei, counts, E);
    k_scan1<<<NB1, 1024, 0, stream>>>(counts, locex, bsum, N);
    k_scan2<<<1, 1024, 0, stream>>>(bsum, NB1);
    k_scan3<<<(N + 255) / 256, 256, 0, stream>>>(locex, bsum, cursor, rowptr, N);
    k_scatter<<<(E + 255) / 256, 256, 0, stream>>>(ei, pos, cursor, s_src, s_dst, s_fid, E);

    // -------- gate tables for all layers (fp16) --------
    k_tab_all<<<LAY * 256, 256, 0, stream>>>(mlp_w1, mlp_b1, mlp_w2, mlp_b2, tab);

    // -------- feature embedding --------
    hipMemsetAsync(stats, 0, 128 * 4, stream);
    k_fe1<<<(N * 64 + 255) / 256, 256, 0, stream>>>(x, fe_w1, fe_b1, h, N);
    k_bnstat<<<256, 256, 0, stream>>>(h, stats, N);
    k_bnfin<<<1, 64, 0, stream>>>(stats, prm, bn_g, bn_b, 1.0f / (float)N);
    k_fe2<<<(N * 128 + 255) / 256, 256, 0, stream>>>(h, prm, fe_w2, fe_b2, v, N);

    // vlin for layer 0
    const int gblk = (N + 63) / 64;
    k_gemm_rb<<<gblk, 256, 0, stream>>>(v, lin_w, vlin, N);

    // -------- interaction layers --------
    for (int l = 0; l < LAY; l++) {
        hipMemsetAsync(agg, 0, (size_t)N * 128 * 4, stream);
        k_edge_tab<<<(E + 255) / 256, 256, 0, stream>>>(
            s_src, s_dst, s_fid, rowptr, counts, vlin,
            tab + (size_t)l * K_TAB * 128, agg, E);
        const float* lin_next = (l + 1 < LAY) ? lin_w + (size_t)(l + 1) * 128 * 128 : nullptr;
        k_update<<<gblk, 256, 0, stream>>>(
            agg, v1_w + (size_t)l * 128 * 128, v1_b + (size_t)l * 128,
            v2_w + (size_t)l * 128 * 128, v2_b + (size_t)l * 128,
            v, lin_next, vlin, N);
    }

    // -------- fused readout --------
    hipMemsetAsync(d_out, 0, (size_t)out_size * 4, stream);
    k_uout<<<(N + 3) / 4, 256, 0, stream>>>(v, u1_w, u1_b, u2_w, u2_b, batch, (float*)d_out, N);
}

// Round 7
// 1242.174 us; speedup vs baseline: 9.6674x; 1.2004x over previous
//
#include <hip/hip_runtime.h>
#include <hip/hip_fp16.h>
#include <math.h>

#define DEV __device__ __forceinline__

constexpr int NGAUSS = 50;
constexpr int LAY = 6;
constexpr int K_TAB = 8192;
constexpr float DMAX = 40.0f;
constexpr float TSCALE = (float)(K_TAB - 1) / DMAX;   // fid = d * TSCALE
constexpr float STEP = 6.0f / 49.0f;
constexpr float COEFF = -0.5f / (STEP * STEP);
constexpr float LN2F = 0.69314718055994531f;
constexpr float PI_OVER_CUT = 0.52359877559829887f;  // pi/6

DEV float sspf(float x) {
    float ax = fabsf(x);
    float e = __expf(-ax);
    return fmaxf(x, 0.f) + __logf(1.f + e) - LN2F;
}

// ---- fp16 pack/unpack helpers (storage fp16, math f32) ----
DEV float4 ld_h4(const ushort* p) {          // 8B load -> 4 floats
    uint2 r = *(const uint2*)p;
    __half2 a = __builtin_bit_cast(__half2, r.x);
    __half2 b = __builtin_bit_cast(__half2, r.y);
    float2 fa = __half22float2(a), fb = __half22float2(b);
    return make_float4(fa.x, fa.y, fb.x, fb.y);
}
DEV void st_h4(ushort* p, float4 v) {        // 4 floats -> 8B store
    uint2 r;
    r.x = __builtin_bit_cast(uint, __float22half2_rn(make_float2(v.x, v.y)));
    r.y = __builtin_bit_cast(uint, __float22half2_rn(make_float2(v.z, v.w)));
    *(uint2*)p = r;
}

// ---------------- edge sort pre-pass (once per call) ----------------
__global__ void k_hist(const int* __restrict__ ei, int* __restrict__ counts, int E) {
    int e = blockIdx.x * 256 + threadIdx.x;
    if (e < E) atomicAdd(&counts[ei[E + e]], 1);
}

// hierarchical scan: stage 1 — per-block (1024 elems) local exclusive scan + block sums
__global__ void k_scan1(const int* __restrict__ counts, int* __restrict__ locex,
                        int* __restrict__ bsum, int n) {
    __shared__ int s_wsum[16];
    const int tid = threadIdx.x;
    const int i = blockIdx.x * 1024 + tid;
    const int lane = tid & 63, wv = tid >> 6;
    int v = (i < n) ? counts[i] : 0;
    int x = v;
    #pragma unroll
    for (int off = 1; off < 64; off <<= 1) {
        int y = __shfl_up(x, off, 64);
        if (lane >= off) x += y;
    }
    if (lane == 63) s_wsum[wv] = x;
    __syncthreads();
    if (wv == 0 && lane < 16) {
        int wval = s_wsum[lane];
        int wx = wval;
        #pragma unroll
        for (int off = 1; off < 16; off <<= 1) {
            int wy = __shfl_up(wx, off, 16);
            if (lane >= off) wx += wy;
        }
        s_wsum[lane] = wx - wval;  // exclusive wave prefix
    }
    __syncthreads();
    if (i < n) locex[i] = s_wsum[wv] + x - v;
    if (tid == 1023) bsum[blockIdx.x] = s_wsum[15] + x;
}

// stage 2 — exclusive scan of block sums (nb <= 1024), one block
__global__ void k_scan2(int* __restrict__ bsum, int nb) {
    __shared__ int s_wsum[16];
    const int tid = threadIdx.x;
    const int lane = tid & 63, wv = tid >> 6;
    int v = (tid < nb) ? bsum[tid] : 0;
    int x = v;
    #pragma unroll
    for (int off = 1; off < 64; off <<= 1) {
        int y = __shfl_up(x, off, 64);
        if (lane >= off) x += y;
    }
    if (lane == 63) s_wsum[wv] = x;
    __syncthreads();
    if (wv == 0 && lane < 16) {
        int wval = s_wsum[lane];
        int wx = wval;
        #pragma unroll
        for (int off = 1; off < 16; off <<= 1) {
            int wy = __shfl_up(wx, off, 16);
            if (lane >= off) wx += wy;
        }
        s_wsum[lane] = wx - wval;
    }
    __syncthreads();
    if (tid < nb) bsum[tid] = s_wsum[wv] + x - v;  // exclusive
}

// stage 3 — add block offsets, emit cursor + pristine rowptr
__global__ void k_scan3(const int* __restrict__ locex, const int* __restrict__ bsumex,
                        int* __restrict__ cursor, int* __restrict__ rowptr, int n) {
    int i = blockIdx.x * 256 + threadIdx.x;
    if (i >= n) return;
    int e = locex[i] + bsumex[i >> 10];
    cursor[i] = e;
    rowptr[i] = e;
}

// scatter edges into dst-sorted slots; fuse geometry -> table coordinate fid
__global__ void k_scatter(const int* __restrict__ ei, const float* __restrict__ pos,
                          int* __restrict__ cursor, int* __restrict__ s_src,
                          float* __restrict__ s_fid, int E) {
    int e = blockIdx.x * 256 + threadIdx.x;
    if (e >= E) return;
    int r = ei[e], c = ei[E + e];
    int p = atomicAdd(&cursor[c], 1);
    float dx = pos[3 * r + 0] - pos[3 * c + 0];
    float dy = pos[3 * r + 1] - pos[3 * c + 1];
    float dz = pos[3 * r + 2] - pos[3 * c + 2];
    float d = sqrtf(dx * dx + dy * dy + dz * dz);
    s_src[p] = r;
    s_fid[p] = fminf(d * TSCALE, (float)(K_TAB - 2) + 0.999f);
}

// ---------------- gate table build (fp16 output), ALL layers in one launch ----------------
__launch_bounds__(256)
__global__ void k_tab_all(const float* __restrict__ w1A, const float* __restrict__ b1A,
                          const float* __restrict__ w2A, const float* __restrict__ b2A,
                          ushort* __restrict__ tabA) {
    const int layer = blockIdx.x >> 8;
    const int k0 = (blockIdx.x & 255) * 32;
    const float* w1 = w1A + (size_t)layer * NGAUSS * 128;
    const float* b1 = b1A + (size_t)layer * 128;
    const float* w2 = w2A + (size_t)layer * 128 * 128;
    const float* b2 = b2A + (size_t)layer * 128;
    ushort* tab = tabA + (size_t)layer * K_TAB * 128;

    __shared__ float s_demb[32][NGAUSS];  // 6.4 KB
    __shared__ float s_t1[32][128];       // 16 KB
    const int tid = threadIdx.x;

    for (int i = tid; i < 32 * NGAUSS; i += 256) {
        int r = i / NGAUSS, g = i - r * NGAUSS;
        float d = (float)(k0 + r) * (1.0f / TSCALE);
        float t = d - g * STEP;
        s_demb[r][g] = __expf(COEFF * t * t);
    }
    __syncthreads();

    const int cg = tid & 31, rg = tid >> 5;
    const int r0 = rg << 2;        // 4 rows per thread
    const int c4 = cg << 2;

    float4 b1v = *(const float4*)&b1[c4];
    float4 acc[4];
    #pragma unroll
    for (int i = 0; i < 4; i++) acc[i] = b1v;
    #pragma unroll 2
    for (int k = 0; k < NGAUSS; k++) {
        float4 wv = *(const float4*)&w1[(k << 7) + c4];
        #pragma unroll
        for (int i = 0; i < 4; i++) {
            float dv = s_demb[r0 + i][k];
            acc[i].x = fmaf(dv, wv.x, acc[i].x);
            acc[i].y = fmaf(dv, wv.y, acc[i].y);
            acc[i].z = fmaf(dv, wv.z, acc[i].z);
            acc[i].w = fmaf(dv, wv.w, acc[i].w);
        }
    }
    #pragma unroll
    for (int i = 0; i < 4; i++) {
        float4 t;
        t.x = sspf(acc[i].x); t.y = sspf(acc[i].y);
        t.z = sspf(acc[i].z); t.w = sspf(acc[i].w);
        *(float4*)&s_t1[r0 + i][c4] = t;
    }
    __syncthreads();

    float4 b2v = *(const float4*)&b2[c4];
    float4 a2[4];
    #pragma unroll
    for (int i = 0; i < 4; i++) a2[i] = b2v;
    #pragma unroll 4
    for (int k = 0; k < 128; k++) {
        float4 wv = *(const float4*)&w2[(k << 7) + c4];
        #pragma unroll
        for (int i = 0; i < 4; i++) {
            float tv = s_t1[r0 + i][k];
            a2[i].x = fmaf(tv, wv.x, a2[i].x);
            a2[i].y = fmaf(tv, wv.y, a2[i].y);
            a2[i].z = fmaf(tv, wv.z, a2[i].z);
            a2[i].w = fmaf(tv, wv.w, a2[i].w);
        }
    }
    #pragma unroll
    for (int i = 0; i < 4; i++) {
        int knot = k0 + r0 + i;
        float d = (float)knot * (1.0f / TSCALE);
        float cc = 0.5f * (__cosf(d * PI_OVER_CUT) + 1.0f);
        float4 o;
        o.x = a2[i].x * cc; o.y = a2[i].y * cc;
        o.z = a2[i].z * cc; o.w = a2[i].w * cc;
        st_h4(&tab[((size_t)knot << 7) + c4], o);
    }
}

// ---------------- node-centric CSR edge kernel: no atomics, no memset ----------------
// 64 nodes/block; half-wave (32 lanes x 4ch) walks each node's dst-sorted edge list
__launch_bounds__(256)
__global__ void k_edge_csr(const int* __restrict__ s_src, const float* __restrict__ s_fid,
                           const int* __restrict__ rowptr, const int* __restrict__ counts,
                           const ushort* __restrict__ vlin, const ushort* __restrict__ tab,
                           float* __restrict__ agg, int N) {
    const int tid = threadIdx.x;
    const int c4 = (tid & 31) << 2;
    const int rg = tid >> 5;
    const int nbase = blockIdx.x * 64 + rg * 8;
    const ushort* tabc = tab + c4;
    const ushort* vlc = vlin + c4;

    for (int i = 0; i < 8; i++) {
        int n = nbase + i;
        if (n >= N) return;
        int rs = rowptr[n];
        int re = rs + counts[n];
        float4 run = make_float4(0.f, 0.f, 0.f, 0.f);
        int e = rs;
        for (; e + 4 <= re; e += 4) {
            float4 T0[4], T1[4], VL[4];
            float FR[4];
            #pragma unroll
            for (int j = 0; j < 4; j++) {
                float fid = s_fid[e + j];
                int i0 = (int)fid;
                FR[j] = fid - (float)i0;
                const ushort* tp = tabc + ((size_t)i0 << 7);
                T0[j] = ld_h4(tp);
                T1[j] = ld_h4(tp + 128);
                VL[j] = ld_h4(vlc + ((size_t)s_src[e + j] << 7));
            }
            #pragma unroll
            for (int j = 0; j < 4; j++) {
                float4 w;
                w.x = fmaf(FR[j], T1[j].x - T0[j].x, T0[j].x);
                w.y = fmaf(FR[j], T1[j].y - T0[j].y, T0[j].y);
                w.z = fmaf(FR[j], T1[j].z - T0[j].z, T0[j].z);
                w.w = fmaf(FR[j], T1[j].w - T0[j].w, T0[j].w);
                run.x = fmaf(w.x, VL[j].x, run.x);
                run.y = fmaf(w.y, VL[j].y, run.y);
                run.z = fmaf(w.z, VL[j].z, run.z);
                run.w = fmaf(w.w, VL[j].w, run.w);
            }
        }
        for (; e < re; e++) {
            float fid = s_fid[e];
            int i0 = (int)fid;
            float fr = fid - (float)i0;
            const ushort* tp = tabc + ((size_t)i0 << 7);
            float4 t0 = ld_h4(tp);
            float4 t1 = ld_h4(tp + 128);
            float4 vl = ld_h4(vlc + ((size_t)s_src[e] << 7));
            float4 w;
            w.x = fmaf(fr, t1.x - t0.x, t0.x);
            w.y = fmaf(fr, t1.y - t0.y, t0.y);
            w.z = fmaf(fr, t1.z - t0.z, t0.z);
            w.w = fmaf(fr, t1.w - t0.w, t0.w);
            run.x = fmaf(w.x, vl.x, run.x);
            run.y = fmaf(w.y, vl.y, run.y);
            run.z = fmaf(w.z, vl.z, run.z);
            run.w = fmaf(w.w, vl.w, run.w);
        }
        *(float4*)&agg[((size_t)n << 7) + c4] = run;
    }
}

// ---------------- feature embedding ----------------
__global__ void k_fe1(const float* __restrict__ x, const float* __restrict__ w,
                      const float* __restrict__ b, float* __restrict__ h, int N) {
    int idx = blockIdx.x * 256 + threadIdx.x;
    if (idx >= N * 64) return;
    int n = idx >> 6, c = idx & 63;
    const float* xr = x + (size_t)n * 28;
    float acc = b[c];
    #pragma unroll
    for (int k = 0; k < 28; k++) acc = fmaf(xr[k], w[k * 64 + c], acc);
    h[idx] = acc;
}

__global__ void k_bnstat(const float* __restrict__ h, float* __restrict__ stats, int N) {
    __shared__ float s_s[256], s_q[256];
    int tid = threadIdx.x;
    int c = tid & 63, g = tid >> 6;
    float s = 0.f, q = 0.f;
    for (int n = blockIdx.x * 4 + g; n < N; n += gridDim.x * 4) {
        float v = h[(size_t)n * 64 + c];
        s += v; q += v * v;
    }
    s_s[tid] = s; s_q[tid] = q;
    __syncthreads();
    if (tid < 64) {
        s = s_s[tid] + s_s[tid + 64] + s_s[tid + 128] + s_s[tid + 192];
        q = s_q[tid] + s_q[tid + 64] + s_q[tid + 128] + s_q[tid + 192];
        atomicAdd(&stats[tid], s);
        atomicAdd(&stats[64 + tid], q);
    }
}

__global__ void k_bnfin(const float* __restrict__ stats, float* __restrict__ prm,
                        const float* __restrict__ gamma, const float* __restrict__ beta,
                        float invN) {
    int c = threadIdx.x;  // 64 threads
    float mu = stats[c] * invN;
    float var = stats[64 + c] * invN - mu * mu;
    float sc = gamma[c] * rsqrtf(var + 1e-5f);
    prm[c] = sc;
    prm[64 + c] = beta[c] - mu * sc;
}

__global__ void k_fe2(const float* __restrict__ h, const float* __restrict__ prm,
                      const float* __restrict__ w, const float* __restrict__ b,
                      float* __restrict__ v, int N) {
    int idx = blockIdx.x * 256 + threadIdx.x;
    if (idx >= N * 128) return;
    int n = idx >> 7, c = idx & 127;
    const float* hr = h + ((size_t)n << 6);
    float acc = b[c];
    #pragma unroll 8
    for (int k = 0; k < 64; k++) {
        float hv = fmaxf(fmaf(hr[k], prm[k], prm[64 + k]), 0.f);
        acc = fmaf(hv, w[(k << 7) + c], acc);
    }
    v[idx] = fmaxf(acc, 0.f);
}

// ---------------- register-blocked [N,128]x[128,128] GEMM, fp16 output (vlin) ----------------
__launch_bounds__(256, 4)
__global__ void k_gemm_rb(const float* __restrict__ A, const float* __restrict__ W,
                          ushort* __restrict__ C, int N) {
    __shared__ float sA[64 * 128];  // 32 KB
    const int tid = threadIdx.x;
    const int n0 = blockIdx.x * 64;

    for (int i = tid; i < 64 * 32; i += 256) {
        int row = i >> 5, cq = (i & 31) << 2;
        int gr = n0 + row;
        float4 val = (gr < N) ? *(const float4*)&A[((size_t)gr << 7) + cq]
                              : make_float4(0.f, 0.f, 0.f, 0.f);
        *(float4*)&sA[row * 128 + cq] = val;
    }
    __syncthreads();

    const int cg = tid & 31, rg = tid >> 5;
    const int r0 = rg << 3;
    const int c4 = cg << 2;

    float4 acc[8];
    #pragma unroll
    for (int i = 0; i < 8; i++) acc[i] = make_float4(0.f, 0.f, 0.f, 0.f);
    #pragma unroll 4
    for (int k = 0; k < 128; k++) {
        float4 wv = *(const float4*)&W[(k << 7) + c4];
        #pragma unroll
        for (int i = 0; i < 8; i++) {
            float a = sA[(r0 + i) * 128 + k];
            acc[i].x = fmaf(a, wv.x, acc[i].x);
            acc[i].y = fmaf(a, wv.y, acc[i].y);
            acc[i].z = fmaf(a, wv.z, acc[i].z);
            acc[i].w = fmaf(a, wv.w, acc[i].w);
        }
    }
    #pragma unroll
    for (int i = 0; i < 8; i++) {
        int gr = n0 + r0 + i;
        if (gr < N) st_h4(&C[((size_t)gr << 7) + c4], acc[i]);
    }
}

// ---------------- fused layer update: 3 GEMMs, single 32KB LDS buffer ----------------
__launch_bounds__(256, 4)
__global__ void k_update(const float* __restrict__ agg,
                         const float* __restrict__ w1, const float* __restrict__ b1,
                         const float* __restrict__ w2, const float* __restrict__ b2,
                         float* __restrict__ v,
                         const float* __restrict__ lin, ushort* __restrict__ vlin, int N) {
    __shared__ float sA[64 * 128];  // 32 KB, serially holds agg -> t -> v_new
    const int tid = threadIdx.x;
    const int n0 = blockIdx.x * 64;

    for (int i = tid; i < 64 * 32; i += 256) {
        int row = i >> 5, cq = (i & 31) << 2;
        int gr = n0 + row;
        float4 val = (gr < N) ? *(const float4*)&agg[((size_t)gr << 7) + cq]
                              : make_float4(0.f, 0.f, 0.f, 0.f);
        *(float4*)&sA[row * 128 + cq] = val;
    }
    __syncthreads();

    const int cg = tid & 31, rg = tid >> 5;
    const int r0 = rg << 3;
    const int c4 = cg << 2;

    // GEMM 1: t = ssp(agg@W1 + b1) -> regs
    float4 acc[8];
    {
        float4 b1v = *(const float4*)&b1[c4];
        #pragma unroll
        for (int i = 0; i < 8; i++) acc[i] = b1v;
        #pragma unroll 4
        for (int k = 0; k < 128; k++) {
            float4 wv = *(const float4*)&w1[(k << 7) + c4];
            #pragma unroll
            for (int i = 0; i < 8; i++) {
                float a = sA[(r0 + i) * 128 + k];
                acc[i].x = fmaf(a, wv.x, acc[i].x);
                acc[i].y = fmaf(a, wv.y, acc[i].y);
                acc[i].z = fmaf(a, wv.z, acc[i].z);
                acc[i].w = fmaf(a, wv.w, acc[i].w);
            }
        }
    }
    __syncthreads();
    #pragma unroll
    for (int i = 0; i < 8; i++) {
        float4 t;
        t.x = sspf(acc[i].x); t.y = sspf(acc[i].y);
        t.z = sspf(acc[i].z); t.w = sspf(acc[i].w);
        *(float4*)&sA[(r0 + i) * 128 + c4] = t;
    }
    __syncthreads();

    // GEMM 2: v_new = t@W2 + b2 + v_old -> regs
    {
        float4 b2v = *(const float4*)&b2[c4];
        #pragma unroll
        for (int i = 0; i < 8; i++) acc[i] = b2v;
        #pragma unroll 4
        for (int k = 0; k < 128; k++) {
            float4 wv = *(const float4*)&w2[(k << 7) + c4];
            #pragma unroll
            for (int i = 0; i < 8; i++) {
                float a = sA[(r0 + i) * 128 + k];
                acc[i].x = fmaf(a, wv.x, acc[i].x);
                acc[i].y = fmaf(a, wv.y, acc[i].y);
                acc[i].z = fmaf(a, wv.z, acc[i].z);
                acc[i].w = fmaf(a, wv.w, acc[i].w);
            }
        }
    }
    __syncthreads();
    #pragma unroll
    for (int i = 0; i < 8; i++) {
        int gr = n0 + r0 + i;
        float4 vn = make_float4(0.f, 0.f, 0.f, 0.f);
        if (gr < N) {
            float4 vo = *(const float4*)&v[((size_t)gr << 7) + c4];
            vn.x = acc[i].x + vo.x; vn.y = acc[i].y + vo.y;
            vn.z = acc[i].z + vo.z; vn.w = acc[i].w + vo.w;
            *(float4*)&v[((size_t)gr << 7) + c4] = vn;
        }
        *(float4*)&sA[(r0 + i) * 128 + c4] = vn;
    }
    if (!lin) return;
    __syncthreads();

    // GEMM 3: vlin(fp16) = v_new @ lin
    {
        #pragma unroll
        for (int i = 0; i < 8; i++) acc[i] = make_float4(0.f, 0.f, 0.f, 0.f);
        #pragma unroll 4
        for (int k = 0; k < 128; k++) {
            float4 wv = *(const float4*)&lin[(k << 7) + c4];
            #pragma unroll
            for (int i = 0; i < 8; i++) {
                float a = sA[(r0 + i) * 128 + k];
                acc[i].x = fmaf(a, wv.x, acc[i].x);
                acc[i].y = fmaf(a, wv.y, acc[i].y);
                acc[i].z = fmaf(a, wv.z, acc[i].z);
                acc[i].w = fmaf(a, wv.w, acc[i].w);
            }
        }
        #pragma unroll
        for (int i = 0; i < 8; i++) {
            int gr = n0 + r0 + i;
            if (gr < N) st_h4(&vlin[((size_t)gr << 7) + c4], acc[i]);
        }
    }
}

// ---------------- tiled fused readout ----------------
// stage v tile; t = ssp(v@u1w+u1b) [64x64]; s = t@u2w+u2b [64x32]; batch-segmented atomics
__launch_bounds__(256, 4)
__global__ void k_uout(const float* __restrict__ v, const float* __restrict__ u1w,
                       const float* __restrict__ u1b, const float* __restrict__ u2w,
                       const float* __restrict__ u2b, const int* __restrict__ batch,
                       float* __restrict__ out, int N) {
    __shared__ float sA[64 * 128];  // 32 KB: v tile, then reused for t tile (64x64)
    const int tid = threadIdx.x;
    const int n0 = blockIdx.x * 64;

    for (int i = tid; i < 64 * 32; i += 256) {
        int row = i >> 5, cq = (i & 31) << 2;
        int gr = n0 + row;
        float4 val = (gr < N) ? *(const float4*)&v[((size_t)gr << 7) + cq]
                              : make_float4(0.f, 0.f, 0.f, 0.f);
        *(float4*)&sA[row * 128 + cq] = val;
    }
    __syncthreads();

    const int cg = tid & 31, rg = tid >> 5;
    const int r0 = rg << 3;
    const int c2 = cg << 1;

    // GEMM 1: [64,128]@[128,64], thread = 8 rows x 2 cols
    float2 acc[8];
    {
        float2 b1v = *(const float2*)&u1b[c2];
        #pragma unroll
        for (int i = 0; i < 8; i++) acc[i] = b1v;
        #pragma unroll 4
        for (int k = 0; k < 128; k++) {
            float2 wv = *(const float2*)&u1w[(k << 6) + c2];
            #pragma unroll
            for (int i = 0; i < 8; i++) {
                float a = sA[(r0 + i) * 128 + k];
                acc[i].x = fmaf(a, wv.x, acc[i].x);
                acc[i].y = fmaf(a, wv.y, acc[i].y);
            }
        }
    }
    __syncthreads();
    #pragma unroll
    for (int i = 0; i < 8; i++) {
        sA[(r0 + i) * 64 + c2 + 0] = sspf(acc[i].x);
        sA[(r0 + i) * 64 + c2 + 1] = sspf(acc[i].y);
    }
    __syncthreads();

    // GEMM 2: [64,64]@[64,32], thread = 8 rows x 1 col (cg)
    float acc2[8];
    {
        float bb = u2b[cg];
        #pragma unroll
        for (int i = 0; i < 8; i++) acc2[i] = bb;
        #pragma unroll 4
        for (int k = 0; k < 64; k++) {
            float wv = u2w[(k << 5) + cg];
            #pragma unroll
            for (int i = 0; i < 8; i++)
                acc2[i] = fmaf(sA[(r0 + i) * 64 + k], wv, acc2[i]);
        }
    }

    // batch-segmented atomic flush (batch sorted)
    int cur = -1;
    float run = 0.f;
    #pragma unroll
    for (int i = 0; i < 8; i++) {
        int gr = n0 + r0 + i;
        int g = (gr < N) ? batch[gr] : -1;
        if (g != cur) {
            if (cur >= 0) atomicAdd(&out[(size_t)cur * 32 + cg], run);
            cur = g;
            run = 0.f;
        }
        if (g >= 0) run += acc2[i];
    }
    if (cur >= 0) atomicAdd(&out[(size_t)cur * 32 + cg], run);
}

extern "C" void kernel_launch(void* const* d_in, const int* in_sizes, int n_in,
                              void* d_out, int out_size, void* d_ws, size_t ws_size,
                              hipStream_t stream) {
    const float* x      = (const float*)d_in[0];
    const float* pos    = (const float*)d_in[1];
    const int*   batch  = (const int*)d_in[2];
    const int*   ei     = (const int*)d_in[3];
    const float* fe_w1  = (const float*)d_in[4];
    const float* fe_b1  = (const float*)d_in[5];
    const float* bn_g   = (const float*)d_in[6];
    const float* bn_b   = (const float*)d_in[7];
    const float* fe_w2  = (const float*)d_in[8];
    const float* fe_b2  = (const float*)d_in[9];
    const float* lin_w  = (const float*)d_in[10];
    const float* mlp_w1 = (const float*)d_in[11];
    const float* mlp_b1 = (const float*)d_in[12];
    const float* mlp_w2 = (const float*)d_in[13];
    const float* mlp_b2 = (const float*)d_in[14];
    const float* v1_w   = (const float*)d_in[15];
    const float* v1_b   = (const float*)d_in[16];
    const float* v2_w   = (const float*)d_in[17];
    const float* v2_b   = (const float*)d_in[18];
    const float* u1_w   = (const float*)d_in[19];
    const float* u1_b   = (const float*)d_in[20];
    const float* u2_w   = (const float*)d_in[21];
    const float* u2_b   = (const float*)d_in[22];

    const int N = in_sizes[0] / 28;
    const int E = in_sizes[3] / 2;
    const int NB1 = (N + 1023) / 1024;

    char* ws = (char*)d_ws;
    size_t o = 0;
    auto alloc = [&](size_t bytes) { void* p = ws + o; o += (bytes + 255) & ~(size_t)255; return p; };
    int*    counts = (int*)   alloc((size_t)N * 4);
    int*    cursor = (int*)   alloc((size_t)N * 4);
    int*    rowptr = (int*)   alloc((size_t)N * 4);
    int*    bsum   = (int*)   alloc((size_t)NB1 * 4);
    int*    s_src  = (int*)   alloc((size_t)E * 4);
    float*  s_fid  = (float*) alloc((size_t)E * 4);
    float*  stats  = (float*) alloc(128 * 4);
    float*  prm    = (float*) alloc(128 * 4);
    ushort* tab    = (ushort*)alloc((size_t)LAY * K_TAB * 128 * 2);  // 12 MB fp16
    float*  v      = (float*) alloc((size_t)N * 128 * 4);
    ushort* vlin   = (ushort*)alloc((size_t)N * 128 * 2);            // fp16
    float*  agg    = (float*) alloc((size_t)N * 128 * 4);
    float*  h      = agg;     // alias: h (N x 64 f32) used only before agg's first use
    int*    locex  = (int*)   alloc((size_t)N * 4);  // scan scratch

    // -------- one-time edge sort (dst-ordered CSR) --------
    hipMemsetAsync(counts, 0, (size_t)N * 4, stream);
    k_hist<<<(E + 255) / 256, 256, 0, stream>>>(ei, counts, E);
    k_scan1<<<NB1, 1024, 0, stream>>>(counts, locex, bsum, N);
    k_scan2<<<1, 1024, 0, stream>>>(bsum, NB1);
    k_scan3<<<(N + 255) / 256, 256, 0, stream>>>(locex, bsum, cursor, rowptr, N);
    k_scatter<<<(E + 255) / 256, 256, 0, stream>>>(ei, pos, cursor, s_src, s_fid, E);

    // -------- gate tables for all layers (fp16) --------
    k_tab_all<<<LAY * 256, 256, 0, stream>>>(mlp_w1, mlp_b1, mlp_w2, mlp_b2, tab);

    // -------- feature embedding --------
    hipMemsetAsync(stats, 0, 128 * 4, stream);
    k_fe1<<<(N * 64 + 255) / 256, 256, 0, stream>>>(x, fe_w1, fe_b1, h, N);
    k_bnstat<<<256, 256, 0, stream>>>(h, stats, N);
    k_bnfin<<<1, 64, 0, stream>>>(stats, prm, bn_g, bn_b, 1.0f / (float)N);
    k_fe2<<<(N * 128 + 255) / 256, 256, 0, stream>>>(h, prm, fe_w2, fe_b2, v, N);

    // vlin for layer 0
    const int gblk = (N + 63) / 64;
    k_gemm_rb<<<gblk, 256, 0, stream>>>(v, lin_w, vlin, N);

    // -------- interaction layers (no memsets: agg fully overwritten) --------
    for (int l = 0; l < LAY; l++) {
        k_edge_csr<<<gblk, 256, 0, stream>>>(
            s_src, s_fid, rowptr, counts, vlin,
            tab + (size_t)l * K_TAB * 128, agg, N);
        const float* lin_next = (l + 1 < LAY) ? lin_w + (size_t)(l + 1) * 128 * 128 : nullptr;
        k_update<<<gblk, 256, 0, stream>>>(
            agg, v1_w + (size_t)l * 128 * 128, v1_b + (size_t)l * 128,
            v2_w + (size_t)l * 128 * 128, v2_b + (size_t)l * 128,
            v, lin_next, vlin, N);
    }

    // -------- fused readout --------
    hipMemsetAsync(d_out, 0, (size_t)out_size * 4, stream);
    k_uout<<<gblk, 256, 0, stream>>>(v, u1_w, u1_b, u2_w, u2_b, batch, (float*)d_out, N);
}

// Round 8
// 1097.325 us; speedup vs baseline: 10.9435x; 1.1320x over previous
//
#include <hip/hip_runtime.h>
#include <hip/hip_fp16.h>
#include <math.h>

#define DEV __device__ __forceinline__

constexpr int NGAUSS = 50;
constexpr int LAY = 6;
constexpr int K_TAB = 8192;
constexpr float DMAX = 40.0f;
constexpr float TSCALE = (float)(K_TAB - 1) / DMAX;   // fid = d * TSCALE
constexpr float STEP = 6.0f / 49.0f;
constexpr float COEFF = -0.5f / (STEP * STEP);
constexpr float LN2F = 0.69314718055994531f;
constexpr float PI_OVER_CUT = 0.52359877559829887f;  // pi/6

using f16x8 = __attribute__((ext_vector_type(8))) _Float16;
using f16x4 = __attribute__((ext_vector_type(4))) _Float16;
using f32x4 = __attribute__((ext_vector_type(4))) float;

#define MFMA16(a, b, c) __builtin_amdgcn_mfma_f32_16x16x32_f16(a, b, c, 0, 0, 0)

DEV float sspf(float x) {
    float ax = fabsf(x);
    float e = __expf(-ax);
    return fmaxf(x, 0.f) + __logf(1.f + e) - LN2F;
}

// ---- fp16 pack/unpack helpers (storage fp16, math f32) ----
DEV float4 ld_h4(const ushort* p) {          // 8B load -> 4 floats
    uint2 r = *(const uint2*)p;
    __half2 a = __builtin_bit_cast(__half2, r.x);
    __half2 b = __builtin_bit_cast(__half2, r.y);
    float2 fa = __half22float2(a), fb = __half22float2(b);
    return make_float4(fa.x, fa.y, fb.x, fb.y);
}
DEV void st_h4(ushort* p, float4 v) {        // 4 floats -> 8B store
    uint2 r;
    r.x = __builtin_bit_cast(uint, __float22half2_rn(make_float2(v.x, v.y)));
    r.y = __builtin_bit_cast(uint, __float22half2_rn(make_float2(v.z, v.w)));
    *(uint2*)p = r;
}

// ---------------- weight convert+transpose (fp32 [K][C] -> fp16 [C][K]) ----------------
__global__ void k_cvtT128(const float* __restrict__ src, ushort* __restrict__ dst) {
    const float* s = src + (size_t)blockIdx.x * 16384;
    ushort* d = dst + (size_t)blockIdx.x * 16384;
    for (int i = threadIdx.x; i < 16384; i += 256) {
        int k = i >> 7, c = i & 127;
        d[(c << 7) + k] = __builtin_bit_cast(ushort, (_Float16)s[i]);
    }
}
__global__ void k_cvtT_fe(const float* __restrict__ src, ushort* __restrict__ dst) {
    // fe_w2: [64][128] -> dst[c(128)][k(64)]
    for (int i = threadIdx.x; i < 8192; i += 256) {
        int k = i >> 7, c = i & 127;
        dst[(c << 6) + k] = __builtin_bit_cast(ushort, (_Float16)src[i]);
    }
}

// ---------------- edge sort pre-pass (once per call) ----------------
__global__ void k_hist(const int* __restrict__ ei, int* __restrict__ counts, int E) {
    int e = blockIdx.x * 256 + threadIdx.x;
    if (e < E) atomicAdd(&counts[ei[E + e]], 1);
}

__global__ void k_scan1(const int* __restrict__ counts, int* __restrict__ locex,
                        int* __restrict__ bsum, int n) {
    __shared__ int s_wsum[16];
    const int tid = threadIdx.x;
    const int i = blockIdx.x * 1024 + tid;
    const int lane = tid & 63, wv = tid >> 6;
    int v = (i < n) ? counts[i] : 0;
    int x = v;
    #pragma unroll
    for (int off = 1; off < 64; off <<= 1) {
        int y = __shfl_up(x, off, 64);
        if (lane >= off) x += y;
    }
    if (lane == 63) s_wsum[wv] = x;
    __syncthreads();
    if (wv == 0 && lane < 16) {
        int wval = s_wsum[lane];
        int wx = wval;
        #pragma unroll
        for (int off = 1; off < 16; off <<= 1) {
            int wy = __shfl_up(wx, off, 16);
            if (lane >= off) wx += wy;
        }
        s_wsum[lane] = wx - wval;
    }
    __syncthreads();
    if (i < n) locex[i] = s_wsum[wv] + x - v;
    if (tid == 1023) bsum[blockIdx.x] = s_wsum[15] + x;
}

__global__ void k_scan2(int* __restrict__ bsum, int nb) {
    __shared__ int s_wsum[16];
    const int tid = threadIdx.x;
    const int lane = tid & 63, wv = tid >> 6;
    int v = (tid < nb) ? bsum[tid] : 0;
    int x = v;
    #pragma unroll
    for (int off = 1; off < 64; off <<= 1) {
        int y = __shfl_up(x, off, 64);
        if (lane >= off) x += y;
    }
    if (lane == 63) s_wsum[wv] = x;
    __syncthreads();
    if (wv == 0 && lane < 16) {
        int wval = s_wsum[lane];
        int wx = wval;
        #pragma unroll
        for (int off = 1; off < 16; off <<= 1) {
            int wy = __shfl_up(wx, off, 16);
            if (lane >= off) wx += wy;
        }
        s_wsum[lane] = wx - wval;
    }
    __syncthreads();
    if (tid < nb) bsum[tid] = s_wsum[wv] + x - v;
}

__global__ void k_scan3(const int* __restrict__ locex, const int* __restrict__ bsumex,
                        int* __restrict__ cursor, int* __restrict__ rowptr, int n) {
    int i = blockIdx.x * 256 + threadIdx.x;
    if (i >= n) return;
    int e = locex[i] + bsumex[i >> 10];
    cursor[i] = e;
    rowptr[i] = e;
}

__global__ void k_scatter(const int* __restrict__ ei, const float* __restrict__ pos,
                          int* __restrict__ cursor, int* __restrict__ s_src,
                          float* __restrict__ s_fid, int E) {
    int e = blockIdx.x * 256 + threadIdx.x;
    if (e >= E) return;
    int r = ei[e], c = ei[E + e];
    int p = atomicAdd(&cursor[c], 1);
    float dx = pos[3 * r + 0] - pos[3 * c + 0];
    float dy = pos[3 * r + 1] - pos[3 * c + 1];
    float dz = pos[3 * r + 2] - pos[3 * c + 2];
    float d = sqrtf(dx * dx + dy * dy + dz * dz);
    s_src[p] = r;
    s_fid[p] = fminf(d * TSCALE, (float)(K_TAB - 2) + 0.999f);
}

// ---------------- gate table build (fp16 output), ALL layers in one launch ----------------
__launch_bounds__(256)
__global__ void k_tab_all(const float* __restrict__ w1A, const float* __restrict__ b1A,
                          const float* __restrict__ w2A, const float* __restrict__ b2A,
                          ushort* __restrict__ tabA) {
    const int layer = blockIdx.x >> 8;
    const int k0 = (blockIdx.x & 255) * 32;
    const float* w1 = w1A + (size_t)layer * NGAUSS * 128;
    const float* b1 = b1A + (size_t)layer * 128;
    const float* w2 = w2A + (size_t)layer * 128 * 128;
    const float* b2 = b2A + (size_t)layer * 128;
    ushort* tab = tabA + (size_t)layer * K_TAB * 128;

    __shared__ float s_demb[32][NGAUSS];
    __shared__ float s_t1[32][128];
    const int tid = threadIdx.x;

    for (int i = tid; i < 32 * NGAUSS; i += 256) {
        int r = i / NGAUSS, g = i - r * NGAUSS;
        float d = (float)(k0 + r) * (1.0f / TSCALE);
        float t = d - g * STEP;
        s_demb[r][g] = __expf(COEFF * t * t);
    }
    __syncthreads();

    const int cg = tid & 31, rg = tid >> 5;
    const int r0 = rg << 2;
    const int c4 = cg << 2;

    float4 b1v = *(const float4*)&b1[c4];
    float4 acc[4];
    #pragma unroll
    for (int i = 0; i < 4; i++) acc[i] = b1v;
    #pragma unroll 2
    for (int k = 0; k < NGAUSS; k++) {
        float4 wv = *(const float4*)&w1[(k << 7) + c4];
        #pragma unroll
        for (int i = 0; i < 4; i++) {
            float dv = s_demb[r0 + i][k];
            acc[i].x = fmaf(dv, wv.x, acc[i].x);
            acc[i].y = fmaf(dv, wv.y, acc[i].y);
            acc[i].z = fmaf(dv, wv.z, acc[i].z);
            acc[i].w = fmaf(dv, wv.w, acc[i].w);
        }
    }
    #pragma unroll
    for (int i = 0; i < 4; i++) {
        float4 t;
        t.x = sspf(acc[i].x); t.y = sspf(acc[i].y);
        t.z = sspf(acc[i].z); t.w = sspf(acc[i].w);
        *(float4*)&s_t1[r0 + i][c4] = t;
    }
    __syncthreads();

    float4 b2v = *(const float4*)&b2[c4];
    float4 a2[4];
    #pragma unroll
    for (int i = 0; i < 4; i++) a2[i] = b2v;
    #pragma unroll 4
    for (int k = 0; k < 128; k++) {
        float4 wv = *(const float4*)&w2[(k << 7) + c4];
        #pragma unroll
        for (int i = 0; i < 4; i++) {
            float tv = s_t1[r0 + i][k];
            a2[i].x = fmaf(tv, wv.x, a2[i].x);
            a2[i].y = fmaf(tv, wv.y, a2[i].y);
            a2[i].z = fmaf(tv, wv.z, a2[i].z);
            a2[i].w = fmaf(tv, wv.w, a2[i].w);
        }
    }
    #pragma unroll
    for (int i = 0; i < 4; i++) {
        int knot = k0 + r0 + i;
        float d = (float)knot * (1.0f / TSCALE);
        float cc = 0.5f * (__cosf(d * PI_OVER_CUT) + 1.0f);
        float4 o;
        o.x = a2[i].x * cc; o.y = a2[i].y * cc;
        o.z = a2[i].z * cc; o.w = a2[i].w * cc;
        st_h4(&tab[((size_t)knot << 7) + c4], o);
    }
}

// ---------------- node-centric CSR edge kernel: no atomics, no memset ----------------
__launch_bounds__(256)
__global__ void k_edge_csr(const int* __restrict__ s_src, const float* __restrict__ s_fid,
                           const int* __restrict__ rowptr, const int* __restrict__ counts,
                           const ushort* __restrict__ vlin, const ushort* __restrict__ tab,
                           float* __restrict__ agg, int N) {
    const int tid = threadIdx.x;
    const int c4 = (tid & 31) << 2;
    const int rg = tid >> 5;
    const int nbase = blockIdx.x * 64 + rg * 8;
    const ushort* tabc = tab + c4;
    const ushort* vlc = vlin + c4;

    for (int i = 0; i < 8; i++) {
        int n = nbase + i;
        if (n >= N) return;
        int rs = rowptr[n];
        int re = rs + counts[n];
        float4 run = make_float4(0.f, 0.f, 0.f, 0.f);
        int e = rs;
        for (; e + 4 <= re; e += 4) {
            float4 T0[4], T1[4], VL[4];
            float FR[4];
            #pragma unroll
            for (int j = 0; j < 4; j++) {
                float fid = s_fid[e + j];
                int i0 = (int)fid;
                FR[j] = fid - (float)i0;
                const ushort* tp = tabc + ((size_t)i0 << 7);
                T0[j] = ld_h4(tp);
                T1[j] = ld_h4(tp + 128);
                VL[j] = ld_h4(vlc + ((size_t)s_src[e + j] << 7));
            }
            #pragma unroll
            for (int j = 0; j < 4; j++) {
                float4 w;
                w.x = fmaf(FR[j], T1[j].x - T0[j].x, T0[j].x);
                w.y = fmaf(FR[j], T1[j].y - T0[j].y, T0[j].y);
                w.z = fmaf(FR[j], T1[j].z - T0[j].z, T0[j].z);
                w.w = fmaf(FR[j], T1[j].w - T0[j].w, T0[j].w);
                run.x = fmaf(w.x, VL[j].x, run.x);
                run.y = fmaf(w.y, VL[j].y, run.y);
                run.z = fmaf(w.z, VL[j].z, run.z);
                run.w = fmaf(w.w, VL[j].w, run.w);
            }
        }
        for (; e < re; e++) {
            float fid = s_fid[e];
            int i0 = (int)fid;
            float fr = fid - (float)i0;
            const ushort* tp = tabc + ((size_t)i0 << 7);
            float4 t0 = ld_h4(tp);
            float4 t1 = ld_h4(tp + 128);
            float4 vl = ld_h4(vlc + ((size_t)s_src[e] << 7));
            float4 w;
            w.x = fmaf(fr, t1.x - t0.x, t0.x);
            w.y = fmaf(fr, t1.y - t0.y, t0.y);
            w.z = fmaf(fr, t1.z - t0.z, t0.z);
            w.w = fmaf(fr, t1.w - t0.w, t0.w);
            run.x = fmaf(w.x, vl.x, run.x);
            run.y = fmaf(w.y, vl.y, run.y);
            run.z = fmaf(w.z, vl.z, run.z);
            run.w = fmaf(w.w, vl.w, run.w);
        }
        *(float4*)&agg[((size_t)n << 7) + c4] = run;
    }
}

// ---------------- feature embedding ----------------
__global__ void k_fe1(const float* __restrict__ x, const float* __restrict__ w,
                      const float* __restrict__ b, float* __restrict__ h, int N) {
    int idx = blockIdx.x * 256 + threadIdx.x;
    if (idx >= N * 64) return;
    int n = idx >> 6, c = idx & 63;
    const float* xr = x + (size_t)n * 28;
    float acc = b[c];
    #pragma unroll
    for (int k = 0; k < 28; k++) acc = fmaf(xr[k], w[k * 64 + c], acc);
    h[idx] = acc;
}

__global__ void k_bnstat(const float* __restrict__ h, float* __restrict__ stats, int N) {
    __shared__ float s_s[256], s_q[256];
    int tid = threadIdx.x;
    int c = tid & 63, g = tid >> 6;
    float s = 0.f, q = 0.f;
    for (int n = blockIdx.x * 4 + g; n < N; n += gridDim.x * 4) {
        float v = h[(size_t)n * 64 + c];
        s += v; q += v * v;
    }
    s_s[tid] = s; s_q[tid] = q;
    __syncthreads();
    if (tid < 64) {
        s = s_s[tid] + s_s[tid + 64] + s_s[tid + 128] + s_s[tid + 192];
        q = s_q[tid] + s_q[tid + 64] + s_q[tid + 128] + s_q[tid + 192];
        atomicAdd(&stats[tid], s);
        atomicAdd(&stats[64 + tid], q);
    }
}

__global__ void k_bnfin(const float* __restrict__ stats, float* __restrict__ prm,
                        const float* __restrict__ gamma, const float* __restrict__ beta,
                        float invN) {
    int c = threadIdx.x;  // 64 threads
    float mu = stats[c] * invN;
    float var = stats[64 + c] * invN - mu * mu;
    float sc = gamma[c] * rsqrtf(var + 1e-5f);
    prm[c] = sc;
    prm[64 + c] = beta[c] - mu * sc;
}

// ---------------- MFMA fe2: v = relu( relu(bn(h)) @ fe_w2 + b2 ), K=64 ----------------
__launch_bounds__(256, 4)
__global__ void k_fe2(const float* __restrict__ h, const float* __restrict__ prm,
                      const ushort* __restrict__ w2T, const float* __restrict__ b2,
                      float* __restrict__ v, int N) {
    constexpr int LDP = 72;
    __shared__ _Float16 sH[64 * LDP];
    const int tid = threadIdx.x;
    const int n0 = blockIdx.x * 64;

    for (int i = tid; i < 64 * 16; i += 256) {
        int row = i >> 4, c4 = (i & 15) << 2;
        int gr = n0 + row;
        float4 hv = (gr < N) ? *(const float4*)&h[((size_t)gr << 6) + c4]
                             : make_float4(0.f, 0.f, 0.f, 0.f);
        float4 sc = *(const float4*)&prm[c4];
        float4 sh = *(const float4*)&prm[64 + c4];
        f16x4 o;
        o[0] = (_Float16)fmaxf(fmaf(hv.x, sc.x, sh.x), 0.f);
        o[1] = (_Float16)fmaxf(fmaf(hv.y, sc.y, sh.y), 0.f);
        o[2] = (_Float16)fmaxf(fmaf(hv.z, sc.z, sh.z), 0.f);
        o[3] = (_Float16)fmaxf(fmaf(hv.w, sc.w, sh.w), 0.f);
        *(f16x4*)&sH[row * LDP + c4] = o;
    }
    __syncthreads();

    const int wid = tid >> 6, lane = tid & 63;
    const int lr = lane & 15, lg = lane >> 4;
    const int kof = lg << 3;
    const int arow = wid * 16 + lr;
    const int drow0 = wid * 16 + (lg << 2);

    f16x8 a0 = *(const f16x8*)&sH[arow * LDP + kof];
    f16x8 a1 = *(const f16x8*)&sH[arow * LDP + 32 + kof];

    #pragma unroll
    for (int n = 0; n < 8; n++) {
        const ushort* bp = w2T + (((size_t)(n << 4) + lr) << 6);
        f32x4 c = {0.f, 0.f, 0.f, 0.f};
        c = MFMA16(a0, *(const f16x8*)(bp + kof), c);
        c = MFMA16(a1, *(const f16x8*)(bp + 32 + kof), c);
        int col = (n << 4) + lr;
        float bb = b2[col];
        #pragma unroll
        for (int r = 0; r < 4; r++) {
            int gr = n0 + drow0 + r;
            if (gr < N) v[((size_t)gr << 7) + col] = fmaxf(c[r] + bb, 0.f);
        }
    }
}

// ---------------- MFMA single GEMM: vlin(fp16) = v @ lin, K=128 ----------------
__launch_bounds__(256, 4)
__global__ void k_gemm_rb(const float* __restrict__ A, const ushort* __restrict__ wT,
                          ushort* __restrict__ C, int N) {
    constexpr int LDP = 136;
    __shared__ _Float16 sA[64 * LDP];
    const int tid = threadIdx.x;
    const int n0 = blockIdx.x * 64;

    for (int i = tid; i < 64 * 32; i += 256) {
        int row = i >> 5, c4 = (i & 31) << 2;
        int gr = n0 + row;
        float4 val = (gr < N) ? *(const float4*)&A[((size_t)gr << 7) + c4]
                              : make_float4(0.f, 0.f, 0.f, 0.f);
        f16x4 o;
        o[0] = (_Float16)val.x; o[1] = (_Float16)val.y;
        o[2] = (_Float16)val.z; o[3] = (_Float16)val.w;
        *(f16x4*)&sA[row * LDP + c4] = o;
    }
    __syncthreads();

    const int wid = tid >> 6, lane = tid & 63;
    const int lr = lane & 15, lg = lane >> 4;
    const int kof = lg << 3;
    const int arow = wid * 16 + lr;
    const int drow0 = wid * 16 + (lg << 2);

    f16x8 a0 = *(const f16x8*)&sA[arow * LDP + kof];
    f16x8 a1 = *(const f16x8*)&sA[arow * LDP + 32 + kof];
    f16x8 a2 = *(const f16x8*)&sA[arow * LDP + 64 + kof];
    f16x8 a3 = *(const f16x8*)&sA[arow * LDP + 96 + kof];

    #pragma unroll
    for (int n = 0; n < 8; n++) {
        const ushort* bp = wT + (((size_t)(n << 4) + lr) << 7);
        f32x4 c = {0.f, 0.f, 0.f, 0.f};
        c = MFMA16(a0, *(const f16x8*)(bp + kof), c);
        c = MFMA16(a1, *(const f16x8*)(bp + 32 + kof), c);
        c = MFMA16(a2, *(const f16x8*)(bp + 64 + kof), c);
        c = MFMA16(a3, *(const f16x8*)(bp + 96 + kof), c);
        int col = (n << 4) + lr;
        #pragma unroll
        for (int r = 0; r < 4; r++) {
            int gr = n0 + drow0 + r;
            if (gr < N) C[((size_t)gr << 7) + col] =
                __builtin_bit_cast(ushort, (_Float16)c[r]);
        }
    }
}

// ---------------- MFMA fused layer update: 3 GEMMs ----------------
// t = ssp(agg@W1+b1); v_new = t@W2+b2 + v_old; vlin(fp16) = v_new@lin (if lin)
__launch_bounds__(256, 4)
__global__ void k_update(const float* __restrict__ agg,
                         const ushort* __restrict__ w1T, const float* __restrict__ b1,
                         const ushort* __restrict__ w2T, const float* __restrict__ b2,
                         float* __restrict__ v,
                         const ushort* __restrict__ linT, ushort* __restrict__ vlin, int N) {
    constexpr int LDP = 136;
    __shared__ _Float16 sA[64 * LDP];   // 17.4 KB: agg -> t -> v_new (fp16)
    const int tid = threadIdx.x;
    const int n0 = blockIdx.x * 64;

    for (int i = tid; i < 64 * 32; i += 256) {
        int row = i >> 5, c4 = (i & 31) << 2;
        int gr = n0 + row;
        float4 val = (gr < N) ? *(const float4*)&agg[((size_t)gr << 7) + c4]
                              : make_float4(0.f, 0.f, 0.f, 0.f);
        f16x4 o;
        o[0] = (_Float16)val.x; o[1] = (_Float16)val.y;
        o[2] = (_Float16)val.z; o[3] = (_Float16)val.w;
        *(f16x4*)&sA[row * LDP + c4] = o;
    }
    __syncthreads();

    const int wid = tid >> 6, lane = tid & 63;
    const int lr = lane & 15, lg = lane >> 4;
    const int kof = lg << 3;
    const int arow = wid * 16 + lr;
    const int drow0 = wid * 16 + (lg << 2);

    f16x8 a0, a1, a2, a3;
    f32x4 acc[8];

    // ---- GEMM 1: t = ssp(agg @ W1 + b1) ----
    a0 = *(const f16x8*)&sA[arow * LDP + kof];
    a1 = *(const f16x8*)&sA[arow * LDP + 32 + kof];
    a2 = *(const f16x8*)&sA[arow * LDP + 64 + kof];
    a3 = *(const f16x8*)&sA[arow * LDP + 96 + kof];
    #pragma unroll
    for (int n = 0; n < 8; n++) {
        const ushort* bp = w1T + (((size_t)(n << 4) + lr) << 7);
        f32x4 c = {0.f, 0.f, 0.f, 0.f};
        c = MFMA16(a0, *(const f16x8*)(bp + kof), c);
        c = MFMA16(a1, *(const f16x8*)(bp + 32 + kof), c);
        c = MFMA16(a2, *(const f16x8*)(bp + 64 + kof), c);
        c = MFMA16(a3, *(const f16x8*)(bp + 96 + kof), c);
        acc[n] = c;
    }
    __syncthreads();
    #pragma unroll
    for (int n = 0; n < 8; n++) {
        int col = (n << 4) + lr;
        float bb = b1[col];
        #pragma unroll
        for (int r = 0; r < 4; r++)
            sA[(drow0 + r) * LDP + col] = (_Float16)sspf(acc[n][r] + bb);
    }
    __syncthreads();

    // ---- GEMM 2: v_new = t @ W2 + b2 + v_old ----
    a0 = *(const f16x8*)&sA[arow * LDP + kof];
    a1 = *(const f16x8*)&sA[arow * LDP + 32 + kof];
    a2 = *(const f16x8*)&sA[arow * LDP + 64 + kof];
    a3 = *(const f16x8*)&sA[arow * LDP + 96 + kof];
    #pragma unroll
    for (int n = 0; n < 8; n++) {
        const ushort* bp = w2T + (((size_t)(n << 4) + lr) << 7);
        f32x4 c = {0.f, 0.f, 0.f, 0.f};
        c = MFMA16(a0, *(const f16x8*)(bp + kof), c);
        c = MFMA16(a1, *(const f16x8*)(bp + 32 + kof), c);
        c = MFMA16(a2, *(const f16x8*)(bp + 64 + kof), c);
        c = MFMA16(a3, *(const f16x8*)(bp + 96 + kof), c);
        acc[n] = c;
    }
    __syncthreads();
    #pragma unroll
    for (int n = 0; n < 8; n++) {
        int col = (n << 4) + lr;
        float bb = b2[col];
        #pragma unroll
        for (int r = 0; r < 4; r++) {
            int gr = n0 + drow0 + r;
            float vn = 0.f;
            if (gr < N) {
                vn = acc[n][r] + bb + v[((size_t)gr << 7) + col];
                v[((size_t)gr << 7) + col] = vn;
            }
            sA[(drow0 + r) * LDP + col] = (_Float16)vn;
        }
    }
    if (!linT) return;
    __syncthreads();

    // ---- GEMM 3: vlin(fp16) = v_new @ lin ----
    a0 = *(const f16x8*)&sA[arow * LDP + kof];
    a1 = *(const f16x8*)&sA[arow * LDP + 32 + kof];
    a2 = *(const f16x8*)&sA[arow * LDP + 64 + kof];
    a3 = *(const f16x8*)&sA[arow * LDP + 96 + kof];
    #pragma unroll
    for (int n = 0; n < 8; n++) {
        const ushort* bp = linT + (((size_t)(n << 4) + lr) << 7);
        f32x4 c = {0.f, 0.f, 0.f, 0.f};
        c = MFMA16(a0, *(const f16x8*)(bp + kof), c);
        c = MFMA16(a1, *(const f16x8*)(bp + 32 + kof), c);
        c = MFMA16(a2, *(const f16x8*)(bp + 64 + kof), c);
        c = MFMA16(a3, *(const f16x8*)(bp + 96 + kof), c);
        int col = (n << 4) + lr;
        #pragma unroll
        for (int r = 0; r < 4; r++) {
            int gr = n0 + drow0 + r;
            if (gr < N) vlin[((size_t)gr << 7) + col] =
                __builtin_bit_cast(ushort, (_Float16)c[r]);
        }
    }
}

// ---------------- tiled fused readout ----------------
__launch_bounds__(256, 4)
__global__ void k_uout(const float* __restrict__ v, const float* __restrict__ u1w,
                       const float* __restrict__ u1b, const float* __restrict__ u2w,
                       const float* __restrict__ u2b, const int* __restrict__ batch,
                       float* __restrict__ out, int N) {
    __shared__ float sA[64 * 128];
    const int tid = threadIdx.x;
    const int n0 = blockIdx.x * 64;

    for (int i = tid; i < 64 * 32; i += 256) {
        int row = i >> 5, cq = (i & 31) << 2;
        int gr = n0 + row;
        float4 val = (gr < N) ? *(const float4*)&v[((size_t)gr << 7) + cq]
                              : make_float4(0.f, 0.f, 0.f, 0.f);
        *(float4*)&sA[row * 128 + cq] = val;
    }
    __syncthreads();

    const int cg = tid & 31, rg = tid >> 5;
    const int r0 = rg << 3;
    const int c2 = cg << 1;

    float2 acc[8];
    {
        float2 b1v = *(const float2*)&u1b[c2];
        #pragma unroll
        for (int i = 0; i < 8; i++) acc[i] = b1v;
        #pragma unroll 4
        for (int k = 0; k < 128; k++) {
            float2 wv = *(const float2*)&u1w[(k << 6) + c2];
            #pragma unroll
            for (int i = 0; i < 8; i++) {
                float a = sA[(r0 + i) * 128 + k];
                acc[i].x = fmaf(a, wv.x, acc[i].x);
                acc[i].y = fmaf(a, wv.y, acc[i].y);
            }
        }
    }
    __syncthreads();
    #pragma unroll
    for (int i = 0; i < 8; i++) {
        sA[(r0 + i) * 64 + c2 + 0] = sspf(acc[i].x);
        sA[(r0 + i) * 64 + c2 + 1] = sspf(acc[i].y);
    }
    __syncthreads();

    float acc2[8];
    {
        float bb = u2b[cg];
        #pragma unroll
        for (int i = 0; i < 8; i++) acc2[i] = bb;
        #pragma unroll 4
        for (int k = 0; k < 64; k++) {
            float wv = u2w[(k << 5) + cg];
            #pragma unroll
            for (int i = 0; i < 8; i++)
                acc2[i] = fmaf(sA[(r0 + i) * 64 + k], wv, acc2[i]);
        }
    }

    int cur = -1;
    float run = 0.f;
    #pragma unroll
    for (int i = 0; i < 8; i++) {
        int gr = n0 + r0 + i;
        int g = (gr < N) ? batch[gr] : -1;
        if (g != cur) {
            if (cur >= 0) atomicAdd(&out[(size_t)cur * 32 + cg], run);
            cur = g;
            run = 0.f;
        }
        if (g >= 0) run += acc2[i];
    }
    if (cur >= 0) atomicAdd(&out[(size_t)cur * 32 + cg], run);
}

extern "C" void kernel_launch(void* const* d_in, const int* in_sizes, int n_in,
                              void* d_out, int out_size, void* d_ws, size_t ws_size,
                              hipStream_t stream) {
    const float* x      = (const float*)d_in[0];
    const float* pos    = (const float*)d_in[1];
    const int*   batch  = (const int*)d_in[2];
    const int*   ei     = (const int*)d_in[3];
    const float* fe_w1  = (const float*)d_in[4];
    const float* fe_b1  = (const float*)d_in[5];
    const float* bn_g   = (const float*)d_in[6];
    const float* bn_b   = (const float*)d_in[7];
    const float* fe_w2  = (const float*)d_in[8];
    const float* fe_b2  = (const float*)d_in[9];
    const float* lin_w  = (const float*)d_in[10];
    const float* mlp_w1 = (const float*)d_in[11];
    const float* mlp_b1 = (const float*)d_in[12];
    const float* mlp_w2 = (const float*)d_in[13];
    const float* mlp_b2 = (const float*)d_in[14];
    const float* v1_w   = (const float*)d_in[15];
    const float* v1_b   = (const float*)d_in[16];
    const float* v2_w   = (const float*)d_in[17];
    const float* v2_b   = (const float*)d_in[18];
    const float* u1_w   = (const float*)d_in[19];
    const float* u1_b   = (const float*)d_in[20];
    const float* u2_w   = (const float*)d_in[21];
    const float* u2_b   = (const float*)d_in[22];

    const int N = in_sizes[0] / 28;
    const int E = in_sizes[3] / 2;
    const int NB1 = (N + 1023) / 1024;

    char* ws = (char*)d_ws;
    size_t o = 0;
    auto alloc = [&](size_t bytes) { void* p = ws + o; o += (bytes + 255) & ~(size_t)255; return p; };
    int*    counts = (int*)   alloc((size_t)N * 4);
    int*    cursor = (int*)   alloc((size_t)N * 4);
    int*    rowptr = (int*)   alloc((size_t)N * 4);
    int*    bsum   = (int*)   alloc((size_t)NB1 * 4);
    int*    s_src  = (int*)   alloc((size_t)E * 4);
    float*  s_fid  = (float*) alloc((size_t)E * 4);
    float*  stats  = (float*) alloc(128 * 4);
    float*  prm    = (float*) alloc(128 * 4);
    ushort* tab    = (ushort*)alloc((size_t)LAY * K_TAB * 128 * 2);  // 12 MB fp16
    float*  v      = (float*) alloc((size_t)N * 128 * 4);
    ushort* vlin   = (ushort*)alloc((size_t)N * 128 * 2);            // fp16
    float*  agg    = (float*) alloc((size_t)N * 128 * 4);
    float*  h      = agg;     // alias: h (N x 64 f32) used only before agg's first use
    int*    locex  = (int*)   alloc((size_t)N * 4);
    ushort* v1T    = (ushort*)alloc((size_t)LAY * 16384 * 2);   // fp16 transposed weights
    ushort* v2T    = (ushort*)alloc((size_t)LAY * 16384 * 2);
    ushort* linT   = (ushort*)alloc((size_t)LAY * 16384 * 2);
    ushort* fe2T   = (ushort*)alloc((size_t)8192 * 2);

    // -------- weight conversion (fp16, transposed) --------
    k_cvtT128<<<LAY, 256, 0, stream>>>(v1_w, v1T);
    k_cvtT128<<<LAY, 256, 0, stream>>>(v2_w, v2T);
    k_cvtT128<<<LAY, 256, 0, stream>>>(lin_w, linT);
    k_cvtT_fe<<<1, 256, 0, stream>>>(fe_w2, fe2T);

    // -------- one-time edge sort (dst-ordered CSR) --------
    hipMemsetAsync(counts, 0, (size_t)N * 4, stream);
    k_hist<<<(E + 255) / 256, 256, 0, stream>>>(ei, counts, E);
    k_scan1<<<NB1, 1024, 0, stream>>>(counts, locex, bsum, N);
    k_scan2<<<1, 1024, 0, stream>>>(bsum, NB1);
    k_scan3<<<(N + 255) / 256, 256, 0, stream>>>(locex, bsum, cursor, rowptr, N);
    k_scatter<<<(E + 255) / 256, 256, 0, stream>>>(ei, pos, cursor, s_src, s_fid, E);

    // -------- gate tables for all layers (fp16) --------
    k_tab_all<<<LAY * 256, 256, 0, stream>>>(mlp_w1, mlp_b1, mlp_w2, mlp_b2, tab);

    // -------- feature embedding --------
    hipMemsetAsync(stats, 0, 128 * 4, stream);
    k_fe1<<<(N * 64 + 255) / 256, 256, 0, stream>>>(x, fe_w1, fe_b1, h, N);
    k_bnstat<<<256, 256, 0, stream>>>(h, stats, N);
    k_bnfin<<<1, 64, 0, stream>>>(stats, prm, bn_g, bn_b, 1.0f / (float)N);
    const int gblk = (N + 63) / 64;
    k_fe2<<<gblk, 256, 0, stream>>>(h, prm, fe2T, fe_b2, v, N);

    // vlin for layer 0
    k_gemm_rb<<<gblk, 256, 0, stream>>>(v, linT, vlin, N);

    // -------- interaction layers --------
    for (int l = 0; l < LAY; l++) {
        k_edge_csr<<<gblk, 256, 0, stream>>>(
            s_src, s_fid, rowptr, counts, vlin,
            tab + (size_t)l * K_TAB * 128, agg, N);
        const ushort* lin_next = (l + 1 < LAY) ? linT + (size_t)(l + 1) * 16384 : nullptr;
        k_update<<<gblk, 256, 0, stream>>>(
            agg, v1T + (size_t)l * 16384, v1_b + (size_t)l * 128,
            v2T + (size_t)l * 16384, v2_b + (size_t)l * 128,
            v, lin_next, vlin, N);
    }

    // -------- fused readout --------
    hipMemsetAsync(d_out, 0, (size_t)out_size * 4, stream);
    k_uout<<<gblk, 256, 0, stream>>>(v, u1_w, u1_b, u2_w, u2_b, batch, (float*)d_out, N);
}

// Round 9
// 944.227 us; speedup vs baseline: 12.7179x; 1.1621x over previous
//
#include <hip/hip_runtime.h>
#include <hip/hip_fp16.h>
#include <math.h>

#define DEV __device__ __forceinline__

constexpr int NGAUSS = 50;
constexpr int LAY = 6;
constexpr int K_TAB = 8192;
constexpr float DMAX = 40.0f;
constexpr float TSCALE = (float)(K_TAB - 1) / DMAX;   // fid = d * TSCALE
constexpr float STEP = 6.0f / 49.0f;
constexpr float COEFF = -0.5f / (STEP * STEP);
constexpr float LN2F = 0.69314718055994531f;
constexpr float PI_OVER_CUT = 0.52359877559829887f;  // pi/6

using f16x8 = __attribute__((ext_vector_type(8))) _Float16;
using f16x4 = __attribute__((ext_vector_type(4))) _Float16;
using f32x4 = __attribute__((ext_vector_type(4))) float;

#define MFMA16(a, b, c) __builtin_amdgcn_mfma_f32_16x16x32_f16(a, b, c, 0, 0, 0)

DEV float sspf(float x) {
    float ax = fabsf(x);
    float e = __expf(-ax);
    return fmaxf(x, 0.f) + __logf(1.f + e) - LN2F;
}

// ---- fp16 pack/unpack helpers (storage fp16, math f32) ----
DEV float4 ld_h4(const ushort* p) {          // 8B load -> 4 floats
    uint2 r = *(const uint2*)p;
    __half2 a = __builtin_bit_cast(__half2, r.x);
    __half2 b = __builtin_bit_cast(__half2, r.y);
    float2 fa = __half22float2(a), fb = __half22float2(b);
    return make_float4(fa.x, fa.y, fb.x, fb.y);
}
DEV void st_h4(ushort* p, float4 v) {        // 4 floats -> 8B store
    uint2 r;
    r.x = __builtin_bit_cast(uint, __float22half2_rn(make_float2(v.x, v.y)));
    r.y = __builtin_bit_cast(uint, __float22half2_rn(make_float2(v.z, v.w)));
    *(uint2*)p = r;
}

// ---------------- weight convert+transpose (fp32 [K][C] -> fp16 [C][K]) ----------------
__global__ void k_cvtT128(const float* __restrict__ src, ushort* __restrict__ dst) {
    const float* s = src + (size_t)blockIdx.x * 16384;
    ushort* d = dst + (size_t)blockIdx.x * 16384;
    for (int i = threadIdx.x; i < 16384; i += 256) {
        int k = i >> 7, c = i & 127;
        d[(c << 7) + k] = __builtin_bit_cast(ushort, (_Float16)s[i]);
    }
}
__global__ void k_cvtT_fe(const float* __restrict__ src, ushort* __restrict__ dst) {
    // fe_w2: [64][128] -> dst[c(128)][k(64)]
    for (int i = threadIdx.x; i < 8192; i += 256) {
        int k = i >> 7, c = i & 127;
        dst[(c << 6) + k] = __builtin_bit_cast(ushort, (_Float16)src[i]);
    }
}

// ---------------- edge sort pre-pass (once per call) ----------------
__global__ void k_hist(const int* __restrict__ ei, int* __restrict__ counts, int E) {
    int e = blockIdx.x * 256 + threadIdx.x;
    if (e < E) atomicAdd(&counts[ei[E + e]], 1);
}

__global__ void k_scan1(const int* __restrict__ counts, int* __restrict__ locex,
                        int* __restrict__ bsum, int n) {
    __shared__ int s_wsum[16];
    const int tid = threadIdx.x;
    const int i = blockIdx.x * 1024 + tid;
    const int lane = tid & 63, wv = tid >> 6;
    int v = (i < n) ? counts[i] : 0;
    int x = v;
    #pragma unroll
    for (int off = 1; off < 64; off <<= 1) {
        int y = __shfl_up(x, off, 64);
        if (lane >= off) x += y;
    }
    if (lane == 63) s_wsum[wv] = x;
    __syncthreads();
    if (wv == 0 && lane < 16) {
        int wval = s_wsum[lane];
        int wx = wval;
        #pragma unroll
        for (int off = 1; off < 16; off <<= 1) {
            int wy = __shfl_up(wx, off, 16);
            if (lane >= off) wx += wy;
        }
        s_wsum[lane] = wx - wval;
    }
    __syncthreads();
    if (i < n) locex[i] = s_wsum[wv] + x - v;
    if (tid == 1023) bsum[blockIdx.x] = s_wsum[15] + x;
}

__global__ void k_scan2(int* __restrict__ bsum, int nb) {
    __shared__ int s_wsum[16];
    const int tid = threadIdx.x;
    const int lane = tid & 63, wv = tid >> 6;
    int v = (tid < nb) ? bsum[tid] : 0;
    int x = v;
    #pragma unroll
    for (int off = 1; off < 64; off <<= 1) {
        int y = __shfl_up(x, off, 64);
        if (lane >= off) x += y;
    }
    if (lane == 63) s_wsum[wv] = x;
    __syncthreads();
    if (wv == 0 && lane < 16) {
        int wval = s_wsum[lane];
        int wx = wval;
        #pragma unroll
        for (int off = 1; off < 16; off <<= 1) {
            int wy = __shfl_up(wx, off, 16);
            if (lane >= off) wx += wy;
        }
        s_wsum[lane] = wx - wval;
    }
    __syncthreads();
    if (tid < nb) bsum[tid] = s_wsum[wv] + x - v;
}

__global__ void k_scan3(const int* __restrict__ locex, const int* __restrict__ bsumex,
                        int* __restrict__ cursor, int* __restrict__ rowptr, int n) {
    int i = blockIdx.x * 256 + threadIdx.x;
    if (i >= n) return;
    int e = locex[i] + bsumex[i >> 10];
    cursor[i] = e;
    rowptr[i] = e;
}

__global__ void k_scatter(const int* __restrict__ ei, const float* __restrict__ pos,
                          int* __restrict__ cursor, int* __restrict__ s_src,
                          float* __restrict__ s_fid, int E) {
    int e = blockIdx.x * 256 + threadIdx.x;
    if (e >= E) return;
    int r = ei[e], c = ei[E + e];
    int p = atomicAdd(&cursor[c], 1);
    float dx = pos[3 * r + 0] - pos[3 * c + 0];
    float dy = pos[3 * r + 1] - pos[3 * c + 1];
    float dz = pos[3 * r + 2] - pos[3 * c + 2];
    float d = sqrtf(dx * dx + dy * dy + dz * dz);
    s_src[p] = r;
    s_fid[p] = fminf(d * TSCALE, (float)(K_TAB - 2) + 0.999f);
}

// ---------------- gate table build (fp16 output), ALL layers in one launch ----------------
__launch_bounds__(256)
__global__ void k_tab_all(const float* __restrict__ w1A, const float* __restrict__ b1A,
                          const float* __restrict__ w2A, const float* __restrict__ b2A,
                          ushort* __restrict__ tabA) {
    const int layer = blockIdx.x >> 8;
    const int k0 = (blockIdx.x & 255) * 32;
    const float* w1 = w1A + (size_t)layer * NGAUSS * 128;
    const float* b1 = b1A + (size_t)layer * 128;
    const float* w2 = w2A + (size_t)layer * 128 * 128;
    const float* b2 = b2A + (size_t)layer * 128;
    ushort* tab = tabA + (size_t)layer * K_TAB * 128;

    __shared__ float s_demb[32][NGAUSS];
    __shared__ float s_t1[32][128];
    const int tid = threadIdx.x;

    for (int i = tid; i < 32 * NGAUSS; i += 256) {
        int r = i / NGAUSS, g = i - r * NGAUSS;
        float d = (float)(k0 + r) * (1.0f / TSCALE);
        float t = d - g * STEP;
        s_demb[r][g] = __expf(COEFF * t * t);
    }
    __syncthreads();

    const int cg = tid & 31, rg = tid >> 5;
    const int r0 = rg << 2;
    const int c4 = cg << 2;

    float4 b1v = *(const float4*)&b1[c4];
    float4 acc[4];
    #pragma unroll
    for (int i = 0; i < 4; i++) acc[i] = b1v;
    #pragma unroll 2
    for (int k = 0; k < NGAUSS; k++) {
        float4 wv = *(const float4*)&w1[(k << 7) + c4];
        #pragma unroll
        for (int i = 0; i < 4; i++) {
            float dv = s_demb[r0 + i][k];
            acc[i].x = fmaf(dv, wv.x, acc[i].x);
            acc[i].y = fmaf(dv, wv.y, acc[i].y);
            acc[i].z = fmaf(dv, wv.z, acc[i].z);
            acc[i].w = fmaf(dv, wv.w, acc[i].w);
        }
    }
    #pragma unroll
    for (int i = 0; i < 4; i++) {
        float4 t;
        t.x = sspf(acc[i].x); t.y = sspf(acc[i].y);
        t.z = sspf(acc[i].z); t.w = sspf(acc[i].w);
        *(float4*)&s_t1[r0 + i][c4] = t;
    }
    __syncthreads();

    float4 b2v = *(const float4*)&b2[c4];
    float4 a2[4];
    #pragma unroll
    for (int i = 0; i < 4; i++) a2[i] = b2v;
    #pragma unroll 4
    for (int k = 0; k < 128; k++) {
        float4 wv = *(const float4*)&w2[(k << 7) + c4];
        #pragma unroll
        for (int i = 0; i < 4; i++) {
            float tv = s_t1[r0 + i][k];
            a2[i].x = fmaf(tv, wv.x, a2[i].x);
            a2[i].y = fmaf(tv, wv.y, a2[i].y);
            a2[i].z = fmaf(tv, wv.z, a2[i].z);
            a2[i].w = fmaf(tv, wv.w, a2[i].w);
        }
    }
    #pragma unroll
    for (int i = 0; i < 4; i++) {
        int knot = k0 + r0 + i;
        float d = (float)knot * (1.0f / TSCALE);
        float cc = 0.5f * (__cosf(d * PI_OVER_CUT) + 1.0f);
        float4 o;
        o.x = a2[i].x * cc; o.y = a2[i].y * cc;
        o.z = a2[i].z * cc; o.w = a2[i].w * cc;
        st_h4(&tab[((size_t)knot << 7) + c4], o);
    }
}

// ---------------- node-centric CSR edge kernel: 1 node per 32-lane group ----------------
__launch_bounds__(256)
__global__ void k_edge_csr(const int* __restrict__ s_src, const float* __restrict__ s_fid,
                           const int* __restrict__ rowptr, const int* __restrict__ counts,
                           const ushort* __restrict__ vlin, const ushort* __restrict__ tab,
                           float* __restrict__ agg, int N) {
    const int tid = threadIdx.x;
    const int c4 = (tid & 31) << 2;
    const int n = blockIdx.x * 8 + (tid >> 5);
    if (n >= N) return;
    const ushort* tabc = tab + c4;
    const ushort* vlc = vlin + c4;

    int rs = rowptr[n];
    int re = rs + counts[n];
    float4 run = make_float4(0.f, 0.f, 0.f, 0.f);
    int e = rs;
    for (; e + 4 <= re; e += 4) {
        float4 T0[4], T1[4], VL[4];
        float FR[4];
        #pragma unroll
        for (int j = 0; j < 4; j++) {
            float fid = s_fid[e + j];
            int i0 = (int)fid;
            FR[j] = fid - (float)i0;
            const ushort* tp = tabc + ((size_t)i0 << 7);
            T0[j] = ld_h4(tp);
            T1[j] = ld_h4(tp + 128);
            VL[j] = ld_h4(vlc + ((size_t)s_src[e + j] << 7));
        }
        #pragma unroll
        for (int j = 0; j < 4; j++) {
            float4 w;
            w.x = fmaf(FR[j], T1[j].x - T0[j].x, T0[j].x);
            w.y = fmaf(FR[j], T1[j].y - T0[j].y, T0[j].y);
            w.z = fmaf(FR[j], T1[j].z - T0[j].z, T0[j].z);
            w.w = fmaf(FR[j], T1[j].w - T0[j].w, T0[j].w);
            run.x = fmaf(w.x, VL[j].x, run.x);
            run.y = fmaf(w.y, VL[j].y, run.y);
            run.z = fmaf(w.z, VL[j].z, run.z);
            run.w = fmaf(w.w, VL[j].w, run.w);
        }
    }
    for (; e < re; e++) {
        float fid = s_fid[e];
        int i0 = (int)fid;
        float fr = fid - (float)i0;
        const ushort* tp = tabc + ((size_t)i0 << 7);
        float4 t0 = ld_h4(tp);
        float4 t1 = ld_h4(tp + 128);
        float4 vl = ld_h4(vlc + ((size_t)s_src[e] << 7));
        float4 w;
        w.x = fmaf(fr, t1.x - t0.x, t0.x);
        w.y = fmaf(fr, t1.y - t0.y, t0.y);
        w.z = fmaf(fr, t1.z - t0.z, t0.z);
        w.w = fmaf(fr, t1.w - t0.w, t0.w);
        run.x = fmaf(w.x, vl.x, run.x);
        run.y = fmaf(w.y, vl.y, run.y);
        run.z = fmaf(w.z, vl.z, run.z);
        run.w = fmaf(w.w, vl.w, run.w);
    }
    *(float4*)&agg[((size_t)n << 7) + c4] = run;
}

// ---------------- feature embedding ----------------
__global__ void k_fe1(const float* __restrict__ x, const float* __restrict__ w,
                      const float* __restrict__ b, float* __restrict__ h, int N) {
    int idx = blockIdx.x * 256 + threadIdx.x;
    if (idx >= N * 64) return;
    int n = idx >> 6, c = idx & 63;
    const float* xr = x + (size_t)n * 28;
    float acc = b[c];
    #pragma unroll
    for (int k = 0; k < 28; k++) acc = fmaf(xr[k], w[k * 64 + c], acc);
    h[idx] = acc;
}

__global__ void k_bnstat(const float* __restrict__ h, float* __restrict__ stats, int N) {
    __shared__ float s_s[256], s_q[256];
    int tid = threadIdx.x;
    int c = tid & 63, g = tid >> 6;
    float s = 0.f, q = 0.f;
    for (int n = blockIdx.x * 4 + g; n < N; n += gridDim.x * 4) {
        float v = h[(size_t)n * 64 + c];
        s += v; q += v * v;
    }
    s_s[tid] = s; s_q[tid] = q;
    __syncthreads();
    if (tid < 64) {
        s = s_s[tid] + s_s[tid + 64] + s_s[tid + 128] + s_s[tid + 192];
        q = s_q[tid] + s_q[tid + 64] + s_q[tid + 128] + s_q[tid + 192];
        atomicAdd(&stats[tid], s);
        atomicAdd(&stats[64 + tid], q);
    }
}

__global__ void k_bnfin(const float* __restrict__ stats, float* __restrict__ prm,
                        const float* __restrict__ gamma, const float* __restrict__ beta,
                        float invN) {
    int c = threadIdx.x;  // 64 threads
    float mu = stats[c] * invN;
    float var = stats[64 + c] * invN - mu * mu;
    float sc = gamma[c] * rsqrtf(var + 1e-5f);
    prm[c] = sc;
    prm[64 + c] = beta[c] - mu * sc;
}

// ---------------- MFMA fe2: v = relu( relu(bn(h)) @ fe_w2 + b2 ), K=64 ----------------
__launch_bounds__(256, 4)
__global__ void k_fe2(const float* __restrict__ h, const float* __restrict__ prm,
                      const ushort* __restrict__ w2T, const float* __restrict__ b2,
                      float* __restrict__ v, int N) {
    constexpr int LDP = 72;
    __shared__ _Float16 sH[64 * LDP];
    const int tid = threadIdx.x;
    const int n0 = blockIdx.x * 64;

    for (int i = tid; i < 64 * 16; i += 256) {
        int row = i >> 4, c4 = (i & 15) << 2;
        int gr = n0 + row;
        float4 hv = (gr < N) ? *(const float4*)&h[((size_t)gr << 6) + c4]
                             : make_float4(0.f, 0.f, 0.f, 0.f);
        float4 sc = *(const float4*)&prm[c4];
        float4 sh = *(const float4*)&prm[64 + c4];
        f16x4 o;
        o[0] = (_Float16)fmaxf(fmaf(hv.x, sc.x, sh.x), 0.f);
        o[1] = (_Float16)fmaxf(fmaf(hv.y, sc.y, sh.y), 0.f);
        o[2] = (_Float16)fmaxf(fmaf(hv.z, sc.z, sh.z), 0.f);
        o[3] = (_Float16)fmaxf(fmaf(hv.w, sc.w, sh.w), 0.f);
        *(f16x4*)&sH[row * LDP + c4] = o;
    }
    __syncthreads();

    const int wid = tid >> 6, lane = tid & 63;
    const int lr = lane & 15, lg = lane >> 4;
    const int kof = lg << 3;
    const int arow = wid * 16 + lr;
    const int drow0 = wid * 16 + (lg << 2);

    f16x8 a0 = *(const f16x8*)&sH[arow * LDP + kof];
    f16x8 a1 = *(const f16x8*)&sH[arow * LDP + 32 + kof];

    #pragma unroll
    for (int n = 0; n < 8; n++) {
        const ushort* bp = w2T + (((size_t)(n << 4) + lr) << 6);
        f32x4 c = {0.f, 0.f, 0.f, 0.f};
        c = MFMA16(a0, *(const f16x8*)(bp + kof), c);
        c = MFMA16(a1, *(const f16x8*)(bp + 32 + kof), c);
        int col = (n << 4) + lr;
        float bb = b2[col];
        #pragma unroll
        for (int r = 0; r < 4; r++) {
            int gr = n0 + drow0 + r;
            if (gr < N) v[((size_t)gr << 7) + col] = fmaxf(c[r] + bb, 0.f);
        }
    }
}

// ---------------- MFMA single GEMM: vlin(fp16) = v @ lin, K=128 ----------------
__launch_bounds__(256, 4)
__global__ void k_gemm_rb(const float* __restrict__ A, const ushort* __restrict__ wT,
                          ushort* __restrict__ C, int N) {
    constexpr int LDP = 136;
    __shared__ _Float16 sA[64 * LDP];
    const int tid = threadIdx.x;
    const int n0 = blockIdx.x * 64;

    for (int i = tid; i < 64 * 32; i += 256) {
        int row = i >> 5, c4 = (i & 31) << 2;
        int gr = n0 + row;
        float4 val = (gr < N) ? *(const float4*)&A[((size_t)gr << 7) + c4]
                              : make_float4(0.f, 0.f, 0.f, 0.f);
        f16x4 o;
        o[0] = (_Float16)val.x; o[1] = (_Float16)val.y;
        o[2] = (_Float16)val.z; o[3] = (_Float16)val.w;
        *(f16x4*)&sA[row * LDP + c4] = o;
    }
    __syncthreads();

    const int wid = tid >> 6, lane = tid & 63;
    const int lr = lane & 15, lg = lane >> 4;
    const int kof = lg << 3;
    const int arow = wid * 16 + lr;
    const int drow0 = wid * 16 + (lg << 2);

    f16x8 a0 = *(const f16x8*)&sA[arow * LDP + kof];
    f16x8 a1 = *(const f16x8*)&sA[arow * LDP + 32 + kof];
    f16x8 a2 = *(const f16x8*)&sA[arow * LDP + 64 + kof];
    f16x8 a3 = *(const f16x8*)&sA[arow * LDP + 96 + kof];

    #pragma unroll
    for (int n = 0; n < 8; n++) {
        const ushort* bp = wT + (((size_t)(n << 4) + lr) << 7);
        f32x4 c = {0.f, 0.f, 0.f, 0.f};
        c = MFMA16(a0, *(const f16x8*)(bp + kof), c);
        c = MFMA16(a1, *(const f16x8*)(bp + 32 + kof), c);
        c = MFMA16(a2, *(const f16x8*)(bp + 64 + kof), c);
        c = MFMA16(a3, *(const f16x8*)(bp + 96 + kof), c);
        int col = (n << 4) + lr;
        #pragma unroll
        for (int r = 0; r < 4; r++) {
            int gr = n0 + drow0 + r;
            if (gr < N) C[((size_t)gr << 7) + col] =
                __builtin_bit_cast(ushort, (_Float16)c[r]);
        }
    }
}

// ---------------- MFMA fused layer update: 3 GEMMs, 512 threads / 8 waves ----------------
// waves split output columns: wr = wid&3 (16-row group), wc = wid>>2 (64-col half)
__launch_bounds__(512, 4)
__global__ void k_update(const float* __restrict__ agg,
                         const ushort* __restrict__ w1T, const float* __restrict__ b1,
                         const ushort* __restrict__ w2T, const float* __restrict__ b2,
                         float* __restrict__ v,
                         const ushort* __restrict__ linT, ushort* __restrict__ vlin, int N) {
    constexpr int LDP = 136;
    __shared__ _Float16 sA[64 * LDP];   // 17.4 KB: agg -> t -> v_new (fp16)
    const int tid = threadIdx.x;
    const int n0 = blockIdx.x * 64;

    for (int i = tid; i < 64 * 32; i += 512) {
        int row = i >> 5, c4 = (i & 31) << 2;
        int gr = n0 + row;
        float4 val = (gr < N) ? *(const float4*)&agg[((size_t)gr << 7) + c4]
                              : make_float4(0.f, 0.f, 0.f, 0.f);
        f16x4 o;
        o[0] = (_Float16)val.x; o[1] = (_Float16)val.y;
        o[2] = (_Float16)val.z; o[3] = (_Float16)val.w;
        *(f16x4*)&sA[row * LDP + c4] = o;
    }
    __syncthreads();

    const int wid = tid >> 6, lane = tid & 63;
    const int wr = wid & 3, wc = wid >> 2;
    const int lr = lane & 15, lg = lane >> 4;
    const int kof = lg << 3;
    const int arow = wr * 16 + lr;
    const int drow0 = wr * 16 + (lg << 2);
    const int cbase = wc << 6;   // 0 or 64

    f16x8 a0, a1, a2, a3;
    f32x4 acc[4];

    // ---- GEMM 1: t = ssp(agg @ W1 + b1) ----
    a0 = *(const f16x8*)&sA[arow * LDP + kof];
    a1 = *(const f16x8*)&sA[arow * LDP + 32 + kof];
    a2 = *(const f16x8*)&sA[arow * LDP + 64 + kof];
    a3 = *(const f16x8*)&sA[arow * LDP + 96 + kof];
    #pragma unroll
    for (int n = 0; n < 4; n++) {
        const ushort* bp = w1T + (((size_t)(cbase + (n << 4)) + lr) << 7);
        f32x4 c = {0.f, 0.f, 0.f, 0.f};
        c = MFMA16(a0, *(const f16x8*)(bp + kof), c);
        c = MFMA16(a1, *(const f16x8*)(bp + 32 + kof), c);
        c = MFMA16(a2, *(const f16x8*)(bp + 64 + kof), c);
        c = MFMA16(a3, *(const f16x8*)(bp + 96 + kof), c);
        acc[n] = c;
    }
    __syncthreads();
    #pragma unroll
    for (int n = 0; n < 4; n++) {
        int col = cbase + (n << 4) + lr;
        float bb = b1[col];
        #pragma unroll
        for (int r = 0; r < 4; r++)
            sA[(drow0 + r) * LDP + col] = (_Float16)sspf(acc[n][r] + bb);
    }
    __syncthreads();

    // ---- GEMM 2: v_new = t @ W2 + b2 + v_old ----
    a0 = *(const f16x8*)&sA[arow * LDP + kof];
    a1 = *(const f16x8*)&sA[arow * LDP + 32 + kof];
    a2 = *(const f16x8*)&sA[arow * LDP + 64 + kof];
    a3 = *(const f16x8*)&sA[arow * LDP + 96 + kof];
    #pragma unroll
    for (int n = 0; n < 4; n++) {
        const ushort* bp = w2T + (((size_t)(cbase + (n << 4)) + lr) << 7);
        f32x4 c = {0.f, 0.f, 0.f, 0.f};
        c = MFMA16(a0, *(const f16x8*)(bp + kof), c);
        c = MFMA16(a1, *(const f16x8*)(bp + 32 + kof), c);
        c = MFMA16(a2, *(const f16x8*)(bp + 64 + kof), c);
        c = MFMA16(a3, *(const f16x8*)(bp + 96 + kof), c);
        acc[n] = c;
    }
    __syncthreads();
    #pragma unroll
    for (int n = 0; n < 4; n++) {
        int col = cbase + (n << 4) + lr;
        float bb = b2[col];
        #pragma unroll
        for (int r = 0; r < 4; r++) {
            int gr = n0 + drow0 + r;
            float vn = 0.f;
            if (gr < N) {
                vn = acc[n][r] + bb + v[((size_t)gr << 7) + col];
                v[((size_t)gr << 7) + col] = vn;
            }
            sA[(drow0 + r) * LDP + col] = (_Float16)vn;
        }
    }
    if (!linT) return;
    __syncthreads();

    // ---- GEMM 3: vlin(fp16) = v_new @ lin ----
    a0 = *(const f16x8*)&sA[arow * LDP + kof];
    a1 = *(const f16x8*)&sA[arow * LDP + 32 + kof];
    a2 = *(const f16x8*)&sA[arow * LDP + 64 + kof];
    a3 = *(const f16x8*)&sA[arow * LDP + 96 + kof];
    #pragma unroll
    for (int n = 0; n < 4; n++) {
        const ushort* bp = linT + (((size_t)(cbase + (n << 4)) + lr) << 7);
        f32x4 c = {0.f, 0.f, 0.f, 0.f};
        c = MFMA16(a0, *(const f16x8*)(bp + kof), c);
        c = MFMA16(a1, *(const f16x8*)(bp + 32 + kof), c);
        c = MFMA16(a2, *(const f16x8*)(bp + 64 + kof), c);
        c = MFMA16(a3, *(const f16x8*)(bp + 96 + kof), c);
        int col = cbase + (n << 4) + lr;
        #pragma unroll
        for (int r = 0; r < 4; r++) {
            int gr = n0 + drow0 + r;
            if (gr < N) vlin[((size_t)gr << 7) + col] =
                __builtin_bit_cast(ushort, (_Float16)c[r]);
        }
    }
}

// ---------------- tiled fused readout ----------------
__launch_bounds__(256, 4)
__global__ void k_uout(const float* __restrict__ v, const float* __restrict__ u1w,
                       const float* __restrict__ u1b, const float* __restrict__ u2w,
                       const float* __restrict__ u2b, const int* __restrict__ batch,
                       float* __restrict__ out, int N) {
    __shared__ float sA[64 * 128];
    const int tid = threadIdx.x;
    const int n0 = blockIdx.x * 64;

    for (int i = tid; i < 64 * 32; i += 256) {
        int row = i >> 5, cq = (i & 31) << 2;
        int gr = n0 + row;
        float4 val = (gr < N) ? *(const float4*)&v[((size_t)gr << 7) + cq]
                              : make_float4(0.f, 0.f, 0.f, 0.f);
        *(float4*)&sA[row * 128 + cq] = val;
    }
    __syncthreads();

    const int cg = tid & 31, rg = tid >> 5;
    const int r0 = rg << 3;
    const int c2 = cg << 1;

    float2 acc[8];
    {
        float2 b1v = *(const float2*)&u1b[c2];
        #pragma unroll
        for (int i = 0; i < 8; i++) acc[i] = b1v;
        #pragma unroll 4
        for (int k = 0; k < 128; k++) {
            float2 wv = *(const float2*)&u1w[(k << 6) + c2];
            #pragma unroll
            for (int i = 0; i < 8; i++) {
                float a = sA[(r0 + i) * 128 + k];
                acc[i].x = fmaf(a, wv.x, acc[i].x);
                acc[i].y = fmaf(a, wv.y, acc[i].y);
            }
        }
    }
    __syncthreads();
    #pragma unroll
    for (int i = 0; i < 8; i++) {
        sA[(r0 + i) * 64 + c2 + 0] = sspf(acc[i].x);
        sA[(r0 + i) * 64 + c2 + 1] = sspf(acc[i].y);
    }
    __syncthreads();

    float acc2[8];
    {
        float bb = u2b[cg];
        #pragma unroll
        for (int i = 0; i < 8; i++) acc2[i] = bb;
        #pragma unroll 4
        for (int k = 0; k < 64; k++) {
            float wv = u2w[(k << 5) + cg];
            #pragma unroll
            for (int i = 0; i < 8; i++)
                acc2[i] = fmaf(sA[(r0 + i) * 64 + k], wv, acc2[i]);
        }
    }

    int cur = -1;
    float run = 0.f;
    #pragma unroll
    for (int i = 0; i < 8; i++) {
        int gr = n0 + r0 + i;
        int g = (gr < N) ? batch[gr] : -1;
        if (g != cur) {
            if (cur >= 0) atomicAdd(&out[(size_t)cur * 32 + cg], run);
            cur = g;
            run = 0.f;
        }
        if (g >= 0) run += acc2[i];
    }
    if (cur >= 0) atomicAdd(&out[(size_t)cur * 32 + cg], run);
}

extern "C" void kernel_launch(void* const* d_in, const int* in_sizes, int n_in,
                              void* d_out, int out_size, void* d_ws, size_t ws_size,
                              hipStream_t stream) {
    const float* x      = (const float*)d_in[0];
    const float* pos    = (const float*)d_in[1];
    const int*   batch  = (const int*)d_in[2];
    const int*   ei     = (const int*)d_in[3];
    const float* fe_w1  = (const float*)d_in[4];
    const float* fe_b1  = (const float*)d_in[5];
    const float* bn_g   = (const float*)d_in[6];
    const float* bn_b   = (const float*)d_in[7];
    const float* fe_w2  = (const float*)d_in[8];
    const float* fe_b2  = (const float*)d_in[9];
    const float* lin_w  = (const float*)d_in[10];
    const float* mlp_w1 = (const float*)d_in[11];
    const float* mlp_b1 = (const float*)d_in[12];
    const float* mlp_w2 = (const float*)d_in[13];
    const float* mlp_b2 = (const float*)d_in[14];
    const float* v1_w   = (const float*)d_in[15];
    const float* v1_b   = (const float*)d_in[16];
    const float* v2_w   = (const float*)d_in[17];
    const float* v2_b   = (const float*)d_in[18];
    const float* u1_w   = (const float*)d_in[19];
    const float* u1_b   = (const float*)d_in[20];
    const float* u2_w   = (const float*)d_in[21];
    const float* u2_b   = (const float*)d_in[22];

    const int N = in_sizes[0] / 28;
    const int E = in_sizes[3] / 2;
    const int NB1 = (N + 1023) / 1024;

    char* ws = (char*)d_ws;
    size_t o = 0;
    auto alloc = [&](size_t bytes) { void* p = ws + o; o += (bytes + 255) & ~(size_t)255; return p; };
    int*    counts = (int*)   alloc((size_t)N * 4);
    int*    cursor = (int*)   alloc((size_t)N * 4);
    int*    rowptr = (int*)   alloc((size_t)N * 4);
    int*    bsum   = (int*)   alloc((size_t)NB1 * 4);
    int*    s_src  = (int*)   alloc((size_t)E * 4);
    float*  s_fid  = (float*) alloc((size_t)E * 4);
    float*  stats  = (float*) alloc(128 * 4);
    float*  prm    = (float*) alloc(128 * 4);
    ushort* tab    = (ushort*)alloc((size_t)LAY * K_TAB * 128 * 2);  // 12 MB fp16
    float*  v      = (float*) alloc((size_t)N * 128 * 4);
    ushort* vlin   = (ushort*)alloc((size_t)N * 128 * 2);            // fp16
    float*  agg    = (float*) alloc((size_t)N * 128 * 4);
    float*  h      = agg;     // alias: h (N x 64 f32) used only before agg's first use
    int*    locex  = (int*)   alloc((size_t)N * 4);
    ushort* v1T    = (ushort*)alloc((size_t)LAY * 16384 * 2);   // fp16 transposed weights
    ushort* v2T    = (ushort*)alloc((size_t)LAY * 16384 * 2);
    ushort* linT   = (ushort*)alloc((size_t)LAY * 16384 * 2);
    ushort* fe2T   = (ushort*)alloc((size_t)8192 * 2);

    // -------- weight conversion (fp16, transposed) --------
    k_cvtT128<<<LAY, 256, 0, stream>>>(v1_w, v1T);
    k_cvtT128<<<LAY, 256, 0, stream>>>(v2_w, v2T);
    k_cvtT128<<<LAY, 256, 0, stream>>>(lin_w, linT);
    k_cvtT_fe<<<1, 256, 0, stream>>>(fe_w2, fe2T);

    // -------- one-time edge sort (dst-ordered CSR) --------
    hipMemsetAsync(counts, 0, (size_t)N * 4, stream);
    k_hist<<<(E + 255) / 256, 256, 0, stream>>>(ei, counts, E);
    k_scan1<<<NB1, 1024, 0, stream>>>(counts, locex, bsum, N);
    k_scan2<<<1, 1024, 0, stream>>>(bsum, NB1);
    k_scan3<<<(N + 255) / 256, 256, 0, stream>>>(locex, bsum, cursor, rowptr, N);
    k_scatter<<<(E + 255) / 256, 256, 0, stream>>>(ei, pos, cursor, s_src, s_fid, E);

    // -------- gate tables for all layers (fp16) --------
    k_tab_all<<<LAY * 256, 256, 0, stream>>>(mlp_w1, mlp_b1, mlp_w2, mlp_b2, tab);

    // -------- feature embedding --------
    hipMemsetAsync(stats, 0, 128 * 4, stream);
    k_fe1<<<(N * 64 + 255) / 256, 256, 0, stream>>>(x, fe_w1, fe_b1, h, N);
    k_bnstat<<<256, 256, 0, stream>>>(h, stats, N);
    k_bnfin<<<1, 64, 0, stream>>>(stats, prm, bn_g, bn_b, 1.0f / (float)N);
    const int gblk = (N + 63) / 64;
    k_fe2<<<gblk, 256, 0, stream>>>(h, prm, fe2T, fe_b2, v, N);

    // vlin for layer 0
    k_gemm_rb<<<gblk, 256, 0, stream>>>(v, linT, vlin, N);

    // -------- interaction layers --------
    const int eblk = (N + 7) / 8;
    for (int l = 0; l < LAY; l++) {
        k_edge_csr<<<eblk, 256, 0, stream>>>(
            s_src, s_fid, rowptr, counts, vlin,
            tab + (size_t)l * K_TAB * 128, agg, N);
        const ushort* lin_next = (l + 1 < LAY) ? linT + (size_t)(l + 1) * 16384 : nullptr;
        k_update<<<gblk, 512, 0, stream>>>(
            agg, v1T + (size_t)l * 16384, v1_b + (size_t)l * 128,
            v2T + (size_t)l * 16384, v2_b + (size_t)l * 128,
            v, lin_next, vlin, N);
    }

    // -------- fused readout --------
    hipMemsetAsync(d_out, 0, (size_t)out_size * 4, stream);
    k_uout<<<gblk, 256, 0, stream>>>(v, u1_w, u1_b, u2_w, u2_b, batch, (float*)d_out, N);
}